// Round 4
// baseline (1284.221 us; speedup 1.0000x reference)
//
#include <hip/hip_runtime.h>

#define N_NODES 100000
#define N_EDGES 1600000
#define F_IN    128
#define HC      128     // H * C
#define NGRAPH  64
#define NEG_SLOPE 0.2f

static constexpr int SCAN_NB = (N_NODES + 255) / 256;   // 391
static constexpr int TOT_E   = N_EDGES + N_NODES;       // with self loops

typedef __bf16 bf16x8 __attribute__((ext_vector_type(8)));
typedef float  f32x4  __attribute__((ext_vector_type(4)));

// ---------------- CSR build ----------------

__global__ __launch_bounds__(256) void hist_kernel(const int* __restrict__ ei, int* __restrict__ deg) {
    int i = blockIdx.x * 256 + threadIdx.x;
    if (i < N_EDGES) {
        atomicAdd(&deg[ei[N_EDGES + i]], 1);      // dst of real edge
    } else if (i < TOT_E) {
        atomicAdd(&deg[i - N_EDGES], 1);          // self loop
    }
}

__global__ __launch_bounds__(256) void scan_partial(const int* __restrict__ deg, int* __restrict__ bsum) {
    int i = blockIdx.x * 256 + threadIdx.x;
    int d = (i < N_NODES) ? deg[i] : 0;
    for (int off = 32; off; off >>= 1) d += __shfl_down(d, off);
    __shared__ int wsum[4];
    int lane = threadIdx.x & 63, w = threadIdx.x >> 6;
    if (lane == 0) wsum[w] = d;
    __syncthreads();
    if (threadIdx.x == 0) bsum[blockIdx.x] = wsum[0] + wsum[1] + wsum[2] + wsum[3];
}

__global__ void scan_bsum(const int* __restrict__ bsum, int* __restrict__ boff) {
    __shared__ int sd[512];
    int t = threadIdx.x;
    int v = (t < SCAN_NB) ? bsum[t] : 0;
    sd[t] = v; __syncthreads();
    for (int off = 1; off < 512; off <<= 1) {
        int x = (t >= off) ? sd[t - off] : 0;
        __syncthreads();
        sd[t] += x;
        __syncthreads();
    }
    if (t < SCAN_NB) boff[t] = sd[t] - v;   // exclusive
}

__global__ __launch_bounds__(256) void scan_final(const int* __restrict__ deg, const int* __restrict__ boff,
                                                  int* __restrict__ offs, int* __restrict__ cursor) {
    __shared__ int sd[256];
    int t = threadIdx.x;
    int i = blockIdx.x * 256 + t;
    int d = (i < N_NODES) ? deg[i] : 0;
    sd[t] = d; __syncthreads();
    for (int off = 1; off < 256; off <<= 1) {
        int x = (t >= off) ? sd[t - off] : 0;
        __syncthreads();
        sd[t] += x;
        __syncthreads();
    }
    int incl = sd[t];
    int base = boff[blockIdx.x];
    if (i < N_NODES) {
        offs[i + 1] = base + incl;
        cursor[i]   = base + incl - d;
    }
    if (i == 0) offs[0] = 0;
}

__global__ __launch_bounds__(256) void scatter_kernel(const int* __restrict__ ei, int* __restrict__ cursor,
                                                      int* __restrict__ csr_src, int* __restrict__ epos) {
    int i = blockIdx.x * 256 + threadIdx.x;
    int s, d;
    if (i < N_EDGES)      { s = ei[i]; d = ei[N_EDGES + i]; }
    else if (i < TOT_E)   { s = i - N_EDGES; d = s; }
    else return;
    int pos = atomicAdd(&cursor[d], 1);
    csr_src[pos] = s;
    epos[i] = pos;
}

__global__ __launch_bounds__(256) void counts_kernel(const int* __restrict__ batch, int* __restrict__ counts) {
    __shared__ int loc[NGRAPH];
    int t = threadIdx.x;
    if (t < NGRAPH) loc[t] = 0;
    __syncthreads();
    int i = blockIdx.x * 256 + t;
    if (i < N_NODES) atomicAdd(&loc[batch[i]], 1);
    __syncthreads();
    if (t < NGRAPH && loc[t]) atomicAdd(&counts[t], loc[t]);
}

// ---------------- W -> bf16, fragment-ready layout Wt[k>>3][col][k&7] ----------------

__device__ __forceinline__ unsigned short f2bf_rne(float f) {
    unsigned u = __float_as_uint(f);
    u += 0x7fffu + ((u >> 16) & 1u);
    return (unsigned short)(u >> 16);
}

__global__ __launch_bounds__(256) void wtconv_kernel(const float* __restrict__ W, unsigned short* __restrict__ Wt) {
    int i = blockIdx.x * 256 + threadIdx.x;
    if (i >= F_IN * HC) return;
    int k = i >> 7, col = i & 127;
    Wt[(size_t)(k >> 3) * (HC * 8) + col * 8 + (k & 7)] = f2bf_rne(W[i]);
}

// ---------------- GEMM: H = X @ W via MFMA bf16 ----------------
// block = 256 (4 waves), tile = 64 rows x 128 cols. Wave (wr,wc) owns rows 32*wr..+31,
// cols 64*wc..+63. B-frags in registers; A staged fp32->bf16 in LDS, XOR swizzled.

__global__ __launch_bounds__(256) void gemm_mfma(const float* __restrict__ X,
                                                 const unsigned short* __restrict__ Wt,
                                                 float* __restrict__ Hout) {
    __shared__ unsigned short A_lds[64 * F_IN];     // 16 KB
    int t = threadIdx.x;
    int lane = t & 63, wave = t >> 6;
    int wc = wave & 1, wr = wave >> 1;
    int base = blockIdx.x * 64;

    bf16x8 Bf[4][4];
    {
        int colb = wc * 64 + (lane & 15);
        int kbb  = lane >> 4;
#pragma unroll
        for (int ct = 0; ct < 4; ++ct)
#pragma unroll
            for (int ks = 0; ks < 4; ++ks) {
                int kb = kbb + 4 * ks;
                Bf[ct][ks] = *(const bf16x8*)&Wt[(size_t)kb * (HC * 8) + (colb + ct * 16) * 8];
            }
    }

#pragma unroll
    for (int it = 0; it < 8; ++it) {
        int i = t + it * 256;
        int row = i >> 5, c4 = i & 31, k0 = c4 * 4;
        float4 v = make_float4(0.f, 0.f, 0.f, 0.f);
        if (base + row < N_NODES) v = ((const float4*)X)[(size_t)(base + row) * 32 + c4];
        unsigned p0 = (unsigned)f2bf_rne(v.x) | ((unsigned)f2bf_rne(v.y) << 16);
        unsigned p1 = (unsigned)f2bf_rne(v.z) | ((unsigned)f2bf_rne(v.w) << 16);
        int byte = row * 256 + (((k0 >> 3) ^ (row & 7)) << 4) + (k0 & 4) * 2;
        uint2 pk; pk.x = p0; pk.y = p1;
        *(uint2*)((char*)A_lds + byte) = pk;
    }
    __syncthreads();

    f32x4 acc[2][4] = {};
#pragma unroll
    for (int ks = 0; ks < 4; ++ks) {
        bf16x8 Af[2];
#pragma unroll
        for (int r = 0; r < 2; ++r) {
            int row = wr * 32 + r * 16 + (lane & 15);
            int kb  = ks * 4 + (lane >> 4);
            int byte = row * 256 + ((kb ^ (row & 7)) << 4);
            Af[r] = *(const bf16x8*)((const char*)A_lds + byte);
        }
#pragma unroll
        for (int ct = 0; ct < 4; ++ct) {
            acc[0][ct] = __builtin_amdgcn_mfma_f32_16x16x32_bf16(Af[0], Bf[ct][ks], acc[0][ct], 0, 0, 0);
            acc[1][ct] = __builtin_amdgcn_mfma_f32_16x16x32_bf16(Af[1], Bf[ct][ks], acc[1][ct], 0, 0, 0);
        }
    }

#pragma unroll
    for (int r = 0; r < 2; ++r) {
        int row0 = base + wr * 32 + r * 16 + (lane >> 4) * 4;
#pragma unroll
        for (int reg = 0; reg < 4; ++reg) {
            int row = row0 + reg;
            if (row < N_NODES) {
#pragma unroll
                for (int ct = 0; ct < 4; ++ct) {
                    int col = wc * 64 + ct * 16 + (lane & 15);
                    Hout[(size_t)row * HC + col] = acc[r][ct][reg];
                }
            }
        }
    }
}

// ---------------- per-node attention logits ----------------

__global__ __launch_bounds__(256) void alpha_kernel(const float* __restrict__ H,
                                                    const float* __restrict__ a_src, const float* __restrict__ a_dst,
                                                    float* __restrict__ asrc, float* __restrict__ adst) {
    int wid  = (blockIdx.x * 256 + threadIdx.x) >> 6;
    int lane = threadIdx.x & 63;
    if (wid >= N_NODES) return;
    float2 hv = *(const float2*)&H[(size_t)wid * HC + lane * 2];
    int ch = lane * 2;
    float2 as = *(const float2*)&a_src[ch];
    float2 ad = *(const float2*)&a_dst[ch];
    float ps = hv.x * as.x + hv.y * as.y;
    float pd = hv.x * ad.x + hv.y * ad.y;
    for (int off = 16; off; off >>= 1) {
        ps += __shfl_xor(ps, off);
        pd += __shfl_xor(pd, off);
    }
    int head = lane >> 5;
    if ((lane & 31) == 0) {
        asrc[wid * 2 + head] = ps;
        adst[wid * 2 + head] = pd;
    }
}

// ---------------- per-edge softmax numerators, written in CSR order ----------------

__global__ __launch_bounds__(256) void edgew_kernel(const int* __restrict__ ei, const int* __restrict__ epos,
                                                    const float* __restrict__ asrc, const float* __restrict__ adst,
                                                    float* __restrict__ wbuf) {
    int i = blockIdx.x * 256 + threadIdx.x;
    int s, d;
    if (i < N_EDGES)      { s = ei[i]; d = ei[N_EDGES + i]; }
    else if (i < TOT_E)   { s = i - N_EDGES; d = s; }
    else return;
    float2 as = *(const float2*)&asrc[(size_t)s * 2];
    float2 ad = *(const float2*)&adst[(size_t)d * 2];
    float e0 = as.x + ad.x; e0 = e0 > 0.f ? e0 : NEG_SLOPE * e0;
    float e1 = as.y + ad.y; e1 = e1 > 0.f ? e1 : NEG_SLOPE * e1;
    int p = epos[i];
    *(float2*)&wbuf[(size_t)p * 2] = make_float2(__expf(e0), __expf(e1));
}

// ---------------- aggregation: round-2 proven loop + fused-pool epilogue ----------------
// lanes 0-31 process even CSR edges, lanes 32-63 odd edges; each lane holds float4
// (channels 4*hl .. 4*hl+3); halves combined via shfl_xor(32) at the end.
// mode 0: relu -> Hout row.  mode 1: scaled atomicAdd into pooled[batch[wid]].

__global__ __launch_bounds__(256) void agg_kernel(const int* __restrict__ offs, const int* __restrict__ csr_src,
                                                  const float* __restrict__ wbuf,
                                                  const float* __restrict__ Hin, const float* __restrict__ bias,
                                                  float* __restrict__ Hout, int mode,
                                                  const int* __restrict__ batch, const int* __restrict__ counts,
                                                  float* __restrict__ pooled) {
    int wid  = (blockIdx.x * 256 + threadIdx.x) >> 6;
    int lane = threadIdx.x & 63;
    if (wid >= N_NODES) return;
    int beg = offs[wid], end = offs[wid + 1];
    int half = lane >> 5;
    int hl   = lane & 31;          // channels 4*hl .. 4*hl+3
    int head = hl >> 4;

    float den = 0.f;
    float4 acc = make_float4(0.f, 0.f, 0.f, 0.f);

    // unrolled by 2: up to 2 independent h-row gathers in flight per half-wave (4 per wave)
    for (int e = beg + half; e < end; e += 4) {
        int e1 = e + 2;
        bool v1 = e1 < end;
        int s0 = csr_src[e];
        int s1 = v1 ? csr_src[e1] : s0;
        float w0 = wbuf[(size_t)e * 2 + head];
        float w1 = v1 ? wbuf[(size_t)e1 * 2 + head] : 0.f;
        float4 h0 = *(const float4*)&Hin[(size_t)s0 * HC + hl * 4];
        float4 h1 = *(const float4*)&Hin[(size_t)s1 * HC + hl * 4];
        den += w0 + w1;
        acc.x = fmaf(w1, h1.x, fmaf(w0, h0.x, acc.x));
        acc.y = fmaf(w1, h1.y, fmaf(w0, h0.y, acc.y));
        acc.z = fmaf(w1, h1.z, fmaf(w0, h0.z, acc.z));
        acc.w = fmaf(w1, h1.w, fmaf(w0, h0.w, acc.w));
    }

    den   += __shfl_xor(den, 32);
    acc.x += __shfl_xor(acc.x, 32);
    acc.y += __shfl_xor(acc.y, 32);
    acc.z += __shfl_xor(acc.z, 32);
    acc.w += __shfl_xor(acc.w, 32);

    if (half == 0) {
        float inv = 1.0f / den;
        float4 b = *(const float4*)&bias[hl * 4];
        float4 o;
        o.x = fmaf(acc.x, inv, b.x);
        o.y = fmaf(acc.y, inv, b.y);
        o.z = fmaf(acc.z, inv, b.z);
        o.w = fmaf(acc.w, inv, b.w);
        if (mode == 0) {
            o.x = fmaxf(o.x, 0.f); o.y = fmaxf(o.y, 0.f);
            o.z = fmaxf(o.z, 0.f); o.w = fmaxf(o.w, 0.f);
            *(float4*)&Hout[(size_t)wid * HC + hl * 4] = o;
        } else {
            int g = batch[wid];
            float ic = 1.0f / fmaxf((float)counts[g], 1.0f);
            atomicAdd(&pooled[g * HC + hl * 4 + 0], o.x * ic);
            atomicAdd(&pooled[g * HC + hl * 4 + 1], o.y * ic);
            atomicAdd(&pooled[g * HC + hl * 4 + 2], o.z * ic);
            atomicAdd(&pooled[g * HC + hl * 4 + 3], o.w * ic);
        }
    }
}

// ---------------- launch ----------------

extern "C" void kernel_launch(void* const* d_in, const int* in_sizes, int n_in,
                              void* d_out, int out_size, void* d_ws, size_t ws_size,
                              hipStream_t stream) {
    const float* x     = (const float*)d_in[0];
    const int*   ei    = (const int*)d_in[1];
    const int*   batch = (const int*)d_in[2];
    const float* W1    = (const float*)d_in[3];
    const float* a1s   = (const float*)d_in[4];
    const float* a1d   = (const float*)d_in[5];
    const float* b1    = (const float*)d_in[6];
    const float* W2    = (const float*)d_in[7];
    const float* a2s   = (const float*)d_in[8];
    const float* a2d   = (const float*)d_in[9];
    const float* b2    = (const float*)d_in[10];
    float* out = (float*)d_out;

    char* ws = (char*)d_ws;
    const size_t SZ_H = (size_t)N_NODES * HC * sizeof(float);   // 51.2 MB
    float* hA   = (float*)(ws);
    float* hB   = (float*)(ws + SZ_H);
    float* asrc = (float*)(ws + 2 * SZ_H);
    float* adst = asrc + (size_t)N_NODES * 2;
    float* wbuf = adst + (size_t)N_NODES * 2;                   // TOT_E * 2 floats
    unsigned short* wt1 = (unsigned short*)(wbuf + (size_t)TOT_E * 2);
    unsigned short* wt2 = wt1 + F_IN * HC;
    int*   deg  = (int*)(wt2 + F_IN * HC);
    int*   offs = deg + (N_NODES + 1);
    int*   cursor = offs + (N_NODES + 1);
    int*   csr  = cursor + N_NODES;
    int*   epos = csr + TOT_E;
    int*   bsum = epos + TOT_E;
    int*   boff = bsum + SCAN_NB;
    int*   counts = boff + SCAN_NB;

    hipMemsetAsync(deg, 0, (N_NODES + 1) * sizeof(int), stream);
    hipMemsetAsync(counts, 0, NGRAPH * sizeof(int), stream);
    hipMemsetAsync(out, 0, (size_t)out_size * sizeof(float), stream);

    int histBlocks = (TOT_E + 255) / 256;
    wtconv_kernel<<<(F_IN * HC + 255) / 256, 256, 0, stream>>>(W1, wt1);
    wtconv_kernel<<<(F_IN * HC + 255) / 256, 256, 0, stream>>>(W2, wt2);
    hist_kernel<<<histBlocks, 256, 0, stream>>>(ei, deg);
    counts_kernel<<<(N_NODES + 255) / 256, 256, 0, stream>>>(batch, counts);
    scan_partial<<<SCAN_NB, 256, 0, stream>>>(deg, bsum);
    scan_bsum<<<1, 512, 0, stream>>>(bsum, boff);
    scan_final<<<SCAN_NB, 256, 0, stream>>>(deg, boff, offs, cursor);
    scatter_kernel<<<histBlocks, 256, 0, stream>>>(ei, cursor, csr, epos);

    int gemmBlocks = (N_NODES + 63) / 64;
    int waveBlocks = (N_NODES + 3) / 4;

    // layer 1
    gemm_mfma<<<gemmBlocks, 256, 0, stream>>>(x, wt1, hA);
    alpha_kernel<<<waveBlocks, 256, 0, stream>>>(hA, a1s, a1d, asrc, adst);
    edgew_kernel<<<histBlocks, 256, 0, stream>>>(ei, epos, asrc, adst, wbuf);
    agg_kernel<<<waveBlocks, 256, 0, stream>>>(offs, csr, wbuf, hA, b1, hB, 0,
                                               batch, counts, out);

    // layer 2 (pool fused into agg epilogue)
    gemm_mfma<<<gemmBlocks, 256, 0, stream>>>(hB, wt2, hA);
    alpha_kernel<<<waveBlocks, 256, 0, stream>>>(hA, a2s, a2d, asrc, adst);
    edgew_kernel<<<histBlocks, 256, 0, stream>>>(ei, epos, asrc, adst, wbuf);
    agg_kernel<<<waveBlocks, 256, 0, stream>>>(offs, csr, wbuf, hA, b2, nullptr, 1,
                                               batch, counts, out);
}

// Round 5
// 617.866 us; speedup vs baseline: 2.0785x; 2.0785x over previous
//
#include <hip/hip_runtime.h>

#define N_NODES 100000
#define N_EDGES 1600000
#define F_IN    128
#define HC      128     // H * C
#define NGRAPH  64
#define NEG_SLOPE 0.2f

static constexpr int SCAN_NB = (N_NODES + 255) / 256;   // 391
static constexpr int TOT_E   = N_EDGES + N_NODES;       // with self loops

typedef __bf16 bf16x8 __attribute__((ext_vector_type(8)));
typedef float  f32x4  __attribute__((ext_vector_type(4)));

// ---------------- CSR build ----------------

__global__ __launch_bounds__(256) void hist_kernel(const int* __restrict__ ei, int* __restrict__ deg) {
    int i = blockIdx.x * 256 + threadIdx.x;
    if (i < N_EDGES) {
        atomicAdd(&deg[ei[N_EDGES + i]], 1);      // dst of real edge
    } else if (i < TOT_E) {
        atomicAdd(&deg[i - N_EDGES], 1);          // self loop
    }
}

__global__ __launch_bounds__(256) void scan_partial(const int* __restrict__ deg, int* __restrict__ bsum) {
    int i = blockIdx.x * 256 + threadIdx.x;
    int d = (i < N_NODES) ? deg[i] : 0;
    for (int off = 32; off; off >>= 1) d += __shfl_down(d, off);
    __shared__ int wsum[4];
    int lane = threadIdx.x & 63, w = threadIdx.x >> 6;
    if (lane == 0) wsum[w] = d;
    __syncthreads();
    if (threadIdx.x == 0) bsum[blockIdx.x] = wsum[0] + wsum[1] + wsum[2] + wsum[3];
}

__global__ void scan_bsum(const int* __restrict__ bsum, int* __restrict__ boff) {
    __shared__ int sd[512];
    int t = threadIdx.x;
    int v = (t < SCAN_NB) ? bsum[t] : 0;
    sd[t] = v; __syncthreads();
    for (int off = 1; off < 512; off <<= 1) {
        int x = (t >= off) ? sd[t - off] : 0;
        __syncthreads();
        sd[t] += x;
        __syncthreads();
    }
    if (t < SCAN_NB) boff[t] = sd[t] - v;   // exclusive
}

__global__ __launch_bounds__(256) void scan_final(const int* __restrict__ deg, const int* __restrict__ boff,
                                                  int* __restrict__ offs, int* __restrict__ cursor) {
    __shared__ int sd[256];
    int t = threadIdx.x;
    int i = blockIdx.x * 256 + t;
    int d = (i < N_NODES) ? deg[i] : 0;
    sd[t] = d; __syncthreads();
    for (int off = 1; off < 256; off <<= 1) {
        int x = (t >= off) ? sd[t - off] : 0;
        __syncthreads();
        sd[t] += x;
        __syncthreads();
    }
    int incl = sd[t];
    int base = boff[blockIdx.x];
    if (i < N_NODES) {
        offs[i + 1] = base + incl;
        cursor[i]   = base + incl - d;
    }
    if (i == 0) offs[0] = 0;
}

__global__ __launch_bounds__(256) void scatter_kernel(const int* __restrict__ ei, int* __restrict__ cursor,
                                                      int* __restrict__ csr_src, int* __restrict__ epos) {
    int i = blockIdx.x * 256 + threadIdx.x;
    int s, d;
    if (i < N_EDGES)      { s = ei[i]; d = ei[N_EDGES + i]; }
    else if (i < TOT_E)   { s = i - N_EDGES; d = s; }
    else return;
    int pos = atomicAdd(&cursor[d], 1);
    csr_src[pos] = s;
    epos[i] = pos;
}

__global__ __launch_bounds__(256) void counts_kernel(const int* __restrict__ batch, int* __restrict__ counts) {
    __shared__ int loc[NGRAPH];
    int t = threadIdx.x;
    if (t < NGRAPH) loc[t] = 0;
    __syncthreads();
    int i = blockIdx.x * 256 + t;
    if (i < N_NODES) atomicAdd(&loc[batch[i]], 1);
    __syncthreads();
    if (t < NGRAPH && loc[t]) atomicAdd(&counts[t], loc[t]);
}

// ---------------- W -> bf16, fragment-ready layout Wt[k>>3][col][k&7] ----------------

__device__ __forceinline__ unsigned short f2bf_rne(float f) {
    unsigned u = __float_as_uint(f);
    u += 0x7fffu + ((u >> 16) & 1u);
    return (unsigned short)(u >> 16);
}

__global__ __launch_bounds__(256) void wtconv_kernel(const float* __restrict__ W, unsigned short* __restrict__ Wt) {
    int i = blockIdx.x * 256 + threadIdx.x;
    if (i >= F_IN * HC) return;
    int k = i >> 7, col = i & 127;
    Wt[(size_t)(k >> 3) * (HC * 8) + col * 8 + (k & 7)] = f2bf_rne(W[i]);
}

// ---------------- GEMM: H = X @ W via MFMA bf16 ----------------
// block = 256 (4 waves), tile = 64 rows x 128 cols. Wave (wr,wc) owns rows 32*wr..+31,
// cols 64*wc..+63. B-frags in registers; A staged fp32->bf16 in LDS, XOR swizzled.

__global__ __launch_bounds__(256) void gemm_mfma(const float* __restrict__ X,
                                                 const unsigned short* __restrict__ Wt,
                                                 float* __restrict__ Hout) {
    __shared__ unsigned short A_lds[64 * F_IN];     // 16 KB
    int t = threadIdx.x;
    int lane = t & 63, wave = t >> 6;
    int wc = wave & 1, wr = wave >> 1;
    int base = blockIdx.x * 64;

    bf16x8 Bf[4][4];
    {
        int colb = wc * 64 + (lane & 15);
        int kbb  = lane >> 4;
#pragma unroll
        for (int ct = 0; ct < 4; ++ct)
#pragma unroll
            for (int ks = 0; ks < 4; ++ks) {
                int kb = kbb + 4 * ks;
                Bf[ct][ks] = *(const bf16x8*)&Wt[(size_t)kb * (HC * 8) + (colb + ct * 16) * 8];
            }
    }

#pragma unroll
    for (int it = 0; it < 8; ++it) {
        int i = t + it * 256;
        int row = i >> 5, c4 = i & 31, k0 = c4 * 4;
        float4 v = make_float4(0.f, 0.f, 0.f, 0.f);
        if (base + row < N_NODES) v = ((const float4*)X)[(size_t)(base + row) * 32 + c4];
        unsigned p0 = (unsigned)f2bf_rne(v.x) | ((unsigned)f2bf_rne(v.y) << 16);
        unsigned p1 = (unsigned)f2bf_rne(v.z) | ((unsigned)f2bf_rne(v.w) << 16);
        int byte = row * 256 + (((k0 >> 3) ^ (row & 7)) << 4) + (k0 & 4) * 2;
        uint2 pk; pk.x = p0; pk.y = p1;
        *(uint2*)((char*)A_lds + byte) = pk;
    }
    __syncthreads();

    f32x4 acc[2][4] = {};
#pragma unroll
    for (int ks = 0; ks < 4; ++ks) {
        bf16x8 Af[2];
#pragma unroll
        for (int r = 0; r < 2; ++r) {
            int row = wr * 32 + r * 16 + (lane & 15);
            int kb  = ks * 4 + (lane >> 4);
            int byte = row * 256 + ((kb ^ (row & 7)) << 4);
            Af[r] = *(const bf16x8*)((const char*)A_lds + byte);
        }
#pragma unroll
        for (int ct = 0; ct < 4; ++ct) {
            acc[0][ct] = __builtin_amdgcn_mfma_f32_16x16x32_bf16(Af[0], Bf[ct][ks], acc[0][ct], 0, 0, 0);
            acc[1][ct] = __builtin_amdgcn_mfma_f32_16x16x32_bf16(Af[1], Bf[ct][ks], acc[1][ct], 0, 0, 0);
        }
    }

#pragma unroll
    for (int r = 0; r < 2; ++r) {
        int row0 = base + wr * 32 + r * 16 + (lane >> 4) * 4;
#pragma unroll
        for (int reg = 0; reg < 4; ++reg) {
            int row = row0 + reg;
            if (row < N_NODES) {
#pragma unroll
                for (int ct = 0; ct < 4; ++ct) {
                    int col = wc * 64 + ct * 16 + (lane & 15);
                    Hout[(size_t)row * HC + col] = acc[r][ct][reg];
                }
            }
        }
    }
}

// ---------------- per-node attention logits ----------------

__global__ __launch_bounds__(256) void alpha_kernel(const float* __restrict__ H,
                                                    const float* __restrict__ a_src, const float* __restrict__ a_dst,
                                                    float* __restrict__ asrc, float* __restrict__ adst) {
    int wid  = (blockIdx.x * 256 + threadIdx.x) >> 6;
    int lane = threadIdx.x & 63;
    if (wid >= N_NODES) return;
    float2 hv = *(const float2*)&H[(size_t)wid * HC + lane * 2];
    int ch = lane * 2;
    float2 as = *(const float2*)&a_src[ch];
    float2 ad = *(const float2*)&a_dst[ch];
    float ps = hv.x * as.x + hv.y * as.y;
    float pd = hv.x * ad.x + hv.y * ad.y;
    for (int off = 16; off; off >>= 1) {
        ps += __shfl_xor(ps, off);
        pd += __shfl_xor(pd, off);
    }
    int head = lane >> 5;
    if ((lane & 31) == 0) {
        asrc[wid * 2 + head] = ps;
        adst[wid * 2 + head] = pd;
    }
}

// ---------------- per-edge softmax numerators, written in CSR order ----------------

__global__ __launch_bounds__(256) void edgew_kernel(const int* __restrict__ ei, const int* __restrict__ epos,
                                                    const float* __restrict__ asrc, const float* __restrict__ adst,
                                                    float* __restrict__ wbuf) {
    int i = blockIdx.x * 256 + threadIdx.x;
    int s, d;
    if (i < N_EDGES)      { s = ei[i]; d = ei[N_EDGES + i]; }
    else if (i < TOT_E)   { s = i - N_EDGES; d = s; }
    else return;
    float2 as = *(const float2*)&asrc[(size_t)s * 2];
    float2 ad = *(const float2*)&adst[(size_t)d * 2];
    float e0 = as.x + ad.x; e0 = e0 > 0.f ? e0 : NEG_SLOPE * e0;
    float e1 = as.y + ad.y; e1 = e1 > 0.f ? e1 : NEG_SLOPE * e1;
    int p = epos[i];
    *(float2*)&wbuf[(size_t)p * 2] = make_float2(__expf(e0), __expf(e1));
}

// ---------------- aggregation: round-2 proven loop (no pool fusion) ----------------
// lanes 0-31 process even CSR edges, lanes 32-63 odd edges; each lane holds float4
// (channels 4*hl .. 4*hl+3); halves combined via shfl_xor(32) at the end.

__global__ __launch_bounds__(256) void agg_kernel(const int* __restrict__ offs, const int* __restrict__ csr_src,
                                                  const float* __restrict__ wbuf,
                                                  const float* __restrict__ Hin, const float* __restrict__ bias,
                                                  float* __restrict__ Hout, int do_relu) {
    int wid  = (blockIdx.x * 256 + threadIdx.x) >> 6;
    int lane = threadIdx.x & 63;
    if (wid >= N_NODES) return;
    int beg = offs[wid], end = offs[wid + 1];
    int half = lane >> 5;
    int hl   = lane & 31;          // channels 4*hl .. 4*hl+3
    int head = hl >> 4;

    float den = 0.f;
    float4 acc = make_float4(0.f, 0.f, 0.f, 0.f);

    // unrolled by 2: up to 2 independent h-row gathers in flight per half-wave (4 per wave)
    for (int e = beg + half; e < end; e += 4) {
        int e1 = e + 2;
        bool v1 = e1 < end;
        int s0 = csr_src[e];
        int s1 = v1 ? csr_src[e1] : s0;
        float w0 = wbuf[(size_t)e * 2 + head];
        float w1 = v1 ? wbuf[(size_t)e1 * 2 + head] : 0.f;
        float4 h0 = *(const float4*)&Hin[(size_t)s0 * HC + hl * 4];
        float4 h1 = *(const float4*)&Hin[(size_t)s1 * HC + hl * 4];
        den += w0 + w1;
        acc.x = fmaf(w1, h1.x, fmaf(w0, h0.x, acc.x));
        acc.y = fmaf(w1, h1.y, fmaf(w0, h0.y, acc.y));
        acc.z = fmaf(w1, h1.z, fmaf(w0, h0.z, acc.z));
        acc.w = fmaf(w1, h1.w, fmaf(w0, h0.w, acc.w));
    }

    den   += __shfl_xor(den, 32);
    acc.x += __shfl_xor(acc.x, 32);
    acc.y += __shfl_xor(acc.y, 32);
    acc.z += __shfl_xor(acc.z, 32);
    acc.w += __shfl_xor(acc.w, 32);

    if (half == 0) {
        float inv = 1.0f / den;
        float4 b = *(const float4*)&bias[hl * 4];
        float4 o;
        o.x = fmaf(acc.x, inv, b.x);
        o.y = fmaf(acc.y, inv, b.y);
        o.z = fmaf(acc.z, inv, b.z);
        o.w = fmaf(acc.w, inv, b.w);
        if (do_relu) {
            o.x = fmaxf(o.x, 0.f); o.y = fmaxf(o.y, 0.f);
            o.z = fmaxf(o.z, 0.f); o.w = fmaxf(o.w, 0.f);
        }
        *(float4*)&Hout[(size_t)wid * HC + hl * 4] = o;
    }
}

// ---------------- mean pool (separate kernel; 8K atomics only) ----------------

__global__ __launch_bounds__(256) void pool_kernel(const float* __restrict__ H2, const int* __restrict__ counts,
                                                   float* __restrict__ out) {
    int g = blockIdx.x;
    int chunk = blockIdx.y;
    __shared__ int soff, scnt;
    if (threadIdx.x == 0) {
        int s = 0;
        for (int i = 0; i < g; ++i) s += counts[i];
        soff = s; scnt = counts[g];
    }
    __syncthreads();
    int start = soff, cnt = scnt;
    int r = threadIdx.x >> 7;
    int c = threadIdx.x & 127;
    float acc = 0.f;
    for (int v = chunk * 2 + r; v < cnt; v += 16)
        acc += H2[(size_t)(start + v) * HC + c];
    float inv = 1.0f / fmaxf((float)cnt, 1.0f);
    atomicAdd(&out[g * HC + c], acc * inv);
}

// ---------------- launch ----------------

extern "C" void kernel_launch(void* const* d_in, const int* in_sizes, int n_in,
                              void* d_out, int out_size, void* d_ws, size_t ws_size,
                              hipStream_t stream) {
    const float* x     = (const float*)d_in[0];
    const int*   ei    = (const int*)d_in[1];
    const int*   batch = (const int*)d_in[2];
    const float* W1    = (const float*)d_in[3];
    const float* a1s   = (const float*)d_in[4];
    const float* a1d   = (const float*)d_in[5];
    const float* b1    = (const float*)d_in[6];
    const float* W2    = (const float*)d_in[7];
    const float* a2s   = (const float*)d_in[8];
    const float* a2d   = (const float*)d_in[9];
    const float* b2    = (const float*)d_in[10];
    float* out = (float*)d_out;

    char* ws = (char*)d_ws;
    const size_t SZ_H = (size_t)N_NODES * HC * sizeof(float);   // 51.2 MB
    float* hA   = (float*)(ws);
    float* hB   = (float*)(ws + SZ_H);
    float* asrc = (float*)(ws + 2 * SZ_H);
    float* adst = asrc + (size_t)N_NODES * 2;
    float* wbuf = adst + (size_t)N_NODES * 2;                   // TOT_E * 2 floats
    unsigned short* wt1 = (unsigned short*)(wbuf + (size_t)TOT_E * 2);
    unsigned short* wt2 = wt1 + F_IN * HC;
    int*   deg  = (int*)(wt2 + F_IN * HC);
    int*   offs = deg + (N_NODES + 1);
    int*   cursor = offs + (N_NODES + 1);
    int*   csr  = cursor + N_NODES;
    int*   epos = csr + TOT_E;
    int*   bsum = epos + TOT_E;
    int*   boff = bsum + SCAN_NB;
    int*   counts = boff + SCAN_NB;

    hipMemsetAsync(deg, 0, (N_NODES + 1) * sizeof(int), stream);
    hipMemsetAsync(counts, 0, NGRAPH * sizeof(int), stream);
    hipMemsetAsync(out, 0, (size_t)out_size * sizeof(float), stream);

    int histBlocks = (TOT_E + 255) / 256;
    wtconv_kernel<<<(F_IN * HC + 255) / 256, 256, 0, stream>>>(W1, wt1);
    wtconv_kernel<<<(F_IN * HC + 255) / 256, 256, 0, stream>>>(W2, wt2);
    hist_kernel<<<histBlocks, 256, 0, stream>>>(ei, deg);
    counts_kernel<<<(N_NODES + 255) / 256, 256, 0, stream>>>(batch, counts);
    scan_partial<<<SCAN_NB, 256, 0, stream>>>(deg, bsum);
    scan_bsum<<<1, 512, 0, stream>>>(bsum, boff);
    scan_final<<<SCAN_NB, 256, 0, stream>>>(deg, boff, offs, cursor);
    scatter_kernel<<<histBlocks, 256, 0, stream>>>(ei, cursor, csr, epos);

    int gemmBlocks = (N_NODES + 63) / 64;
    int waveBlocks = (N_NODES + 3) / 4;

    // layer 1
    gemm_mfma<<<gemmBlocks, 256, 0, stream>>>(x, wt1, hA);
    alpha_kernel<<<waveBlocks, 256, 0, stream>>>(hA, a1s, a1d, asrc, adst);
    edgew_kernel<<<histBlocks, 256, 0, stream>>>(ei, epos, asrc, adst, wbuf);
    agg_kernel<<<waveBlocks, 256, 0, stream>>>(offs, csr, wbuf, hA, b1, hB, 1);

    // layer 2
    gemm_mfma<<<gemmBlocks, 256, 0, stream>>>(hB, wt2, hA);
    alpha_kernel<<<waveBlocks, 256, 0, stream>>>(hA, a2s, a2d, asrc, adst);
    edgew_kernel<<<histBlocks, 256, 0, stream>>>(ei, epos, asrc, adst, wbuf);
    agg_kernel<<<waveBlocks, 256, 0, stream>>>(offs, csr, wbuf, hA, b2, hB, 0);

    // pool
    pool_kernel<<<dim3(NGRAPH, 8), 256, 0, stream>>>(hB, counts, out);
}

// Round 6
// 501.591 us; speedup vs baseline: 2.5603x; 1.2318x over previous
//
#include <hip/hip_runtime.h>

#define N_NODES 100000
#define N_EDGES 1600000
#define F_IN    128
#define HC      128     // H * C
#define NGRAPH  64
#define NEG_SLOPE 0.2f

static constexpr int SCAN_NB = (N_NODES + 255) / 256;   // 391
static constexpr int TOT_E   = N_EDGES + N_NODES;       // with self loops

typedef __bf16 bf16x8 __attribute__((ext_vector_type(8)));
typedef float  f32x4  __attribute__((ext_vector_type(4)));

__device__ __forceinline__ unsigned short f2bf_rne(float f) {
    unsigned u = __float_as_uint(f);
    u += 0x7fffu + ((u >> 16) & 1u);
    return (unsigned short)(u >> 16);
}
__device__ __forceinline__ float bf2f(unsigned b) {        // low 16 bits used
    return __uint_as_float(b << 16);
}

// ---------------- CSR build ----------------

__global__ __launch_bounds__(256) void hist_kernel(const int* __restrict__ ei, int* __restrict__ deg) {
    int i = blockIdx.x * 256 + threadIdx.x;
    if (i < N_EDGES) {
        atomicAdd(&deg[ei[N_EDGES + i]], 1);      // dst of real edge
    } else if (i < TOT_E) {
        atomicAdd(&deg[i - N_EDGES], 1);          // self loop
    }
}

__global__ __launch_bounds__(256) void scan_partial(const int* __restrict__ deg, int* __restrict__ bsum) {
    int i = blockIdx.x * 256 + threadIdx.x;
    int d = (i < N_NODES) ? deg[i] : 0;
    for (int off = 32; off; off >>= 1) d += __shfl_down(d, off);
    __shared__ int wsum[4];
    int lane = threadIdx.x & 63, w = threadIdx.x >> 6;
    if (lane == 0) wsum[w] = d;
    __syncthreads();
    if (threadIdx.x == 0) bsum[blockIdx.x] = wsum[0] + wsum[1] + wsum[2] + wsum[3];
}

__global__ void scan_bsum(const int* __restrict__ bsum, int* __restrict__ boff) {
    __shared__ int sd[512];
    int t = threadIdx.x;
    int v = (t < SCAN_NB) ? bsum[t] : 0;
    sd[t] = v; __syncthreads();
    for (int off = 1; off < 512; off <<= 1) {
        int x = (t >= off) ? sd[t - off] : 0;
        __syncthreads();
        sd[t] += x;
        __syncthreads();
    }
    if (t < SCAN_NB) boff[t] = sd[t] - v;   // exclusive
}

__global__ __launch_bounds__(256) void scan_final(const int* __restrict__ deg, const int* __restrict__ boff,
                                                  int* __restrict__ offs, int* __restrict__ cursor) {
    __shared__ int sd[256];
    int t = threadIdx.x;
    int i = blockIdx.x * 256 + t;
    int d = (i < N_NODES) ? deg[i] : 0;
    sd[t] = d; __syncthreads();
    for (int off = 1; off < 256; off <<= 1) {
        int x = (t >= off) ? sd[t - off] : 0;
        __syncthreads();
        sd[t] += x;
        __syncthreads();
    }
    int incl = sd[t];
    int base = boff[blockIdx.x];
    if (i < N_NODES) {
        offs[i + 1] = base + incl;
        cursor[i]   = base + incl - d;
    }
    if (i == 0) offs[0] = 0;
}

__global__ __launch_bounds__(256) void scatter_kernel(const int* __restrict__ ei, int* __restrict__ cursor,
                                                      int* __restrict__ csr_src) {
    int i = blockIdx.x * 256 + threadIdx.x;
    int s, d;
    if (i < N_EDGES)      { s = ei[i]; d = ei[N_EDGES + i]; }
    else if (i < TOT_E)   { s = i - N_EDGES; d = s; }
    else return;
    int pos = atomicAdd(&cursor[d], 1);
    csr_src[pos] = s;
}

__global__ __launch_bounds__(256) void counts_kernel(const int* __restrict__ batch, int* __restrict__ counts) {
    __shared__ int loc[NGRAPH];
    int t = threadIdx.x;
    if (t < NGRAPH) loc[t] = 0;
    __syncthreads();
    int i = blockIdx.x * 256 + t;
    if (i < N_NODES) atomicAdd(&loc[batch[i]], 1);
    __syncthreads();
    if (t < NGRAPH && loc[t]) atomicAdd(&counts[t], loc[t]);
}

// ---------------- W -> bf16, fragment-ready layout Wt[k>>3][col][k&7] ----------------

__global__ __launch_bounds__(256) void wtconv_kernel(const float* __restrict__ W, unsigned short* __restrict__ Wt) {
    int i = blockIdx.x * 256 + threadIdx.x;
    if (i >= F_IN * HC) return;
    int k = i >> 7, col = i & 127;
    Wt[(size_t)(k >> 3) * (HC * 8) + col * 8 + (k & 7)] = f2bf_rne(W[i]);
}

// ---------------- GEMM: H = X @ W via MFMA bf16; output stored bf16 ----------------
// block = 256 (4 waves), tile = 64 rows x 128 cols. BF16IN: input rows are bf16.

template<bool BF16IN>
__global__ __launch_bounds__(256) void gemm_mfma(const void* __restrict__ Xv,
                                                 const unsigned short* __restrict__ Wt,
                                                 unsigned short* __restrict__ Hout) {
    __shared__ unsigned short A_lds[64 * F_IN];     // 16 KB
    int t = threadIdx.x;
    int lane = t & 63, wave = t >> 6;
    int wc = wave & 1, wr = wave >> 1;
    int base = blockIdx.x * 64;

    bf16x8 Bf[4][4];
    {
        int colb = wc * 64 + (lane & 15);
        int kbb  = lane >> 4;
#pragma unroll
        for (int ct = 0; ct < 4; ++ct)
#pragma unroll
            for (int ks = 0; ks < 4; ++ks) {
                int kb = kbb + 4 * ks;
                Bf[ct][ks] = *(const bf16x8*)&Wt[(size_t)kb * (HC * 8) + (colb + ct * 16) * 8];
            }
    }

#pragma unroll
    for (int it = 0; it < 8; ++it) {
        int i = t + it * 256;
        int row = i >> 5, c4 = i & 31, k0 = c4 * 4;
        uint2 pk; pk.x = 0; pk.y = 0;
        if (base + row < N_NODES) {
            if (BF16IN) {
                pk = ((const uint2*)Xv)[(size_t)(base + row) * 32 + c4];   // 4 ch bf16-packed
            } else {
                float4 v = ((const float4*)Xv)[(size_t)(base + row) * 32 + c4];
                pk.x = (unsigned)f2bf_rne(v.x) | ((unsigned)f2bf_rne(v.y) << 16);
                pk.y = (unsigned)f2bf_rne(v.z) | ((unsigned)f2bf_rne(v.w) << 16);
            }
        }
        int byte = row * 256 + (((k0 >> 3) ^ (row & 7)) << 4) + (k0 & 4) * 2;
        *(uint2*)((char*)A_lds + byte) = pk;
    }
    __syncthreads();

    f32x4 acc[2][4] = {};
#pragma unroll
    for (int ks = 0; ks < 4; ++ks) {
        bf16x8 Af[2];
#pragma unroll
        for (int r = 0; r < 2; ++r) {
            int row = wr * 32 + r * 16 + (lane & 15);
            int kb  = ks * 4 + (lane >> 4);
            int byte = row * 256 + ((kb ^ (row & 7)) << 4);
            Af[r] = *(const bf16x8*)((const char*)A_lds + byte);
        }
#pragma unroll
        for (int ct = 0; ct < 4; ++ct) {
            acc[0][ct] = __builtin_amdgcn_mfma_f32_16x16x32_bf16(Af[0], Bf[ct][ks], acc[0][ct], 0, 0, 0);
            acc[1][ct] = __builtin_amdgcn_mfma_f32_16x16x32_bf16(Af[1], Bf[ct][ks], acc[1][ct], 0, 0, 0);
        }
    }

#pragma unroll
    for (int r = 0; r < 2; ++r) {
        int row0 = base + wr * 32 + r * 16 + (lane >> 4) * 4;
#pragma unroll
        for (int reg = 0; reg < 4; ++reg) {
            int row = row0 + reg;
            if (row < N_NODES) {
#pragma unroll
                for (int ct = 0; ct < 4; ++ct) {
                    int col = wc * 64 + ct * 16 + (lane & 15);
                    Hout[(size_t)row * HC + col] = f2bf_rne(acc[r][ct][reg]);
                }
            }
        }
    }
}

// ---------------- per-node attention logits (bf16 h) ----------------

__global__ __launch_bounds__(256) void alpha_kernel(const unsigned short* __restrict__ H,
                                                    const float* __restrict__ a_src, const float* __restrict__ a_dst,
                                                    float* __restrict__ asrc, float* __restrict__ adst) {
    int wid  = (blockIdx.x * 256 + threadIdx.x) >> 6;
    int lane = threadIdx.x & 63;
    if (wid >= N_NODES) return;
    unsigned hv = *(const unsigned*)&H[(size_t)wid * HC + lane * 2];
    float h0 = bf2f(hv & 0xffffu), h1 = bf2f(hv >> 16);
    int ch = lane * 2;
    float2 as = *(const float2*)&a_src[ch];
    float2 ad = *(const float2*)&a_dst[ch];
    float ps = h0 * as.x + h1 * as.y;
    float pd = h0 * ad.x + h1 * ad.y;
    for (int off = 16; off; off >>= 1) {
        ps += __shfl_xor(ps, off);
        pd += __shfl_xor(pd, off);
    }
    int head = lane >> 5;
    if ((lane & 31) == 0) {
        asrc[wid * 2 + head] = ps;
        adst[wid * 2 + head] = pd;
    }
}

// ---------------- aggregation: proven half-wave loop, weights inline, bf16 h ----------------
// lanes 0-31 process even CSR edges, lanes 32-63 odd; each lane holds 4 channels
// (4*hl .. 4*hl+3); halves combined via shfl_xor(32). asrc is an 800 KB L2-resident table.

__global__ __launch_bounds__(256) void agg_kernel(const int* __restrict__ offs, const int* __restrict__ csr_src,
                                                  const float* __restrict__ asrc, const float* __restrict__ adst,
                                                  const unsigned short* __restrict__ Hin,
                                                  const float* __restrict__ bias,
                                                  unsigned short* __restrict__ Hout, int do_relu) {
    int wid  = (blockIdx.x * 256 + threadIdx.x) >> 6;
    int lane = threadIdx.x & 63;
    if (wid >= N_NODES) return;
    int beg = offs[wid], end = offs[wid + 1];
    int half = lane >> 5;
    int hl   = lane & 31;          // channels 4*hl .. 4*hl+3
    int head = hl >> 4;
    float2 adv = *(const float2*)&adst[(size_t)wid * 2];
    float madst = head ? adv.y : adv.x;
    const float2* av = (const float2*)asrc;

    float den = 0.f;
    float4 acc = make_float4(0.f, 0.f, 0.f, 0.f);

    for (int e = beg + half; e < end; e += 4) {
        int en = e + 2;
        bool v1 = en < end;
        int s0 = csr_src[e];
        int s1 = v1 ? csr_src[en] : s0;
        float2 a0 = av[s0];
        float2 a1 = av[s1];
        uint2 g0 = *(const uint2*)&Hin[(size_t)s0 * HC + hl * 4];
        uint2 g1 = *(const uint2*)&Hin[(size_t)s1 * HC + hl * 4];
        float l0 = (head ? a0.y : a0.x) + madst; l0 = l0 > 0.f ? l0 : NEG_SLOPE * l0;
        float l1 = (head ? a1.y : a1.x) + madst; l1 = l1 > 0.f ? l1 : NEG_SLOPE * l1;
        float w0 = __expf(l0);
        float w1 = v1 ? __expf(l1) : 0.f;
        den += w0 + w1;
        acc.x = fmaf(w1, bf2f(g1.x & 0xffffu), fmaf(w0, bf2f(g0.x & 0xffffu), acc.x));
        acc.y = fmaf(w1, bf2f(g1.x >> 16),     fmaf(w0, bf2f(g0.x >> 16),     acc.y));
        acc.z = fmaf(w1, bf2f(g1.y & 0xffffu), fmaf(w0, bf2f(g0.y & 0xffffu), acc.z));
        acc.w = fmaf(w1, bf2f(g1.y >> 16),     fmaf(w0, bf2f(g0.y >> 16),     acc.w));
    }

    den   += __shfl_xor(den, 32);
    acc.x += __shfl_xor(acc.x, 32);
    acc.y += __shfl_xor(acc.y, 32);
    acc.z += __shfl_xor(acc.z, 32);
    acc.w += __shfl_xor(acc.w, 32);

    if (half == 0) {
        float inv = 1.0f / den;
        float4 b = *(const float4*)&bias[hl * 4];
        float o0 = fmaf(acc.x, inv, b.x);
        float o1 = fmaf(acc.y, inv, b.y);
        float o2 = fmaf(acc.z, inv, b.z);
        float o3 = fmaf(acc.w, inv, b.w);
        if (do_relu) {
            o0 = fmaxf(o0, 0.f); o1 = fmaxf(o1, 0.f);
            o2 = fmaxf(o2, 0.f); o3 = fmaxf(o3, 0.f);
        }
        uint2 st;
        st.x = (unsigned)f2bf_rne(o0) | ((unsigned)f2bf_rne(o1) << 16);
        st.y = (unsigned)f2bf_rne(o2) | ((unsigned)f2bf_rne(o3) << 16);
        *(uint2*)&Hout[(size_t)wid * HC + hl * 4] = st;
    }
}

// ---------------- mean pool (bf16 input; 8K atomics only) ----------------

__global__ __launch_bounds__(256) void pool_kernel(const unsigned short* __restrict__ H2,
                                                   const int* __restrict__ counts,
                                                   float* __restrict__ out) {
    int g = blockIdx.x;
    int chunk = blockIdx.y;
    __shared__ int soff, scnt;
    if (threadIdx.x == 0) {
        int s = 0;
        for (int i = 0; i < g; ++i) s += counts[i];
        soff = s; scnt = counts[g];
    }
    __syncthreads();
    int start = soff, cnt = scnt;
    int r = threadIdx.x >> 7;
    int c = threadIdx.x & 127;
    float acc = 0.f;
    for (int v = chunk * 2 + r; v < cnt; v += 16)
        acc += bf2f((unsigned)H2[(size_t)(start + v) * HC + c]);
    float inv = 1.0f / fmaxf((float)cnt, 1.0f);
    atomicAdd(&out[g * HC + c], acc * inv);
}

// ---------------- launch ----------------

extern "C" void kernel_launch(void* const* d_in, const int* in_sizes, int n_in,
                              void* d_out, int out_size, void* d_ws, size_t ws_size,
                              hipStream_t stream) {
    const float* x     = (const float*)d_in[0];
    const int*   ei    = (const int*)d_in[1];
    const int*   batch = (const int*)d_in[2];
    const float* W1    = (const float*)d_in[3];
    const float* a1s   = (const float*)d_in[4];
    const float* a1d   = (const float*)d_in[5];
    const float* b1    = (const float*)d_in[6];
    const float* W2    = (const float*)d_in[7];
    const float* a2s   = (const float*)d_in[8];
    const float* a2d   = (const float*)d_in[9];
    const float* b2    = (const float*)d_in[10];
    float* out = (float*)d_out;

    char* ws = (char*)d_ws;
    const size_t NH = (size_t)N_NODES * HC;                 // elements per h buffer
    unsigned short* hA = (unsigned short*)ws;               // 25.6 MB
    unsigned short* hB = hA + NH;                           // 25.6 MB
    float* asrc = (float*)(hB + NH);
    float* adst = asrc + (size_t)N_NODES * 2;
    unsigned short* wt1 = (unsigned short*)(adst + (size_t)N_NODES * 2);
    unsigned short* wt2 = wt1 + F_IN * HC;
    int*   deg  = (int*)(wt2 + F_IN * HC);
    int*   offs = deg + (N_NODES + 1);
    int*   cursor = offs + (N_NODES + 1);
    int*   csr  = cursor + N_NODES;
    int*   bsum = csr + TOT_E;
    int*   boff = bsum + SCAN_NB;
    int*   counts = boff + SCAN_NB;

    hipMemsetAsync(deg, 0, (N_NODES + 1) * sizeof(int), stream);
    hipMemsetAsync(counts, 0, NGRAPH * sizeof(int), stream);
    hipMemsetAsync(out, 0, (size_t)out_size * sizeof(float), stream);

    int histBlocks = (TOT_E + 255) / 256;
    wtconv_kernel<<<(F_IN * HC + 255) / 256, 256, 0, stream>>>(W1, wt1);
    wtconv_kernel<<<(F_IN * HC + 255) / 256, 256, 0, stream>>>(W2, wt2);
    hist_kernel<<<histBlocks, 256, 0, stream>>>(ei, deg);
    counts_kernel<<<(N_NODES + 255) / 256, 256, 0, stream>>>(batch, counts);
    scan_partial<<<SCAN_NB, 256, 0, stream>>>(deg, bsum);
    scan_bsum<<<1, 512, 0, stream>>>(bsum, boff);
    scan_final<<<SCAN_NB, 256, 0, stream>>>(deg, boff, offs, cursor);
    scatter_kernel<<<histBlocks, 256, 0, stream>>>(ei, cursor, csr);

    int gemmBlocks = (N_NODES + 63) / 64;
    int waveBlocks = (N_NODES + 3) / 4;

    // layer 1
    gemm_mfma<false><<<gemmBlocks, 256, 0, stream>>>(x, wt1, hA);
    alpha_kernel<<<waveBlocks, 256, 0, stream>>>(hA, a1s, a1d, asrc, adst);
    agg_kernel<<<waveBlocks, 256, 0, stream>>>(offs, csr, asrc, adst, hA, b1, hB, 1);

    // layer 2
    gemm_mfma<true><<<gemmBlocks, 256, 0, stream>>>(hB, wt2, hA);
    alpha_kernel<<<waveBlocks, 256, 0, stream>>>(hA, a2s, a2d, asrc, adst);
    agg_kernel<<<waveBlocks, 256, 0, stream>>>(offs, csr, asrc, adst, hA, b2, hB, 0);

    // pool
    pool_kernel<<<dim3(NGRAPH, 8), 256, 0, stream>>>(hB, counts, out);
}

// Round 7
// 404.909 us; speedup vs baseline: 3.1716x; 1.2388x over previous
//
#include <hip/hip_runtime.h>

#define N_NODES 100000
#define N_EDGES 1600000
#define F_IN    128
#define HC      128     // H * C
#define NGRAPH  64
#define NEG_SLOPE 0.2f

static constexpr int SCAN_NB = (N_NODES + 255) / 256;   // 391
static constexpr int TOT_E   = N_EDGES + N_NODES;       // with self loops

// CSR binned build
#define CHUNK  2048
#define NBLK   831            // ceil(TOT_E / CHUNK)
#define NBUCK  196            // ceil(N_NODES / 512), bucket = dst >> 9

typedef __bf16 bf16x8 __attribute__((ext_vector_type(8)));
typedef float  f32x4  __attribute__((ext_vector_type(4)));

__device__ __forceinline__ unsigned short f2bf_rne(float f) {
    unsigned u = __float_as_uint(f);
    u += 0x7fffu + ((u >> 16) & 1u);
    return (unsigned short)(u >> 16);
}
__device__ __forceinline__ float bf2f(unsigned b) {        // low 16 bits used
    return __uint_as_float(b << 16);
}

// ---------------- binned partition: edges -> block-local bucket-grouped pairs ----------------
// Also accumulates the global degree histogram (replaces hist_kernel).

__global__ __launch_bounds__(256) void binpart_kernel(const int* __restrict__ ei,
                                                      int* __restrict__ deg,
                                                      uint2* __restrict__ pairs,
                                                      int* __restrict__ seg_start,
                                                      int* __restrict__ seg_cnt) {
    __shared__ int cnt[NBUCK];
    __shared__ int sc[256];
    int t = threadIdx.x, blk = blockIdx.x;
    long base = (long)blk * CHUNK;

    for (int j = t; j < NBUCK; j += 256) cnt[j] = 0;
    __syncthreads();

    // phase A: count buckets + global degree
    for (int j = t; j < CHUNK; j += 256) {
        long i = base + j;
        int d = -1;
        if (i < N_EDGES)    d = ei[N_EDGES + i];
        else if (i < TOT_E) d = (int)(i - N_EDGES);
        if (d >= 0) {
            atomicAdd(&cnt[d >> 9], 1);
            atomicAdd(&deg[d], 1);
        }
    }
    __syncthreads();

    // phase B: block-local exclusive scan of bucket counts
    sc[t] = (t < NBUCK) ? cnt[t] : 0;
    __syncthreads();
    for (int off = 1; off < 256; off <<= 1) {
        int v = (t >= off) ? sc[t - off] : 0;
        __syncthreads();
        sc[t] += v;
        __syncthreads();
    }
    if (t < NBUCK) {
        int c = cnt[t], st = sc[t] - c;
        seg_start[(size_t)blk * NBUCK + t] = st;
        seg_cnt[(size_t)blk * NBUCK + t]   = c;
        cnt[t] = st;                        // reuse as cursor
    }
    __syncthreads();

    // phase C: scatter edges bucket-grouped into the block's own 16 KB region
    for (int j = t; j < CHUNK; j += 256) {
        long i = base + j;
        int s = -1, d = -1;
        if (i < N_EDGES)    { s = ei[i]; d = ei[N_EDGES + i]; }
        else if (i < TOT_E) { s = (int)(i - N_EDGES); d = s; }
        if (d >= 0) {
            int pos = atomicAdd(&cnt[d >> 9], 1);
            pairs[base + pos] = make_uint2((unsigned)s, (unsigned)d);
        }
    }
}

// ---------------- degree scan (unchanged) ----------------

__global__ __launch_bounds__(256) void scan_partial(const int* __restrict__ deg, int* __restrict__ bsum) {
    int i = blockIdx.x * 256 + threadIdx.x;
    int d = (i < N_NODES) ? deg[i] : 0;
    for (int off = 32; off; off >>= 1) d += __shfl_down(d, off);
    __shared__ int wsum[4];
    int lane = threadIdx.x & 63, w = threadIdx.x >> 6;
    if (lane == 0) wsum[w] = d;
    __syncthreads();
    if (threadIdx.x == 0) bsum[blockIdx.x] = wsum[0] + wsum[1] + wsum[2] + wsum[3];
}

__global__ void scan_bsum(const int* __restrict__ bsum, int* __restrict__ boff) {
    __shared__ int sd[512];
    int t = threadIdx.x;
    int v = (t < SCAN_NB) ? bsum[t] : 0;
    sd[t] = v; __syncthreads();
    for (int off = 1; off < 512; off <<= 1) {
        int x = (t >= off) ? sd[t - off] : 0;
        __syncthreads();
        sd[t] += x;
        __syncthreads();
    }
    if (t < SCAN_NB) boff[t] = sd[t] - v;   // exclusive
}

__global__ __launch_bounds__(256) void scan_final(const int* __restrict__ deg, const int* __restrict__ boff,
                                                  int* __restrict__ offs) {
    __shared__ int sd[256];
    int t = threadIdx.x;
    int i = blockIdx.x * 256 + t;
    int d = (i < N_NODES) ? deg[i] : 0;
    sd[t] = d; __syncthreads();
    for (int off = 1; off < 256; off <<= 1) {
        int x = (t >= off) ? sd[t - off] : 0;
        __syncthreads();
        sd[t] += x;
        __syncthreads();
    }
    if (i < N_NODES) offs[i + 1] = boff[blockIdx.x] + sd[t];
    if (i == 0) offs[0] = 0;
}

// ---------------- per-bucket exact scatter (one block owns one 512-node csr window) ----------------

__global__ __launch_bounds__(1024) void bucket_scatter(const uint2* __restrict__ pairs,
                                                       const int* __restrict__ seg_start,
                                                       const int* __restrict__ seg_cnt,
                                                       const int* __restrict__ offs,
                                                       int* __restrict__ csr_src) {
    int b = blockIdx.x, t = threadIdx.x;
    int nodeBase = b << 9;
    __shared__ int cur[512];
    __shared__ int pref[NBLK];     // inclusive prefix of this bucket's segment counts
    __shared__ int sstart[NBLK];

    if (t < 512) {
        int n = nodeBase + t;
        cur[t] = (n < N_NODES) ? offs[n] : 0;
    }
    for (int j = t; j < NBLK; j += 1024) {
        pref[j]   = seg_cnt[(size_t)j * NBUCK + b];
        sstart[j] = seg_start[(size_t)j * NBUCK + b];
    }
    __syncthreads();
    for (int off = 1; off < NBLK; off <<= 1) {
        int v = 0;
        if (t < NBLK && t >= off) v = pref[t - off];
        __syncthreads();
        if (t < NBLK) pref[t] += v;
        __syncthreads();
    }
    int M = pref[NBLK - 1];

    for (int j = t; j < M; j += 1024) {
        int lo = 0, hi = NBLK - 1;                 // smallest seg with pref[seg] > j
        while (lo < hi) { int mid = (lo + hi) >> 1; if (pref[mid] > j) hi = mid; else lo = mid + 1; }
        int within = j - (lo ? pref[lo - 1] : 0);
        uint2 e = pairs[(size_t)lo * CHUNK + sstart[lo] + within];
        int pos = atomicAdd(&cur[(int)e.y - nodeBase], 1);
        csr_src[pos] = (int)e.x;
    }
}

__global__ __launch_bounds__(256) void counts_kernel(const int* __restrict__ batch, int* __restrict__ counts) {
    __shared__ int loc[NGRAPH];
    int t = threadIdx.x;
    if (t < NGRAPH) loc[t] = 0;
    __syncthreads();
    int i = blockIdx.x * 256 + t;
    if (i < N_NODES) atomicAdd(&loc[batch[i]], 1);
    __syncthreads();
    if (t < NGRAPH && loc[t]) atomicAdd(&counts[t], loc[t]);
}

// ---------------- W -> bf16, fragment-ready layout Wt[k>>3][col][k&7] ----------------

__global__ __launch_bounds__(256) void wtconv_kernel(const float* __restrict__ W, unsigned short* __restrict__ Wt) {
    int i = blockIdx.x * 256 + threadIdx.x;
    if (i >= F_IN * HC) return;
    int k = i >> 7, col = i & 127;
    Wt[(size_t)(k >> 3) * (HC * 8) + col * 8 + (k & 7)] = f2bf_rne(W[i]);
}

// ---------------- GEMM: H = X @ W via MFMA bf16; output stored bf16 ----------------

template<bool BF16IN>
__global__ __launch_bounds__(256) void gemm_mfma(const void* __restrict__ Xv,
                                                 const unsigned short* __restrict__ Wt,
                                                 unsigned short* __restrict__ Hout) {
    __shared__ unsigned short A_lds[64 * F_IN];     // 16 KB
    int t = threadIdx.x;
    int lane = t & 63, wave = t >> 6;
    int wc = wave & 1, wr = wave >> 1;
    int base = blockIdx.x * 64;

    bf16x8 Bf[4][4];
    {
        int colb = wc * 64 + (lane & 15);
        int kbb  = lane >> 4;
#pragma unroll
        for (int ct = 0; ct < 4; ++ct)
#pragma unroll
            for (int ks = 0; ks < 4; ++ks) {
                int kb = kbb + 4 * ks;
                Bf[ct][ks] = *(const bf16x8*)&Wt[(size_t)kb * (HC * 8) + (colb + ct * 16) * 8];
            }
    }

#pragma unroll
    for (int it = 0; it < 8; ++it) {
        int i = t + it * 256;
        int row = i >> 5, c4 = i & 31, k0 = c4 * 4;
        uint2 pk; pk.x = 0; pk.y = 0;
        if (base + row < N_NODES) {
            if (BF16IN) {
                pk = ((const uint2*)Xv)[(size_t)(base + row) * 32 + c4];
            } else {
                float4 v = ((const float4*)Xv)[(size_t)(base + row) * 32 + c4];
                pk.x = (unsigned)f2bf_rne(v.x) | ((unsigned)f2bf_rne(v.y) << 16);
                pk.y = (unsigned)f2bf_rne(v.z) | ((unsigned)f2bf_rne(v.w) << 16);
            }
        }
        int byte = row * 256 + (((k0 >> 3) ^ (row & 7)) << 4) + (k0 & 4) * 2;
        *(uint2*)((char*)A_lds + byte) = pk;
    }
    __syncthreads();

    f32x4 acc[2][4] = {};
#pragma unroll
    for (int ks = 0; ks < 4; ++ks) {
        bf16x8 Af[2];
#pragma unroll
        for (int r = 0; r < 2; ++r) {
            int row = wr * 32 + r * 16 + (lane & 15);
            int kb  = ks * 4 + (lane >> 4);
            int byte = row * 256 + ((kb ^ (row & 7)) << 4);
            Af[r] = *(const bf16x8*)((const char*)A_lds + byte);
        }
#pragma unroll
        for (int ct = 0; ct < 4; ++ct) {
            acc[0][ct] = __builtin_amdgcn_mfma_f32_16x16x32_bf16(Af[0], Bf[ct][ks], acc[0][ct], 0, 0, 0);
            acc[1][ct] = __builtin_amdgcn_mfma_f32_16x16x32_bf16(Af[1], Bf[ct][ks], acc[1][ct], 0, 0, 0);
        }
    }

#pragma unroll
    for (int r = 0; r < 2; ++r) {
        int row0 = base + wr * 32 + r * 16 + (lane >> 4) * 4;
#pragma unroll
        for (int reg = 0; reg < 4; ++reg) {
            int row = row0 + reg;
            if (row < N_NODES) {
#pragma unroll
                for (int ct = 0; ct < 4; ++ct) {
                    int col = wc * 64 + ct * 16 + (lane & 15);
                    Hout[(size_t)row * HC + col] = f2bf_rne(acc[r][ct][reg]);
                }
            }
        }
    }
}

// ---------------- per-node attention logits (bf16 h) ----------------

__global__ __launch_bounds__(256) void alpha_kernel(const unsigned short* __restrict__ H,
                                                    const float* __restrict__ a_src, const float* __restrict__ a_dst,
                                                    float* __restrict__ asrc, float* __restrict__ adst) {
    int wid  = (blockIdx.x * 256 + threadIdx.x) >> 6;
    int lane = threadIdx.x & 63;
    if (wid >= N_NODES) return;
    unsigned hv = *(const unsigned*)&H[(size_t)wid * HC + lane * 2];
    float h0 = bf2f(hv & 0xffffu), h1 = bf2f(hv >> 16);
    int ch = lane * 2;
    float2 as = *(const float2*)&a_src[ch];
    float2 ad = *(const float2*)&a_dst[ch];
    float ps = h0 * as.x + h1 * as.y;
    float pd = h0 * ad.x + h1 * ad.y;
    for (int off = 16; off; off >>= 1) {
        ps += __shfl_xor(ps, off);
        pd += __shfl_xor(pd, off);
    }
    int head = lane >> 5;
    if ((lane & 31) == 0) {
        asrc[wid * 2 + head] = ps;
        adst[wid * 2 + head] = pd;
    }
}

// ---------------- aggregation: half-wave loop, weights inline, bf16 h ----------------

__global__ __launch_bounds__(256) void agg_kernel(const int* __restrict__ offs, const int* __restrict__ csr_src,
                                                  const float* __restrict__ asrc, const float* __restrict__ adst,
                                                  const unsigned short* __restrict__ Hin,
                                                  const float* __restrict__ bias,
                                                  unsigned short* __restrict__ Hout, int do_relu) {
    int wid  = (blockIdx.x * 256 + threadIdx.x) >> 6;
    int lane = threadIdx.x & 63;
    if (wid >= N_NODES) return;
    int beg = offs[wid], end = offs[wid + 1];
    int half = lane >> 5;
    int hl   = lane & 31;          // channels 4*hl .. 4*hl+3
    int head = hl >> 4;
    float2 adv = *(const float2*)&adst[(size_t)wid * 2];
    float madst = head ? adv.y : adv.x;
    const float2* av = (const float2*)asrc;

    float den = 0.f;
    float4 acc = make_float4(0.f, 0.f, 0.f, 0.f);

    for (int e = beg + half; e < end; e += 4) {
        int en = e + 2;
        bool v1 = en < end;
        int s0 = csr_src[e];
        int s1 = v1 ? csr_src[en] : s0;
        float2 a0 = av[s0];
        float2 a1 = av[s1];
        uint2 g0 = *(const uint2*)&Hin[(size_t)s0 * HC + hl * 4];
        uint2 g1 = *(const uint2*)&Hin[(size_t)s1 * HC + hl * 4];
        float l0 = (head ? a0.y : a0.x) + madst; l0 = l0 > 0.f ? l0 : NEG_SLOPE * l0;
        float l1 = (head ? a1.y : a1.x) + madst; l1 = l1 > 0.f ? l1 : NEG_SLOPE * l1;
        float w0 = __expf(l0);
        float w1 = v1 ? __expf(l1) : 0.f;
        den += w0 + w1;
        acc.x = fmaf(w1, bf2f(g1.x & 0xffffu), fmaf(w0, bf2f(g0.x & 0xffffu), acc.x));
        acc.y = fmaf(w1, bf2f(g1.x >> 16),     fmaf(w0, bf2f(g0.x >> 16),     acc.y));
        acc.z = fmaf(w1, bf2f(g1.y & 0xffffu), fmaf(w0, bf2f(g0.y & 0xffffu), acc.z));
        acc.w = fmaf(w1, bf2f(g1.y >> 16),     fmaf(w0, bf2f(g0.y >> 16),     acc.w));
    }

    den   += __shfl_xor(den, 32);
    acc.x += __shfl_xor(acc.x, 32);
    acc.y += __shfl_xor(acc.y, 32);
    acc.z += __shfl_xor(acc.z, 32);
    acc.w += __shfl_xor(acc.w, 32);

    if (half == 0) {
        float inv = 1.0f / den;
        float4 b = *(const float4*)&bias[hl * 4];
        float o0 = fmaf(acc.x, inv, b.x);
        float o1 = fmaf(acc.y, inv, b.y);
        float o2 = fmaf(acc.z, inv, b.z);
        float o3 = fmaf(acc.w, inv, b.w);
        if (do_relu) {
            o0 = fmaxf(o0, 0.f); o1 = fmaxf(o1, 0.f);
            o2 = fmaxf(o2, 0.f); o3 = fmaxf(o3, 0.f);
        }
        uint2 st;
        st.x = (unsigned)f2bf_rne(o0) | ((unsigned)f2bf_rne(o1) << 16);
        st.y = (unsigned)f2bf_rne(o2) | ((unsigned)f2bf_rne(o3) << 16);
        *(uint2*)&Hout[(size_t)wid * HC + hl * 4] = st;
    }
}

// ---------------- mean pool (bf16 input; 8K atomics only) ----------------

__global__ __launch_bounds__(256) void pool_kernel(const unsigned short* __restrict__ H2,
                                                   const int* __restrict__ counts,
                                                   float* __restrict__ out) {
    int g = blockIdx.x;
    int chunk = blockIdx.y;
    __shared__ int soff, scnt;
    if (threadIdx.x == 0) {
        int s = 0;
        for (int i = 0; i < g; ++i) s += counts[i];
        soff = s; scnt = counts[g];
    }
    __syncthreads();
    int start = soff, cnt = scnt;
    int r = threadIdx.x >> 7;
    int c = threadIdx.x & 127;
    float acc = 0.f;
    for (int v = chunk * 2 + r; v < cnt; v += 16)
        acc += bf2f((unsigned)H2[(size_t)(start + v) * HC + c]);
    float inv = 1.0f / fmaxf((float)cnt, 1.0f);
    atomicAdd(&out[g * HC + c], acc * inv);
}

// ---------------- launch ----------------

extern "C" void kernel_launch(void* const* d_in, const int* in_sizes, int n_in,
                              void* d_out, int out_size, void* d_ws, size_t ws_size,
                              hipStream_t stream) {
    const float* x     = (const float*)d_in[0];
    const int*   ei    = (const int*)d_in[1];
    const int*   batch = (const int*)d_in[2];
    const float* W1    = (const float*)d_in[3];
    const float* a1s   = (const float*)d_in[4];
    const float* a1d   = (const float*)d_in[5];
    const float* b1    = (const float*)d_in[6];
    const float* W2    = (const float*)d_in[7];
    const float* a2s   = (const float*)d_in[8];
    const float* a2d   = (const float*)d_in[9];
    const float* b2    = (const float*)d_in[10];
    float* out = (float*)d_out;

    char* ws = (char*)d_ws;
    const size_t NH = (size_t)N_NODES * HC;                 // elements per h buffer
    unsigned short* hA = (unsigned short*)ws;               // 25.6 MB
    unsigned short* hB = hA + NH;                           // 25.6 MB
    uint2* pairs = (uint2*)(hB + NH);                       // NBLK*CHUNK*8 = 13.6 MB
    float* asrc = (float*)(pairs + (size_t)NBLK * CHUNK);
    float* adst = asrc + (size_t)N_NODES * 2;
    unsigned short* wt1 = (unsigned short*)(adst + (size_t)N_NODES * 2);
    unsigned short* wt2 = wt1 + F_IN * HC;
    int*   deg  = (int*)(wt2 + F_IN * HC);
    int*   offs = deg + (N_NODES + 1);
    int*   csr  = offs + (N_NODES + 1);
    int*   seg_start = csr + TOT_E;
    int*   seg_cnt   = seg_start + (size_t)NBLK * NBUCK;
    int*   bsum = seg_cnt + (size_t)NBLK * NBUCK;
    int*   boff = bsum + SCAN_NB;
    int*   counts = boff + SCAN_NB;

    hipMemsetAsync(deg, 0, (N_NODES + 1) * sizeof(int), stream);
    hipMemsetAsync(counts, 0, NGRAPH * sizeof(int), stream);
    hipMemsetAsync(out, 0, (size_t)out_size * sizeof(float), stream);

    wtconv_kernel<<<(F_IN * HC + 255) / 256, 256, 0, stream>>>(W1, wt1);
    wtconv_kernel<<<(F_IN * HC + 255) / 256, 256, 0, stream>>>(W2, wt2);
    counts_kernel<<<(N_NODES + 255) / 256, 256, 0, stream>>>(batch, counts);

    // CSR build: bin-partition -> degree scan -> per-bucket exact scatter
    binpart_kernel<<<NBLK, 256, 0, stream>>>(ei, deg, pairs, seg_start, seg_cnt);
    scan_partial<<<SCAN_NB, 256, 0, stream>>>(deg, bsum);
    scan_bsum<<<1, 512, 0, stream>>>(bsum, boff);
    scan_final<<<SCAN_NB, 256, 0, stream>>>(deg, boff, offs);
    bucket_scatter<<<NBUCK, 1024, 0, stream>>>(pairs, seg_start, seg_cnt, offs, csr);

    int gemmBlocks = (N_NODES + 63) / 64;
    int waveBlocks = (N_NODES + 3) / 4;

    // layer 1
    gemm_mfma<false><<<gemmBlocks, 256, 0, stream>>>(x, wt1, hA);
    alpha_kernel<<<waveBlocks, 256, 0, stream>>>(hA, a1s, a1d, asrc, adst);
    agg_kernel<<<waveBlocks, 256, 0, stream>>>(offs, csr, asrc, adst, hA, b1, hB, 1);

    // layer 2
    gemm_mfma<true><<<gemmBlocks, 256, 0, stream>>>(hB, wt2, hA);
    alpha_kernel<<<waveBlocks, 256, 0, stream>>>(hA, a2s, a2d, asrc, adst);
    agg_kernel<<<waveBlocks, 256, 0, stream>>>(offs, csr, asrc, adst, hA, b2, hB, 0);

    // pool
    pool_kernel<<<dim3(NGRAPH, 8), 256, 0, stream>>>(hB, counts, out);
}

// Round 8
// 355.909 us; speedup vs baseline: 3.6083x; 1.1377x over previous
//
#include <hip/hip_runtime.h>

#define N_NODES 100000
#define N_EDGES 1600000
#define F_IN    128
#define HC      128     // H * C
#define NGRAPH  64
#define NEG_SLOPE 0.2f

static constexpr int SCAN_NB = (N_NODES + 255) / 256;   // 391
static constexpr int TOT_E   = N_EDGES + N_NODES;       // with self loops

// CSR binned build
#define CHUNK  2048
#define NBLK   831            // ceil(TOT_E / CHUNK)
#define NBUCK  196            // ceil(N_NODES / 512), bucket = dst >> 9

typedef __bf16 bf16x8 __attribute__((ext_vector_type(8)));
typedef float  f32x4  __attribute__((ext_vector_type(4)));

__device__ __forceinline__ unsigned short f2bf_rne(float f) {
    unsigned u = __float_as_uint(f);
    u += 0x7fffu + ((u >> 16) & 1u);
    return (unsigned short)(u >> 16);
}
__device__ __forceinline__ float bf2f(unsigned b) {        // low 16 bits used
    return __uint_as_float(b << 16);
}

// ---------------- binned partition: edges -> block-local bucket-grouped pairs ----------------

__global__ __launch_bounds__(256) void binpart_kernel(const int* __restrict__ ei,
                                                      int* __restrict__ deg,
                                                      uint2* __restrict__ pairs,
                                                      int* __restrict__ seg_start,
                                                      int* __restrict__ seg_cnt) {
    __shared__ int cnt[NBUCK];
    __shared__ int sc[256];
    int t = threadIdx.x, blk = blockIdx.x;
    long base = (long)blk * CHUNK;

    for (int j = t; j < NBUCK; j += 256) cnt[j] = 0;
    __syncthreads();

    for (int j = t; j < CHUNK; j += 256) {
        long i = base + j;
        int d = -1;
        if (i < N_EDGES)    d = ei[N_EDGES + i];
        else if (i < TOT_E) d = (int)(i - N_EDGES);
        if (d >= 0) {
            atomicAdd(&cnt[d >> 9], 1);
            atomicAdd(&deg[d], 1);
        }
    }
    __syncthreads();

    sc[t] = (t < NBUCK) ? cnt[t] : 0;
    __syncthreads();
    for (int off = 1; off < 256; off <<= 1) {
        int v = (t >= off) ? sc[t - off] : 0;
        __syncthreads();
        sc[t] += v;
        __syncthreads();
    }
    if (t < NBUCK) {
        int c = cnt[t], st = sc[t] - c;
        seg_start[(size_t)blk * NBUCK + t] = st;
        seg_cnt[(size_t)blk * NBUCK + t]   = c;
        cnt[t] = st;
    }
    __syncthreads();

    for (int j = t; j < CHUNK; j += 256) {
        long i = base + j;
        int s = -1, d = -1;
        if (i < N_EDGES)    { s = ei[i]; d = ei[N_EDGES + i]; }
        else if (i < TOT_E) { s = (int)(i - N_EDGES); d = s; }
        if (d >= 0) {
            int pos = atomicAdd(&cnt[d >> 9], 1);
            pairs[base + pos] = make_uint2((unsigned)s, (unsigned)d);
        }
    }
}

// ---------------- degree scan ----------------

__global__ __launch_bounds__(256) void scan_partial(const int* __restrict__ deg, int* __restrict__ bsum) {
    int i = blockIdx.x * 256 + threadIdx.x;
    int d = (i < N_NODES) ? deg[i] : 0;
    for (int off = 32; off; off >>= 1) d += __shfl_down(d, off);
    __shared__ int wsum[4];
    int lane = threadIdx.x & 63, w = threadIdx.x >> 6;
    if (lane == 0) wsum[w] = d;
    __syncthreads();
    if (threadIdx.x == 0) bsum[blockIdx.x] = wsum[0] + wsum[1] + wsum[2] + wsum[3];
}

__global__ void scan_bsum(const int* __restrict__ bsum, int* __restrict__ boff) {
    __shared__ int sd[512];
    int t = threadIdx.x;
    int v = (t < SCAN_NB) ? bsum[t] : 0;
    sd[t] = v; __syncthreads();
    for (int off = 1; off < 512; off <<= 1) {
        int x = (t >= off) ? sd[t - off] : 0;
        __syncthreads();
        sd[t] += x;
        __syncthreads();
    }
    if (t < SCAN_NB) boff[t] = sd[t] - v;   // exclusive
}

__global__ __launch_bounds__(256) void scan_final(const int* __restrict__ deg, const int* __restrict__ boff,
                                                  int* __restrict__ offs) {
    __shared__ int sd[256];
    int t = threadIdx.x;
    int i = blockIdx.x * 256 + t;
    int d = (i < N_NODES) ? deg[i] : 0;
    sd[t] = d; __syncthreads();
    for (int off = 1; off < 256; off <<= 1) {
        int x = (t >= off) ? sd[t - off] : 0;
        __syncthreads();
        sd[t] += x;
        __syncthreads();
    }
    if (i < N_NODES) offs[i + 1] = boff[blockIdx.x] + sd[t];
    if (i == 0) offs[0] = 0;
}

// ---------------- per-bucket exact scatter ----------------

__global__ __launch_bounds__(1024) void bucket_scatter(const uint2* __restrict__ pairs,
                                                       const int* __restrict__ seg_start,
                                                       const int* __restrict__ seg_cnt,
                                                       const int* __restrict__ offs,
                                                       int* __restrict__ csr_src) {
    int b = blockIdx.x, t = threadIdx.x;
    int nodeBase = b << 9;
    __shared__ int cur[512];
    __shared__ int pref[NBLK];
    __shared__ int sstart[NBLK];

    if (t < 512) {
        int n = nodeBase + t;
        cur[t] = (n < N_NODES) ? offs[n] : 0;
    }
    for (int j = t; j < NBLK; j += 1024) {
        pref[j]   = seg_cnt[(size_t)j * NBUCK + b];
        sstart[j] = seg_start[(size_t)j * NBUCK + b];
    }
    __syncthreads();
    for (int off = 1; off < NBLK; off <<= 1) {
        int v = 0;
        if (t < NBLK && t >= off) v = pref[t - off];
        __syncthreads();
        if (t < NBLK) pref[t] += v;
        __syncthreads();
    }
    int M = pref[NBLK - 1];

    for (int j = t; j < M; j += 1024) {
        int lo = 0, hi = NBLK - 1;
        while (lo < hi) { int mid = (lo + hi) >> 1; if (pref[mid] > j) hi = mid; else lo = mid + 1; }
        int within = j - (lo ? pref[lo - 1] : 0);
        uint2 e = pairs[(size_t)lo * CHUNK + sstart[lo] + within];
        int pos = atomicAdd(&cur[(int)e.y - nodeBase], 1);
        csr_src[pos] = (int)e.x;
    }
}

__global__ __launch_bounds__(256) void counts_kernel(const int* __restrict__ batch, int* __restrict__ counts) {
    __shared__ int loc[NGRAPH];
    int t = threadIdx.x;
    if (t < NGRAPH) loc[t] = 0;
    __syncthreads();
    int i = blockIdx.x * 256 + t;
    if (i < N_NODES) atomicAdd(&loc[batch[i]], 1);
    __syncthreads();
    if (t < NGRAPH && loc[t]) atomicAdd(&counts[t], loc[t]);
}

// ---------------- W -> bf16, fragment-ready layout Wt[k>>3][col][k&7] ----------------

__global__ __launch_bounds__(256) void wtconv_kernel(const float* __restrict__ W, unsigned short* __restrict__ Wt) {
    int i = blockIdx.x * 256 + threadIdx.x;
    if (i >= F_IN * HC) return;
    int k = i >> 7, col = i & 127;
    Wt[(size_t)(k >> 3) * (HC * 8) + col * 8 + (k & 7)] = f2bf_rne(W[i]);
}

// ---------------- GEMM: H = X @ W via MFMA bf16; output stored bf16 ----------------

template<bool BF16IN>
__global__ __launch_bounds__(256) void gemm_mfma(const void* __restrict__ Xv,
                                                 const unsigned short* __restrict__ Wt,
                                                 unsigned short* __restrict__ Hout) {
    __shared__ unsigned short A_lds[64 * F_IN];     // 16 KB
    int t = threadIdx.x;
    int lane = t & 63, wave = t >> 6;
    int wc = wave & 1, wr = wave >> 1;
    int base = blockIdx.x * 64;

    bf16x8 Bf[4][4];
    {
        int colb = wc * 64 + (lane & 15);
        int kbb  = lane >> 4;
#pragma unroll
        for (int ct = 0; ct < 4; ++ct)
#pragma unroll
            for (int ks = 0; ks < 4; ++ks) {
                int kb = kbb + 4 * ks;
                Bf[ct][ks] = *(const bf16x8*)&Wt[(size_t)kb * (HC * 8) + (colb + ct * 16) * 8];
            }
    }

#pragma unroll
    for (int it = 0; it < 8; ++it) {
        int i = t + it * 256;
        int row = i >> 5, c4 = i & 31, k0 = c4 * 4;
        uint2 pk; pk.x = 0; pk.y = 0;
        if (base + row < N_NODES) {
            if (BF16IN) {
                pk = ((const uint2*)Xv)[(size_t)(base + row) * 32 + c4];
            } else {
                float4 v = ((const float4*)Xv)[(size_t)(base + row) * 32 + c4];
                pk.x = (unsigned)f2bf_rne(v.x) | ((unsigned)f2bf_rne(v.y) << 16);
                pk.y = (unsigned)f2bf_rne(v.z) | ((unsigned)f2bf_rne(v.w) << 16);
            }
        }
        int byte = row * 256 + (((k0 >> 3) ^ (row & 7)) << 4) + (k0 & 4) * 2;
        *(uint2*)((char*)A_lds + byte) = pk;
    }
    __syncthreads();

    f32x4 acc[2][4] = {};
#pragma unroll
    for (int ks = 0; ks < 4; ++ks) {
        bf16x8 Af[2];
#pragma unroll
        for (int r = 0; r < 2; ++r) {
            int row = wr * 32 + r * 16 + (lane & 15);
            int kb  = ks * 4 + (lane >> 4);
            int byte = row * 256 + ((kb ^ (row & 7)) << 4);
            Af[r] = *(const bf16x8*)((const char*)A_lds + byte);
        }
#pragma unroll
        for (int ct = 0; ct < 4; ++ct) {
            acc[0][ct] = __builtin_amdgcn_mfma_f32_16x16x32_bf16(Af[0], Bf[ct][ks], acc[0][ct], 0, 0, 0);
            acc[1][ct] = __builtin_amdgcn_mfma_f32_16x16x32_bf16(Af[1], Bf[ct][ks], acc[1][ct], 0, 0, 0);
        }
    }

#pragma unroll
    for (int r = 0; r < 2; ++r) {
        int row0 = base + wr * 32 + r * 16 + (lane >> 4) * 4;
#pragma unroll
        for (int reg = 0; reg < 4; ++reg) {
            int row = row0 + reg;
            if (row < N_NODES) {
#pragma unroll
                for (int ct = 0; ct < 4; ++ct) {
                    int col = wc * 64 + ct * 16 + (lane & 15);
                    Hout[(size_t)row * HC + col] = f2bf_rne(acc[r][ct][reg]);
                }
            }
        }
    }
}

// ---------------- per-node attention logits (bf16 h) ----------------

__global__ __launch_bounds__(256) void alpha_kernel(const unsigned short* __restrict__ H,
                                                    const float* __restrict__ a_src, const float* __restrict__ a_dst,
                                                    float* __restrict__ asrc, float* __restrict__ adst) {
    int wid  = (blockIdx.x * 256 + threadIdx.x) >> 6;
    int lane = threadIdx.x & 63;
    if (wid >= N_NODES) return;
    unsigned hv = *(const unsigned*)&H[(size_t)wid * HC + lane * 2];
    float h0 = bf2f(hv & 0xffffu), h1 = bf2f(hv >> 16);
    int ch = lane * 2;
    float2 as = *(const float2*)&a_src[ch];
    float2 ad = *(const float2*)&a_dst[ch];
    float ps = h0 * as.x + h1 * as.y;
    float pd = h0 * ad.x + h1 * ad.y;
    for (int off = 16; off; off >>= 1) {
        ps += __shfl_xor(ps, off);
        pd += __shfl_xor(pd, off);
    }
    int head = lane >> 5;
    if ((lane & 31) == 0) {
        asrc[wid * 2 + head] = ps;
        adst[wid * 2 + head] = pd;
    }
}

// ---------------- aggregation: 16-lane edge groups, 8 gathers in flight ----------------
// 4 groups/wave × 2-unroll; lane q = lane&15 holds channels q*8..q*8+7 (uint4, 16 B).
// head = q>>3 (q<8 -> head0 ch 0-63, q>=8 -> head1 ch 64-127). Per-head denominator is
// preserved because shfl_xor(16)/(32) only combines lanes with equal q.

__global__ __launch_bounds__(256) void agg_kernel(const int* __restrict__ offs, const int* __restrict__ csr_src,
                                                  const float* __restrict__ asrc, const float* __restrict__ adst,
                                                  const unsigned short* __restrict__ Hin,
                                                  const float* __restrict__ bias,
                                                  unsigned short* __restrict__ Hout, int do_relu) {
    int wid  = (blockIdx.x * 256 + threadIdx.x) >> 6;
    int lane = threadIdx.x & 63;
    if (wid >= N_NODES) return;
    int beg = offs[wid], end = offs[wid + 1];
    int grp = lane >> 4;           // 0..3: edge group
    int q   = lane & 15;           // channels q*8 .. q*8+7
    int head = q >> 3;
    float2 adv = *(const float2*)&adst[(size_t)wid * 2];
    float madst = head ? adv.y : adv.x;
    const float2* av = (const float2*)asrc;

    float den = 0.f;
    float a0c = 0.f, a1c = 0.f, a2c = 0.f, a3c = 0.f;
    float a4c = 0.f, a5c = 0.f, a6c = 0.f, a7c = 0.f;

    for (int e = beg + grp; e < end; e += 8) {
        int en = e + 4;
        bool v1 = en < end;
        int s0 = csr_src[e];
        int s1 = v1 ? csr_src[en] : s0;
        float2 aa0 = av[s0];
        float2 aa1 = av[s1];
        uint4 g0 = *(const uint4*)&Hin[(size_t)s0 * HC + q * 8];
        uint4 g1 = *(const uint4*)&Hin[(size_t)s1 * HC + q * 8];
        float l0 = (head ? aa0.y : aa0.x) + madst; l0 = l0 > 0.f ? l0 : NEG_SLOPE * l0;
        float l1 = (head ? aa1.y : aa1.x) + madst; l1 = l1 > 0.f ? l1 : NEG_SLOPE * l1;
        float w0 = __expf(l0);
        float w1 = v1 ? __expf(l1) : 0.f;
        den += w0 + w1;
        a0c = fmaf(w1, bf2f(g1.x & 0xffffu), fmaf(w0, bf2f(g0.x & 0xffffu), a0c));
        a1c = fmaf(w1, bf2f(g1.x >> 16),     fmaf(w0, bf2f(g0.x >> 16),     a1c));
        a2c = fmaf(w1, bf2f(g1.y & 0xffffu), fmaf(w0, bf2f(g0.y & 0xffffu), a2c));
        a3c = fmaf(w1, bf2f(g1.y >> 16),     fmaf(w0, bf2f(g0.y >> 16),     a3c));
        a4c = fmaf(w1, bf2f(g1.z & 0xffffu), fmaf(w0, bf2f(g0.z & 0xffffu), a4c));
        a5c = fmaf(w1, bf2f(g1.z >> 16),     fmaf(w0, bf2f(g0.z >> 16),     a5c));
        a6c = fmaf(w1, bf2f(g1.w & 0xffffu), fmaf(w0, bf2f(g0.w & 0xffffu), a6c));
        a7c = fmaf(w1, bf2f(g1.w >> 16),     fmaf(w0, bf2f(g0.w >> 16),     a7c));
    }

#pragma unroll
    for (int off = 16; off <= 32; off <<= 1) {
        den += __shfl_xor(den, off);
        a0c += __shfl_xor(a0c, off);
        a1c += __shfl_xor(a1c, off);
        a2c += __shfl_xor(a2c, off);
        a3c += __shfl_xor(a3c, off);
        a4c += __shfl_xor(a4c, off);
        a5c += __shfl_xor(a5c, off);
        a6c += __shfl_xor(a6c, off);
        a7c += __shfl_xor(a7c, off);
    }

    if (lane < 16) {
        float inv = 1.0f / den;
        float4 b0 = *(const float4*)&bias[q * 8];
        float4 b1 = *(const float4*)&bias[q * 8 + 4];
        float o0 = fmaf(a0c, inv, b0.x);
        float o1 = fmaf(a1c, inv, b0.y);
        float o2 = fmaf(a2c, inv, b0.z);
        float o3 = fmaf(a3c, inv, b0.w);
        float o4 = fmaf(a4c, inv, b1.x);
        float o5 = fmaf(a5c, inv, b1.y);
        float o6 = fmaf(a6c, inv, b1.z);
        float o7 = fmaf(a7c, inv, b1.w);
        if (do_relu) {
            o0 = fmaxf(o0, 0.f); o1 = fmaxf(o1, 0.f); o2 = fmaxf(o2, 0.f); o3 = fmaxf(o3, 0.f);
            o4 = fmaxf(o4, 0.f); o5 = fmaxf(o5, 0.f); o6 = fmaxf(o6, 0.f); o7 = fmaxf(o7, 0.f);
        }
        uint4 st;
        st.x = (unsigned)f2bf_rne(o0) | ((unsigned)f2bf_rne(o1) << 16);
        st.y = (unsigned)f2bf_rne(o2) | ((unsigned)f2bf_rne(o3) << 16);
        st.z = (unsigned)f2bf_rne(o4) | ((unsigned)f2bf_rne(o5) << 16);
        st.w = (unsigned)f2bf_rne(o6) | ((unsigned)f2bf_rne(o7) << 16);
        *(uint4*)&Hout[(size_t)wid * HC + q * 8] = st;
    }
}

// ---------------- mean pool (bf16 input; 8K atomics only) ----------------

__global__ __launch_bounds__(256) void pool_kernel(const unsigned short* __restrict__ H2,
                                                   const int* __restrict__ counts,
                                                   float* __restrict__ out) {
    int g = blockIdx.x;
    int chunk = blockIdx.y;
    __shared__ int soff, scnt;
    if (threadIdx.x == 0) {
        int s = 0;
        for (int i = 0; i < g; ++i) s += counts[i];
        soff = s; scnt = counts[g];
    }
    __syncthreads();
    int start = soff, cnt = scnt;
    int r = threadIdx.x >> 7;
    int c = threadIdx.x & 127;
    float acc = 0.f;
    for (int v = chunk * 2 + r; v < cnt; v += 16)
        acc += bf2f((unsigned)H2[(size_t)(start + v) * HC + c]);
    float inv = 1.0f / fmaxf((float)cnt, 1.0f);
    atomicAdd(&out[g * HC + c], acc * inv);
}

// ---------------- launch ----------------

extern "C" void kernel_launch(void* const* d_in, const int* in_sizes, int n_in,
                              void* d_out, int out_size, void* d_ws, size_t ws_size,
                              hipStream_t stream) {
    const float* x     = (const float*)d_in[0];
    const int*   ei    = (const int*)d_in[1];
    const int*   batch = (const int*)d_in[2];
    const float* W1    = (const float*)d_in[3];
    const float* a1s   = (const float*)d_in[4];
    const float* a1d   = (const float*)d_in[5];
    const float* b1    = (const float*)d_in[6];
    const float* W2    = (const float*)d_in[7];
    const float* a2s   = (const float*)d_in[8];
    const float* a2d   = (const float*)d_in[9];
    const float* b2    = (const float*)d_in[10];
    float* out = (float*)d_out;

    char* ws = (char*)d_ws;
    const size_t NH = (size_t)N_NODES * HC;                 // elements per h buffer
    unsigned short* hA = (unsigned short*)ws;               // 25.6 MB
    unsigned short* hB = hA + NH;                           // 25.6 MB
    uint2* pairs = (uint2*)(hB + NH);                       // NBLK*CHUNK*8 = 13.6 MB
    float* asrc = (float*)(pairs + (size_t)NBLK * CHUNK);
    float* adst = asrc + (size_t)N_NODES * 2;
    unsigned short* wt1 = (unsigned short*)(adst + (size_t)N_NODES * 2);
    unsigned short* wt2 = wt1 + F_IN * HC;
    int*   deg  = (int*)(wt2 + F_IN * HC);
    int*   offs = deg + (N_NODES + 1);
    int*   csr  = offs + (N_NODES + 1);
    int*   seg_start = csr + TOT_E;
    int*   seg_cnt   = seg_start + (size_t)NBLK * NBUCK;
    int*   bsum = seg_cnt + (size_t)NBLK * NBUCK;
    int*   boff = bsum + SCAN_NB;
    int*   counts = boff + SCAN_NB;

    hipMemsetAsync(deg, 0, (N_NODES + 1) * sizeof(int), stream);
    hipMemsetAsync(counts, 0, NGRAPH * sizeof(int), stream);
    hipMemsetAsync(out, 0, (size_t)out_size * sizeof(float), stream);

    wtconv_kernel<<<(F_IN * HC + 255) / 256, 256, 0, stream>>>(W1, wt1);
    wtconv_kernel<<<(F_IN * HC + 255) / 256, 256, 0, stream>>>(W2, wt2);
    counts_kernel<<<(N_NODES + 255) / 256, 256, 0, stream>>>(batch, counts);

    // CSR build: bin-partition -> degree scan -> per-bucket exact scatter
    binpart_kernel<<<NBLK, 256, 0, stream>>>(ei, deg, pairs, seg_start, seg_cnt);
    scan_partial<<<SCAN_NB, 256, 0, stream>>>(deg, bsum);
    scan_bsum<<<1, 512, 0, stream>>>(bsum, boff);
    scan_final<<<SCAN_NB, 256, 0, stream>>>(deg, boff, offs);
    bucket_scatter<<<NBUCK, 1024, 0, stream>>>(pairs, seg_start, seg_cnt, offs, csr);

    int gemmBlocks = (N_NODES + 63) / 64;
    int waveBlocks = (N_NODES + 3) / 4;

    // layer 1
    gemm_mfma<false><<<gemmBlocks, 256, 0, stream>>>(x, wt1, hA);
    alpha_kernel<<<waveBlocks, 256, 0, stream>>>(hA, a1s, a1d, asrc, adst);
    agg_kernel<<<waveBlocks, 256, 0, stream>>>(offs, csr, asrc, adst, hA, b1, hB, 1);

    // layer 2
    gemm_mfma<true><<<gemmBlocks, 256, 0, stream>>>(hB, wt2, hA);
    alpha_kernel<<<waveBlocks, 256, 0, stream>>>(hA, a2s, a2d, asrc, adst);
    agg_kernel<<<waveBlocks, 256, 0, stream>>>(offs, csr, asrc, adst, hA, b2, hB, 0);

    // pool
    pool_kernel<<<dim3(NGRAPH, 8), 256, 0, stream>>>(hB, counts, out);
}

// Round 9
// 299.785 us; speedup vs baseline: 4.2838x; 1.1872x over previous
//
#include <hip/hip_runtime.h>

#define N_NODES 100000
#define N_EDGES 1600000
#define F_IN    128
#define HC      128     // H * C
#define NGRAPH  64
#define NEG_SLOPE 0.2f

static constexpr int TOT_E = N_EDGES + N_NODES;         // with self loops

// CSR binned build
#define CHUNK  2048
#define NBLK   831            // ceil(TOT_E / CHUNK)
#define NBUCK  196            // ceil(N_NODES / 512), bucket = dst >> 9

typedef __bf16 bf16x8 __attribute__((ext_vector_type(8)));
typedef float  f32x4  __attribute__((ext_vector_type(4)));

__device__ __forceinline__ unsigned short f2bf_rne(float f) {
    unsigned u = __float_as_uint(f);
    u += 0x7fffu + ((u >> 16) & 1u);
    return (unsigned short)(u >> 16);
}
__device__ __forceinline__ float bf2f(unsigned b) {        // low 16 bits used
    return __uint_as_float(b << 16);
}

// ---------------- binned partition: edges -> block-local bucket-grouped packed pairs ----------
// pair word = (src << 9) | (dst & 511). No global atomics.

__global__ __launch_bounds__(256) void binpart_kernel(const int* __restrict__ ei,
                                                      unsigned* __restrict__ pairs,
                                                      int* __restrict__ seg_start,
                                                      int* __restrict__ seg_cnt) {
    __shared__ int cnt[256];      // NBUCK=196, padded
    __shared__ int wtot[4];
    int t = threadIdx.x, blk = blockIdx.x;
    int lane = t & 63, w = t >> 6;
    long base = (long)blk * CHUNK;

    cnt[t] = 0;
    __syncthreads();

    // phase A: bucket counts (LDS only)
    for (int j = t; j < CHUNK; j += 256) {
        long i = base + j;
        int d = -1;
        if (i < N_EDGES)    d = ei[N_EDGES + i];
        else if (i < TOT_E) d = (int)(i - N_EDGES);
        if (d >= 0) atomicAdd(&cnt[d >> 9], 1);
    }
    __syncthreads();

    // phase B: wave-level inclusive scan of 256 counters (2 barriers total)
    int c = cnt[t];
    int x = c;
#pragma unroll
    for (int off = 1; off < 64; off <<= 1) {
        int v = __shfl_up(x, off);
        if (lane >= off) x += v;
    }
    if (lane == 63) wtot[w] = x;
    __syncthreads();
    int add = 0;
#pragma unroll
    for (int k = 0; k < 3; ++k) if (k < w) add += wtot[k];
    x += add;                      // inclusive
    int st = x - c;                // exclusive
    if (t < NBUCK) {
        seg_start[(size_t)blk * NBUCK + t] = st;
        seg_cnt[(size_t)blk * NBUCK + t]   = c;
    }
    __syncthreads();
    cnt[t] = st;                   // reuse as cursor
    __syncthreads();

    // phase C: scatter packed words into the block's own 8 KB region
    for (int j = t; j < CHUNK; j += 256) {
        long i = base + j;
        int s = -1, d = -1;
        if (i < N_EDGES)    { s = ei[i]; d = ei[N_EDGES + i]; }
        else if (i < TOT_E) { s = (int)(i - N_EDGES); d = s; }
        if (d >= 0) {
            int pos = atomicAdd(&cnt[d >> 9], 1);
            pairs[base + pos] = ((unsigned)s << 9) | ((unsigned)d & 511u);
        }
    }
}

// ---------------- per-bucket totals + base offsets (tiny) ----------------

__global__ __launch_bounds__(256) void btot_kernel(const int* __restrict__ seg_cnt, int* __restrict__ btot) {
    int b = blockIdx.x, t = threadIdx.x;
    int s = 0;
    for (int j = t; j < NBLK; j += 256) s += seg_cnt[(size_t)j * NBUCK + b];
    for (int off = 32; off; off >>= 1) s += __shfl_down(s, off);
    __shared__ int ws[4];
    int lane = t & 63, w = t >> 6;
    if (lane == 0) ws[w] = s;
    __syncthreads();
    if (t == 0) btot[b] = ws[0] + ws[1] + ws[2] + ws[3];
}

__global__ __launch_bounds__(256) void bbase_kernel(const int* __restrict__ btot, int* __restrict__ bbase) {
    int t = threadIdx.x;
    int lane = t & 63, w = t >> 6;
    int v = (t < NBUCK) ? btot[t] : 0;
    int x = v;
#pragma unroll
    for (int off = 1; off < 64; off <<= 1) {
        int u = __shfl_up(x, off);
        if (lane >= off) x += u;
    }
    __shared__ int wt[4];
    if (lane == 63) wt[w] = x;
    __syncthreads();
    int add = 0;
#pragma unroll
    for (int k = 0; k < 3; ++k) if (k < w) add += wt[k];
    x += add;
    if (t < NBUCK) bbase[t] = x - v;   // exclusive
}

// ---------------- per-bucket build: count -> offs (coalesced) -> exact scatter ----------------

__global__ __launch_bounds__(1024) void bucket_build(const unsigned* __restrict__ pairs,
                                                     const int* __restrict__ seg_start,
                                                     const int* __restrict__ seg_cnt,
                                                     const int* __restrict__ bbase,
                                                     int* __restrict__ offs,
                                                     int* __restrict__ csr_src) {
    int b = blockIdx.x, t = threadIdx.x;
    int nodeBase = b << 9;
    __shared__ int cur[512];
    __shared__ int pref[NBLK];
    __shared__ int sstart[NBLK];
    __shared__ int wt2[16];

    if (t < 512) cur[t] = 0;
    for (int j = t; j < NBLK; j += 1024) {
        pref[j]   = seg_cnt[(size_t)j * NBUCK + b];
        sstart[j] = seg_start[(size_t)j * NBUCK + b];
    }
    __syncthreads();
    for (int off = 1; off < NBLK; off <<= 1) {
        int v = 0;
        if (t < NBLK && t >= off) v = pref[t - off];
        __syncthreads();
        if (t < NBLK) pref[t] += v;
        __syncthreads();
    }
    int M = pref[NBLK - 1];

    // pass 1: per-node degree counts (LDS)
    for (int j = t; j < M; j += 1024) {
        int lo = 0, hi = NBLK - 1;
        while (lo < hi) { int mid = (lo + hi) >> 1; if (pref[mid] > j) hi = mid; else lo = mid + 1; }
        int within = j - (lo ? pref[lo - 1] : 0);
        unsigned wd = pairs[(size_t)lo * CHUNK + sstart[lo] + within];
        atomicAdd(&cur[wd & 511u], 1);
    }
    __syncthreads();

    // wave scan of 512 counts -> global starts; write offs coalesced
    int lane = t & 63, w = t >> 6;
    int myc = (t < 512) ? cur[t] : 0;
    int x = myc;
#pragma unroll
    for (int off = 1; off < 64; off <<= 1) {
        int u = __shfl_up(x, off);
        if (lane >= off) x += u;
    }
    if (lane == 63) wt2[w] = x;
    __syncthreads();
    int add = 0;
#pragma unroll
    for (int k = 0; k < 15; ++k) if (k < w) add += wt2[k];
    x += add;
    int gstart = bbase[b] + x - myc;
    if (t < 512) {
        if (nodeBase + t <= N_NODES) offs[nodeBase + t] = gstart;
        cur[t] = gstart;
    }
    __syncthreads();

    // pass 2: exact scatter with LDS cursors (block-private csr window)
    for (int j = t; j < M; j += 1024) {
        int lo = 0, hi = NBLK - 1;
        while (lo < hi) { int mid = (lo + hi) >> 1; if (pref[mid] > j) hi = mid; else lo = mid + 1; }
        int within = j - (lo ? pref[lo - 1] : 0);
        unsigned wd = pairs[(size_t)lo * CHUNK + sstart[lo] + within];
        int pos = atomicAdd(&cur[wd & 511u], 1);
        csr_src[pos] = (int)(wd >> 9);
    }
}

__global__ __launch_bounds__(256) void counts_kernel(const int* __restrict__ batch, int* __restrict__ counts) {
    __shared__ int loc[NGRAPH];
    int t = threadIdx.x;
    if (t < NGRAPH) loc[t] = 0;
    __syncthreads();
    int i = blockIdx.x * 256 + t;
    if (i < N_NODES) atomicAdd(&loc[batch[i]], 1);
    __syncthreads();
    if (t < NGRAPH && loc[t]) atomicAdd(&counts[t], loc[t]);
}

// ---------------- W -> bf16, fragment-ready layout Wt[k>>3][col][k&7] ----------------

__global__ __launch_bounds__(256) void wtconv_kernel(const float* __restrict__ W, unsigned short* __restrict__ Wt) {
    int i = blockIdx.x * 256 + threadIdx.x;
    if (i >= F_IN * HC) return;
    int k = i >> 7, col = i & 127;
    Wt[(size_t)(k >> 3) * (HC * 8) + col * 8 + (k & 7)] = f2bf_rne(W[i]);
}

// ---------------- GEMM: H = X @ W via MFMA bf16; output stored bf16 ----------------

template<bool BF16IN>
__global__ __launch_bounds__(256) void gemm_mfma(const void* __restrict__ Xv,
                                                 const unsigned short* __restrict__ Wt,
                                                 unsigned short* __restrict__ Hout) {
    __shared__ unsigned short A_lds[64 * F_IN];     // 16 KB
    int t = threadIdx.x;
    int lane = t & 63, wave = t >> 6;
    int wc = wave & 1, wr = wave >> 1;
    int base = blockIdx.x * 64;

    bf16x8 Bf[4][4];
    {
        int colb = wc * 64 + (lane & 15);
        int kbb  = lane >> 4;
#pragma unroll
        for (int ct = 0; ct < 4; ++ct)
#pragma unroll
            for (int ks = 0; ks < 4; ++ks) {
                int kb = kbb + 4 * ks;
                Bf[ct][ks] = *(const bf16x8*)&Wt[(size_t)kb * (HC * 8) + (colb + ct * 16) * 8];
            }
    }

#pragma unroll
    for (int it = 0; it < 8; ++it) {
        int i = t + it * 256;
        int row = i >> 5, c4 = i & 31, k0 = c4 * 4;
        uint2 pk; pk.x = 0; pk.y = 0;
        if (base + row < N_NODES) {
            if (BF16IN) {
                pk = ((const uint2*)Xv)[(size_t)(base + row) * 32 + c4];
            } else {
                float4 v = ((const float4*)Xv)[(size_t)(base + row) * 32 + c4];
                pk.x = (unsigned)f2bf_rne(v.x) | ((unsigned)f2bf_rne(v.y) << 16);
                pk.y = (unsigned)f2bf_rne(v.z) | ((unsigned)f2bf_rne(v.w) << 16);
            }
        }
        int byte = row * 256 + (((k0 >> 3) ^ (row & 7)) << 4) + (k0 & 4) * 2;
        *(uint2*)((char*)A_lds + byte) = pk;
    }
    __syncthreads();

    f32x4 acc[2][4] = {};
#pragma unroll
    for (int ks = 0; ks < 4; ++ks) {
        bf16x8 Af[2];
#pragma unroll
        for (int r = 0; r < 2; ++r) {
            int row = wr * 32 + r * 16 + (lane & 15);
            int kb  = ks * 4 + (lane >> 4);
            int byte = row * 256 + ((kb ^ (row & 7)) << 4);
            Af[r] = *(const bf16x8*)((const char*)A_lds + byte);
        }
#pragma unroll
        for (int ct = 0; ct < 4; ++ct) {
            acc[0][ct] = __builtin_amdgcn_mfma_f32_16x16x32_bf16(Af[0], Bf[ct][ks], acc[0][ct], 0, 0, 0);
            acc[1][ct] = __builtin_amdgcn_mfma_f32_16x16x32_bf16(Af[1], Bf[ct][ks], acc[1][ct], 0, 0, 0);
        }
    }

#pragma unroll
    for (int r = 0; r < 2; ++r) {
        int row0 = base + wr * 32 + r * 16 + (lane >> 4) * 4;
#pragma unroll
        for (int reg = 0; reg < 4; ++reg) {
            int row = row0 + reg;
            if (row < N_NODES) {
#pragma unroll
                for (int ct = 0; ct < 4; ++ct) {
                    int col = wc * 64 + ct * 16 + (lane & 15);
                    Hout[(size_t)row * HC + col] = f2bf_rne(acc[r][ct][reg]);
                }
            }
        }
    }
}

// ---------------- per-node attention logits (bf16 h) ----------------

__global__ __launch_bounds__(256) void alpha_kernel(const unsigned short* __restrict__ H,
                                                    const float* __restrict__ a_src, const float* __restrict__ a_dst,
                                                    float* __restrict__ asrc, float* __restrict__ adst) {
    int wid  = (blockIdx.x * 256 + threadIdx.x) >> 6;
    int lane = threadIdx.x & 63;
    if (wid >= N_NODES) return;
    unsigned hv = *(const unsigned*)&H[(size_t)wid * HC + lane * 2];
    float h0 = bf2f(hv & 0xffffu), h1 = bf2f(hv >> 16);
    int ch = lane * 2;
    float2 as = *(const float2*)&a_src[ch];
    float2 ad = *(const float2*)&a_dst[ch];
    float ps = h0 * as.x + h1 * as.y;
    float pd = h0 * ad.x + h1 * ad.y;
    for (int off = 16; off; off >>= 1) {
        ps += __shfl_xor(ps, off);
        pd += __shfl_xor(pd, off);
    }
    int head = lane >> 5;
    if ((lane & 31) == 0) {
        asrc[wid * 2 + head] = ps;
        adst[wid * 2 + head] = pd;
    }
}

// ---------------- aggregation: 16-lane edge groups, 8 gathers in flight ----------------

__global__ __launch_bounds__(256) void agg_kernel(const int* __restrict__ offs, const int* __restrict__ csr_src,
                                                  const float* __restrict__ asrc, const float* __restrict__ adst,
                                                  const unsigned short* __restrict__ Hin,
                                                  const float* __restrict__ bias,
                                                  unsigned short* __restrict__ Hout, int do_relu) {
    int wid  = (blockIdx.x * 256 + threadIdx.x) >> 6;
    int lane = threadIdx.x & 63;
    if (wid >= N_NODES) return;
    int beg = offs[wid], end = offs[wid + 1];
    int grp = lane >> 4;           // 0..3: edge group
    int q   = lane & 15;           // channels q*8 .. q*8+7
    int head = q >> 3;
    float2 adv = *(const float2*)&adst[(size_t)wid * 2];
    float madst = head ? adv.y : adv.x;
    const float2* av = (const float2*)asrc;

    float den = 0.f;
    float a0c = 0.f, a1c = 0.f, a2c = 0.f, a3c = 0.f;
    float a4c = 0.f, a5c = 0.f, a6c = 0.f, a7c = 0.f;

    for (int e = beg + grp; e < end; e += 8) {
        int en = e + 4;
        bool v1 = en < end;
        int s0 = csr_src[e];
        int s1 = v1 ? csr_src[en] : s0;
        float2 aa0 = av[s0];
        float2 aa1 = av[s1];
        uint4 g0 = *(const uint4*)&Hin[(size_t)s0 * HC + q * 8];
        uint4 g1 = *(const uint4*)&Hin[(size_t)s1 * HC + q * 8];
        float l0 = (head ? aa0.y : aa0.x) + madst; l0 = l0 > 0.f ? l0 : NEG_SLOPE * l0;
        float l1 = (head ? aa1.y : aa1.x) + madst; l1 = l1 > 0.f ? l1 : NEG_SLOPE * l1;
        float w0 = __expf(l0);
        float w1 = v1 ? __expf(l1) : 0.f;
        den += w0 + w1;
        a0c = fmaf(w1, bf2f(g1.x & 0xffffu), fmaf(w0, bf2f(g0.x & 0xffffu), a0c));
        a1c = fmaf(w1, bf2f(g1.x >> 16),     fmaf(w0, bf2f(g0.x >> 16),     a1c));
        a2c = fmaf(w1, bf2f(g1.y & 0xffffu), fmaf(w0, bf2f(g0.y & 0xffffu), a2c));
        a3c = fmaf(w1, bf2f(g1.y >> 16),     fmaf(w0, bf2f(g0.y >> 16),     a3c));
        a4c = fmaf(w1, bf2f(g1.z & 0xffffu), fmaf(w0, bf2f(g0.z & 0xffffu), a4c));
        a5c = fmaf(w1, bf2f(g1.z >> 16),     fmaf(w0, bf2f(g0.z >> 16),     a5c));
        a6c = fmaf(w1, bf2f(g1.w & 0xffffu), fmaf(w0, bf2f(g0.w & 0xffffu), a6c));
        a7c = fmaf(w1, bf2f(g1.w >> 16),     fmaf(w0, bf2f(g0.w >> 16),     a7c));
    }

#pragma unroll
    for (int off = 16; off <= 32; off <<= 1) {
        den += __shfl_xor(den, off);
        a0c += __shfl_xor(a0c, off);
        a1c += __shfl_xor(a1c, off);
        a2c += __shfl_xor(a2c, off);
        a3c += __shfl_xor(a3c, off);
        a4c += __shfl_xor(a4c, off);
        a5c += __shfl_xor(a5c, off);
        a6c += __shfl_xor(a6c, off);
        a7c += __shfl_xor(a7c, off);
    }

    if (lane < 16) {
        float inv = 1.0f / den;
        float4 b0 = *(const float4*)&bias[q * 8];
        float4 b1 = *(const float4*)&bias[q * 8 + 4];
        float o0 = fmaf(a0c, inv, b0.x);
        float o1 = fmaf(a1c, inv, b0.y);
        float o2 = fmaf(a2c, inv, b0.z);
        float o3 = fmaf(a3c, inv, b0.w);
        float o4 = fmaf(a4c, inv, b1.x);
        float o5 = fmaf(a5c, inv, b1.y);
        float o6 = fmaf(a6c, inv, b1.z);
        float o7 = fmaf(a7c, inv, b1.w);
        if (do_relu) {
            o0 = fmaxf(o0, 0.f); o1 = fmaxf(o1, 0.f); o2 = fmaxf(o2, 0.f); o3 = fmaxf(o3, 0.f);
            o4 = fmaxf(o4, 0.f); o5 = fmaxf(o5, 0.f); o6 = fmaxf(o6, 0.f); o7 = fmaxf(o7, 0.f);
        }
        uint4 st;
        st.x = (unsigned)f2bf_rne(o0) | ((unsigned)f2bf_rne(o1) << 16);
        st.y = (unsigned)f2bf_rne(o2) | ((unsigned)f2bf_rne(o3) << 16);
        st.z = (unsigned)f2bf_rne(o4) | ((unsigned)f2bf_rne(o5) << 16);
        st.w = (unsigned)f2bf_rne(o6) | ((unsigned)f2bf_rne(o7) << 16);
        *(uint4*)&Hout[(size_t)wid * HC + q * 8] = st;
    }
}

// ---------------- mean pool (bf16 input; 8K atomics only) ----------------

__global__ __launch_bounds__(256) void pool_kernel(const unsigned short* __restrict__ H2,
                                                   const int* __restrict__ counts,
                                                   float* __restrict__ out) {
    int g = blockIdx.x;
    int chunk = blockIdx.y;
    __shared__ int soff, scnt;
    if (threadIdx.x == 0) {
        int s = 0;
        for (int i = 0; i < g; ++i) s += counts[i];
        soff = s; scnt = counts[g];
    }
    __syncthreads();
    int start = soff, cnt = scnt;
    int r = threadIdx.x >> 7;
    int c = threadIdx.x & 127;
    float acc = 0.f;
    for (int v = chunk * 2 + r; v < cnt; v += 16)
        acc += bf2f((unsigned)H2[(size_t)(start + v) * HC + c]);
    float inv = 1.0f / fmaxf((float)cnt, 1.0f);
    atomicAdd(&out[g * HC + c], acc * inv);
}

// ---------------- launch ----------------

extern "C" void kernel_launch(void* const* d_in, const int* in_sizes, int n_in,
                              void* d_out, int out_size, void* d_ws, size_t ws_size,
                              hipStream_t stream) {
    const float* x     = (const float*)d_in[0];
    const int*   ei    = (const int*)d_in[1];
    const int*   batch = (const int*)d_in[2];
    const float* W1    = (const float*)d_in[3];
    const float* a1s   = (const float*)d_in[4];
    const float* a1d   = (const float*)d_in[5];
    const float* b1    = (const float*)d_in[6];
    const float* W2    = (const float*)d_in[7];
    const float* a2s   = (const float*)d_in[8];
    const float* a2d   = (const float*)d_in[9];
    const float* b2    = (const float*)d_in[10];
    float* out = (float*)d_out;

    char* ws = (char*)d_ws;
    const size_t NH = (size_t)N_NODES * HC;                 // elements per h buffer
    unsigned short* hA = (unsigned short*)ws;               // 25.6 MB
    unsigned short* hB = hA + NH;                           // 25.6 MB
    unsigned* pairs = (unsigned*)(hB + NH);                 // NBLK*CHUNK*4 = 6.8 MB
    float* asrc = (float*)(pairs + (size_t)NBLK * CHUNK);
    float* adst = asrc + (size_t)N_NODES * 2;
    unsigned short* wt1 = (unsigned short*)(adst + (size_t)N_NODES * 2);
    unsigned short* wt2 = wt1 + F_IN * HC;
    int*   offs = (int*)(wt2 + F_IN * HC);
    int*   csr  = offs + (N_NODES + 1);
    int*   seg_start = csr + TOT_E;
    int*   seg_cnt   = seg_start + (size_t)NBLK * NBUCK;
    int*   btot = seg_cnt + (size_t)NBLK * NBUCK;
    int*   bbase = btot + NBUCK;
    int*   counts = bbase + NBUCK;

    hipMemsetAsync(counts, 0, NGRAPH * sizeof(int), stream);
    hipMemsetAsync(out, 0, (size_t)out_size * sizeof(float), stream);

    wtconv_kernel<<<(F_IN * HC + 255) / 256, 256, 0, stream>>>(W1, wt1);
    wtconv_kernel<<<(F_IN * HC + 255) / 256, 256, 0, stream>>>(W2, wt2);
    counts_kernel<<<(N_NODES + 255) / 256, 256, 0, stream>>>(batch, counts);

    // CSR build: bin-partition -> bucket totals/bases -> per-bucket build (no global atomics)
    binpart_kernel<<<NBLK, 256, 0, stream>>>(ei, pairs, seg_start, seg_cnt);
    btot_kernel<<<NBUCK, 256, 0, stream>>>(seg_cnt, btot);
    bbase_kernel<<<1, 256, 0, stream>>>(btot, bbase);
    bucket_build<<<NBUCK, 1024, 0, stream>>>(pairs, seg_start, seg_cnt, bbase, offs, csr);

    int gemmBlocks = (N_NODES + 63) / 64;
    int waveBlocks = (N_NODES + 3) / 4;

    // layer 1
    gemm_mfma<false><<<gemmBlocks, 256, 0, stream>>>(x, wt1, hA);
    alpha_kernel<<<waveBlocks, 256, 0, stream>>>(hA, a1s, a1d, asrc, adst);
    agg_kernel<<<waveBlocks, 256, 0, stream>>>(offs, csr, asrc, adst, hA, b1, hB, 1);

    // layer 2
    gemm_mfma<true><<<gemmBlocks, 256, 0, stream>>>(hB, wt2, hA);
    alpha_kernel<<<waveBlocks, 256, 0, stream>>>(hA, a2s, a2d, asrc, adst);
    agg_kernel<<<waveBlocks, 256, 0, stream>>>(offs, csr, asrc, adst, hA, b2, hB, 0);

    // pool
    pool_kernel<<<dim3(NGRAPH, 8), 256, 0, stream>>>(hB, counts, out);
}

// Round 10
// 281.240 us; speedup vs baseline: 4.5663x; 1.0659x over previous
//
#include <hip/hip_runtime.h>

#define N_NODES 100000
#define N_EDGES 1600000
#define F_IN    128
#define HC      128     // H * C
#define NGRAPH  64
#define NEG_SLOPE 0.2f

static constexpr int TOT_E = N_EDGES + N_NODES;         // with self loops

// CSR binned build
#define CHUNK  2048
#define NBLK   831            // ceil(TOT_E / CHUNK)
#define NBUCK  196            // ceil(N_NODES / 512), bucket = dst >> 9

typedef __bf16 bf16x8 __attribute__((ext_vector_type(8)));
typedef float  f32x4  __attribute__((ext_vector_type(4)));

__device__ __forceinline__ unsigned short f2bf_rne(float f) {
    unsigned u = __float_as_uint(f);
    u += 0x7fffu + ((u >> 16) & 1u);
    return (unsigned short)(u >> 16);
}
__device__ __forceinline__ float bf2f(unsigned b) {        // low 16 bits used
    return __uint_as_float(b << 16);
}

// ---------------- binned partition: edges -> block-local bucket-grouped packed pairs ----------

__global__ __launch_bounds__(256) void binpart_kernel(const int* __restrict__ ei,
                                                      unsigned* __restrict__ pairs,
                                                      int* __restrict__ seg_start,
                                                      int* __restrict__ seg_cnt) {
    __shared__ int cnt[256];      // NBUCK=196, padded
    __shared__ int wtot[4];
    int t = threadIdx.x, blk = blockIdx.x;
    int lane = t & 63, w = t >> 6;
    long base = (long)blk * CHUNK;

    cnt[t] = 0;
    __syncthreads();

    for (int j = t; j < CHUNK; j += 256) {
        long i = base + j;
        int d = -1;
        if (i < N_EDGES)    d = ei[N_EDGES + i];
        else if (i < TOT_E) d = (int)(i - N_EDGES);
        if (d >= 0) atomicAdd(&cnt[d >> 9], 1);
    }
    __syncthreads();

    int c = cnt[t];
    int x = c;
#pragma unroll
    for (int off = 1; off < 64; off <<= 1) {
        int v = __shfl_up(x, off);
        if (lane >= off) x += v;
    }
    if (lane == 63) wtot[w] = x;
    __syncthreads();
    int add = 0;
#pragma unroll
    for (int k = 0; k < 3; ++k) if (k < w) add += wtot[k];
    x += add;
    int st = x - c;
    if (t < NBUCK) {
        seg_start[(size_t)blk * NBUCK + t] = st;
        seg_cnt[(size_t)blk * NBUCK + t]   = c;
    }
    __syncthreads();
    cnt[t] = st;
    __syncthreads();

    for (int j = t; j < CHUNK; j += 256) {
        long i = base + j;
        int s = -1, d = -1;
        if (i < N_EDGES)    { s = ei[i]; d = ei[N_EDGES + i]; }
        else if (i < TOT_E) { s = (int)(i - N_EDGES); d = s; }
        if (d >= 0) {
            int pos = atomicAdd(&cnt[d >> 9], 1);
            pairs[base + pos] = ((unsigned)s << 9) | ((unsigned)d & 511u);
        }
    }
}

// ---------------- per-bucket totals + base offsets ----------------

__global__ __launch_bounds__(256) void btot_kernel(const int* __restrict__ seg_cnt, int* __restrict__ btot) {
    int b = blockIdx.x, t = threadIdx.x;
    int s = 0;
    for (int j = t; j < NBLK; j += 256) s += seg_cnt[(size_t)j * NBUCK + b];
    for (int off = 32; off; off >>= 1) s += __shfl_down(s, off);
    __shared__ int ws[4];
    int lane = t & 63, w = t >> 6;
    if (lane == 0) ws[w] = s;
    __syncthreads();
    if (t == 0) btot[b] = ws[0] + ws[1] + ws[2] + ws[3];
}

__global__ __launch_bounds__(256) void bbase_kernel(const int* __restrict__ btot, int* __restrict__ bbase) {
    int t = threadIdx.x;
    int lane = t & 63, w = t >> 6;
    int v = (t < NBUCK) ? btot[t] : 0;
    int x = v;
#pragma unroll
    for (int off = 1; off < 64; off <<= 1) {
        int u = __shfl_up(x, off);
        if (lane >= off) x += u;
    }
    __shared__ int wt[4];
    if (lane == 63) wt[w] = x;
    __syncthreads();
    int add = 0;
#pragma unroll
    for (int k = 0; k < 3; ++k) if (k < w) add += wt[k];
    x += add;
    if (t < NBUCK) bbase[t] = x - v;   // exclusive
}

// ---------------- per-bucket build: count -> offs -> exact scatter ----------------

__global__ __launch_bounds__(1024) void bucket_build(const unsigned* __restrict__ pairs,
                                                     const int* __restrict__ seg_start,
                                                     const int* __restrict__ seg_cnt,
                                                     const int* __restrict__ bbase,
                                                     int* __restrict__ offs,
                                                     int* __restrict__ csr_src) {
    int b = blockIdx.x, t = threadIdx.x;
    int nodeBase = b << 9;
    __shared__ int cur[512];
    __shared__ int pref[NBLK];
    __shared__ int sstart[NBLK];
    __shared__ int wt2[16];

    if (t < 512) cur[t] = 0;
    for (int j = t; j < NBLK; j += 1024) {
        pref[j]   = seg_cnt[(size_t)j * NBUCK + b];
        sstart[j] = seg_start[(size_t)j * NBUCK + b];
    }
    __syncthreads();
    for (int off = 1; off < NBLK; off <<= 1) {
        int v = 0;
        if (t < NBLK && t >= off) v = pref[t - off];
        __syncthreads();
        if (t < NBLK) pref[t] += v;
        __syncthreads();
    }
    int M = pref[NBLK - 1];

    for (int j = t; j < M; j += 1024) {
        int lo = 0, hi = NBLK - 1;
        while (lo < hi) { int mid = (lo + hi) >> 1; if (pref[mid] > j) hi = mid; else lo = mid + 1; }
        int within = j - (lo ? pref[lo - 1] : 0);
        unsigned wd = pairs[(size_t)lo * CHUNK + sstart[lo] + within];
        atomicAdd(&cur[wd & 511u], 1);
    }
    __syncthreads();

    int lane = t & 63, w = t >> 6;
    int myc = (t < 512) ? cur[t] : 0;
    int x = myc;
#pragma unroll
    for (int off = 1; off < 64; off <<= 1) {
        int u = __shfl_up(x, off);
        if (lane >= off) x += u;
    }
    if (lane == 63) wt2[w] = x;
    __syncthreads();
    int add = 0;
#pragma unroll
    for (int k = 0; k < 15; ++k) if (k < w) add += wt2[k];
    x += add;
    int gstart = bbase[b] + x - myc;
    if (t < 512) {
        if (nodeBase + t <= N_NODES) offs[nodeBase + t] = gstart;
        cur[t] = gstart;
    }
    __syncthreads();

    for (int j = t; j < M; j += 1024) {
        int lo = 0, hi = NBLK - 1;
        while (lo < hi) { int mid = (lo + hi) >> 1; if (pref[mid] > j) hi = mid; else lo = mid + 1; }
        int within = j - (lo ? pref[lo - 1] : 0);
        unsigned wd = pairs[(size_t)lo * CHUNK + sstart[lo] + within];
        int pos = atomicAdd(&cur[wd & 511u], 1);
        csr_src[pos] = (int)(wd >> 9);
    }
}

__global__ __launch_bounds__(256) void counts_kernel(const int* __restrict__ batch, int* __restrict__ counts) {
    __shared__ int loc[NGRAPH];
    int t = threadIdx.x;
    if (t < NGRAPH) loc[t] = 0;
    __syncthreads();
    int i = blockIdx.x * 256 + t;
    if (i < N_NODES) atomicAdd(&loc[batch[i]], 1);
    __syncthreads();
    if (t < NGRAPH && loc[t]) atomicAdd(&counts[t], loc[t]);
}

// ---------------- W -> bf16, fragment-ready layout Wt[k>>3][col][k&7] ----------------

__global__ __launch_bounds__(256) void wtconv_kernel(const float* __restrict__ W, unsigned short* __restrict__ Wt) {
    int i = blockIdx.x * 256 + threadIdx.x;
    if (i >= F_IN * HC) return;
    int k = i >> 7, col = i & 127;
    Wt[(size_t)(k >> 3) * (HC * 8) + col * 8 + (k & 7)] = f2bf_rne(W[i]);
}

// ---------------- GEMM + fused alpha: H = X @ W (MFMA bf16), alpha dots in epilogue --------
// Wave (wr,wc) holds rows wr*32..+31, cols wc*64..+63 == head wc entirely, so
// alpha_{src,dst}[row, head=wc] is computed in-register + 4-step shfl reduction.

template<bool BF16IN>
__global__ __launch_bounds__(256) void gemm_mfma(const void* __restrict__ Xv,
                                                 const unsigned short* __restrict__ Wt,
                                                 unsigned short* __restrict__ Hout,
                                                 const float* __restrict__ a_src,
                                                 const float* __restrict__ a_dst,
                                                 float* __restrict__ asrc,
                                                 float* __restrict__ adst) {
    __shared__ unsigned short A_lds[64 * F_IN];     // 16 KB
    int t = threadIdx.x;
    int lane = t & 63, wave = t >> 6;
    int wc = wave & 1, wr = wave >> 1;
    int base = blockIdx.x * 64;

    bf16x8 Bf[4][4];
    {
        int colb = wc * 64 + (lane & 15);
        int kbb  = lane >> 4;
#pragma unroll
        for (int ct = 0; ct < 4; ++ct)
#pragma unroll
            for (int ks = 0; ks < 4; ++ks) {
                int kb = kbb + 4 * ks;
                Bf[ct][ks] = *(const bf16x8*)&Wt[(size_t)kb * (HC * 8) + (colb + ct * 16) * 8];
            }
    }

#pragma unroll
    for (int it = 0; it < 8; ++it) {
        int i = t + it * 256;
        int row = i >> 5, c4 = i & 31, k0 = c4 * 4;
        uint2 pk; pk.x = 0; pk.y = 0;
        if (base + row < N_NODES) {
            if (BF16IN) {
                pk = ((const uint2*)Xv)[(size_t)(base + row) * 32 + c4];
            } else {
                float4 v = ((const float4*)Xv)[(size_t)(base + row) * 32 + c4];
                pk.x = (unsigned)f2bf_rne(v.x) | ((unsigned)f2bf_rne(v.y) << 16);
                pk.y = (unsigned)f2bf_rne(v.z) | ((unsigned)f2bf_rne(v.w) << 16);
            }
        }
        int byte = row * 256 + (((k0 >> 3) ^ (row & 7)) << 4) + (k0 & 4) * 2;
        *(uint2*)((char*)A_lds + byte) = pk;
    }
    __syncthreads();

    f32x4 acc[2][4] = {};
#pragma unroll
    for (int ks = 0; ks < 4; ++ks) {
        bf16x8 Af[2];
#pragma unroll
        for (int r = 0; r < 2; ++r) {
            int row = wr * 32 + r * 16 + (lane & 15);
            int kb  = ks * 4 + (lane >> 4);
            int byte = row * 256 + ((kb ^ (row & 7)) << 4);
            Af[r] = *(const bf16x8*)((const char*)A_lds + byte);
        }
#pragma unroll
        for (int ct = 0; ct < 4; ++ct) {
            acc[0][ct] = __builtin_amdgcn_mfma_f32_16x16x32_bf16(Af[0], Bf[ct][ks], acc[0][ct], 0, 0, 0);
            acc[1][ct] = __builtin_amdgcn_mfma_f32_16x16x32_bf16(Af[1], Bf[ct][ks], acc[1][ct], 0, 0, 0);
        }
    }

    // H store (bf16)
#pragma unroll
    for (int r = 0; r < 2; ++r) {
        int row0 = base + wr * 32 + r * 16 + (lane >> 4) * 4;
#pragma unroll
        for (int reg = 0; reg < 4; ++reg) {
            int row = row0 + reg;
            if (row < N_NODES) {
#pragma unroll
                for (int ct = 0; ct < 4; ++ct) {
                    int col = wc * 64 + ct * 16 + (lane & 15);
                    Hout[(size_t)row * HC + col] = f2bf_rne(acc[r][ct][reg]);
                }
            }
        }
    }

    // fused alpha: per-ct coefficients for this lane's column within head wc
    float as_c[4], ad_c[4];
#pragma unroll
    for (int ct = 0; ct < 4; ++ct) {
        int ch = wc * 64 + ct * 16 + (lane & 15);
        as_c[ct] = a_src[ch];
        ad_c[ct] = a_dst[ch];
    }
#pragma unroll
    for (int r = 0; r < 2; ++r) {
#pragma unroll
        for (int reg = 0; reg < 4; ++reg) {
            float ps = acc[r][0][reg] * as_c[0] + acc[r][1][reg] * as_c[1]
                     + acc[r][2][reg] * as_c[2] + acc[r][3][reg] * as_c[3];
            float pd = acc[r][0][reg] * ad_c[0] + acc[r][1][reg] * ad_c[1]
                     + acc[r][2][reg] * ad_c[2] + acc[r][3][reg] * ad_c[3];
#pragma unroll
            for (int off = 1; off < 16; off <<= 1) {
                ps += __shfl_xor(ps, off);
                pd += __shfl_xor(pd, off);
            }
            if ((lane & 15) == 0) {
                int row = base + wr * 32 + r * 16 + (lane >> 4) * 4 + reg;
                if (row < N_NODES) {
                    asrc[(size_t)row * 2 + wc] = ps;
                    adst[(size_t)row * 2 + wc] = pd;
                }
            }
        }
    }
}

// ---------------- aggregation: 8-lane edge groups, 16 gathers in flight ----------------
// grp = lane>>3 (0..7); head = grp&1; eslot = grp>>1 (0..3); lane q8 = lane&7 holds
// channels head*64 + q8*8 (uint4 = 128 B half-row per 8-lane group). 2x unroll ->
// 16 independent gathers/wave. Reduce via xor16+xor32 (preserves head); lanes 0..15
// end with channel base lane*8 and their own head's denominator.

__global__ __launch_bounds__(256) void agg_kernel(const int* __restrict__ offs, const int* __restrict__ csr_src,
                                                  const float* __restrict__ asrc, const float* __restrict__ adst,
                                                  const unsigned short* __restrict__ Hin,
                                                  const float* __restrict__ bias,
                                                  unsigned short* __restrict__ Hout, int do_relu) {
    int wid  = (blockIdx.x * 256 + threadIdx.x) >> 6;
    int lane = threadIdx.x & 63;
    if (wid >= N_NODES) return;
    int beg = offs[wid], end = offs[wid + 1];
    int grp   = lane >> 3;
    int head  = grp & 1;
    int eslot = grp >> 1;          // 0..3
    int q8    = lane & 7;
    float2 adv = *(const float2*)&adst[(size_t)wid * 2];
    float madst = head ? adv.y : adv.x;
    const float2* av = (const float2*)asrc;
    const unsigned short* hbase = Hin + head * 64 + q8 * 8;

    float den = 0.f;
    float a0c = 0.f, a1c = 0.f, a2c = 0.f, a3c = 0.f;
    float a4c = 0.f, a5c = 0.f, a6c = 0.f, a7c = 0.f;

    for (int e = beg + eslot; e < end; e += 8) {
        int en = e + 4;
        bool v1 = en < end;
        int s0 = csr_src[e];
        int s1 = v1 ? csr_src[en] : s0;
        float2 aa0 = av[s0];
        float2 aa1 = av[s1];
        uint4 g0 = *(const uint4*)&hbase[(size_t)s0 * HC];
        uint4 g1 = *(const uint4*)&hbase[(size_t)s1 * HC];
        float l0 = (head ? aa0.y : aa0.x) + madst; l0 = l0 > 0.f ? l0 : NEG_SLOPE * l0;
        float l1 = (head ? aa1.y : aa1.x) + madst; l1 = l1 > 0.f ? l1 : NEG_SLOPE * l1;
        float w0 = __expf(l0);
        float w1 = v1 ? __expf(l1) : 0.f;
        den += w0 + w1;
        a0c = fmaf(w1, bf2f(g1.x & 0xffffu), fmaf(w0, bf2f(g0.x & 0xffffu), a0c));
        a1c = fmaf(w1, bf2f(g1.x >> 16),     fmaf(w0, bf2f(g0.x >> 16),     a1c));
        a2c = fmaf(w1, bf2f(g1.y & 0xffffu), fmaf(w0, bf2f(g0.y & 0xffffu), a2c));
        a3c = fmaf(w1, bf2f(g1.y >> 16),     fmaf(w0, bf2f(g0.y >> 16),     a3c));
        a4c = fmaf(w1, bf2f(g1.z & 0xffffu), fmaf(w0, bf2f(g0.z & 0xffffu), a4c));
        a5c = fmaf(w1, bf2f(g1.z >> 16),     fmaf(w0, bf2f(g0.z >> 16),     a5c));
        a6c = fmaf(w1, bf2f(g1.w & 0xffffu), fmaf(w0, bf2f(g0.w & 0xffffu), a6c));
        a7c = fmaf(w1, bf2f(g1.w >> 16),     fmaf(w0, bf2f(g0.w >> 16),     a7c));
    }

#pragma unroll
    for (int off = 16; off <= 32; off <<= 1) {
        den += __shfl_xor(den, off);
        a0c += __shfl_xor(a0c, off);
        a1c += __shfl_xor(a1c, off);
        a2c += __shfl_xor(a2c, off);
        a3c += __shfl_xor(a3c, off);
        a4c += __shfl_xor(a4c, off);
        a5c += __shfl_xor(a5c, off);
        a6c += __shfl_xor(a6c, off);
        a7c += __shfl_xor(a7c, off);
    }

    if (lane < 16) {
        float inv = 1.0f / den;
        float4 b0 = *(const float4*)&bias[lane * 8];
        float4 b1 = *(const float4*)&bias[lane * 8 + 4];
        float o0 = fmaf(a0c, inv, b0.x);
        float o1 = fmaf(a1c, inv, b0.y);
        float o2 = fmaf(a2c, inv, b0.z);
        float o3 = fmaf(a3c, inv, b0.w);
        float o4 = fmaf(a4c, inv, b1.x);
        float o5 = fmaf(a5c, inv, b1.y);
        float o6 = fmaf(a6c, inv, b1.z);
        float o7 = fmaf(a7c, inv, b1.w);
        if (do_relu) {
            o0 = fmaxf(o0, 0.f); o1 = fmaxf(o1, 0.f); o2 = fmaxf(o2, 0.f); o3 = fmaxf(o3, 0.f);
            o4 = fmaxf(o4, 0.f); o5 = fmaxf(o5, 0.f); o6 = fmaxf(o6, 0.f); o7 = fmaxf(o7, 0.f);
        }
        uint4 st;
        st.x = (unsigned)f2bf_rne(o0) | ((unsigned)f2bf_rne(o1) << 16);
        st.y = (unsigned)f2bf_rne(o2) | ((unsigned)f2bf_rne(o3) << 16);
        st.z = (unsigned)f2bf_rne(o4) | ((unsigned)f2bf_rne(o5) << 16);
        st.w = (unsigned)f2bf_rne(o6) | ((unsigned)f2bf_rne(o7) << 16);
        *(uint4*)&Hout[(size_t)wid * HC + lane * 8] = st;
    }
}

// ---------------- mean pool (bf16 input; 8K atomics only) ----------------

__global__ __launch_bounds__(256) void pool_kernel(const unsigned short* __restrict__ H2,
                                                   const int* __restrict__ counts,
                                                   float* __restrict__ out) {
    int g = blockIdx.x;
    int chunk = blockIdx.y;
    __shared__ int soff, scnt;
    if (threadIdx.x == 0) {
        int s = 0;
        for (int i = 0; i < g; ++i) s += counts[i];
        soff = s; scnt = counts[g];
    }
    __syncthreads();
    int start = soff, cnt = scnt;
    int r = threadIdx.x >> 7;
    int c = threadIdx.x & 127;
    float acc = 0.f;
    for (int v = chunk * 2 + r; v < cnt; v += 16)
        acc += bf2f((unsigned)H2[(size_t)(start + v) * HC + c]);
    float inv = 1.0f / fmaxf((float)cnt, 1.0f);
    atomicAdd(&out[g * HC + c], acc * inv);
}

// ---------------- launch ----------------

extern "C" void kernel_launch(void* const* d_in, const int* in_sizes, int n_in,
                              void* d_out, int out_size, void* d_ws, size_t ws_size,
                              hipStream_t stream) {
    const float* x     = (const float*)d_in[0];
    const int*   ei    = (const int*)d_in[1];
    const int*   batch = (const int*)d_in[2];
    const float* W1    = (const float*)d_in[3];
    const float* a1s   = (const float*)d_in[4];
    const float* a1d   = (const float*)d_in[5];
    const float* b1    = (const float*)d_in[6];
    const float* W2    = (const float*)d_in[7];
    const float* a2s   = (const float*)d_in[8];
    const float* a2d   = (const float*)d_in[9];
    const float* b2    = (const float*)d_in[10];
    float* out = (float*)d_out;

    char* ws = (char*)d_ws;
    const size_t NH = (size_t)N_NODES * HC;                 // elements per h buffer
    unsigned short* hA = (unsigned short*)ws;               // 25.6 MB
    unsigned short* hB = hA + NH;                           // 25.6 MB
    unsigned* pairs = (unsigned*)(hB + NH);                 // NBLK*CHUNK*4 = 6.8 MB
    float* asrc = (float*)(pairs + (size_t)NBLK * CHUNK);
    float* adst = asrc + (size_t)N_NODES * 2;
    unsigned short* wt1 = (unsigned short*)(adst + (size_t)N_NODES * 2);
    unsigned short* wt2 = wt1 + F_IN * HC;
    int*   offs = (int*)(wt2 + F_IN * HC);
    int*   csr  = offs + (N_NODES + 1);
    int*   seg_start = csr + TOT_E;
    int*   seg_cnt   = seg_start + (size_t)NBLK * NBUCK;
    int*   btot = seg_cnt + (size_t)NBLK * NBUCK;
    int*   bbase = btot + NBUCK;
    int*   counts = bbase + NBUCK;

    hipMemsetAsync(counts, 0, NGRAPH * sizeof(int), stream);
    hipMemsetAsync(out, 0, (size_t)out_size * sizeof(float), stream);

    wtconv_kernel<<<(F_IN * HC + 255) / 256, 256, 0, stream>>>(W1, wt1);
    wtconv_kernel<<<(F_IN * HC + 255) / 256, 256, 0, stream>>>(W2, wt2);
    counts_kernel<<<(N_NODES + 255) / 256, 256, 0, stream>>>(batch, counts);

    // CSR build: bin-partition -> bucket totals/bases -> per-bucket build (no global atomics)
    binpart_kernel<<<NBLK, 256, 0, stream>>>(ei, pairs, seg_start, seg_cnt);
    btot_kernel<<<NBUCK, 256, 0, stream>>>(seg_cnt, btot);
    bbase_kernel<<<1, 256, 0, stream>>>(btot, bbase);
    bucket_build<<<NBUCK, 1024, 0, stream>>>(pairs, seg_start, seg_cnt, bbase, offs, csr);

    int gemmBlocks = (N_NODES + 63) / 64;
    int waveBlocks = (N_NODES + 3) / 4;

    // layer 1 (alpha fused into gemm epilogue)
    gemm_mfma<false><<<gemmBlocks, 256, 0, stream>>>(x, wt1, hA, a1s, a1d, asrc, adst);
    agg_kernel<<<waveBlocks, 256, 0, stream>>>(offs, csr, asrc, adst, hA, b1, hB, 1);

    // layer 2
    gemm_mfma<true><<<gemmBlocks, 256, 0, stream>>>(hB, wt2, hA, a2s, a2d, asrc, adst);
    agg_kernel<<<waveBlocks, 256, 0, stream>>>(offs, csr, asrc, adst, hA, b2, hB, 0);

    // pool
    pool_kernel<<<dim3(NGRAPH, 8), 256, 0, stream>>>(hB, counts, out);
}

// Round 11
// 272.053 us; speedup vs baseline: 4.7205x; 1.0338x over previous
//
#include <hip/hip_runtime.h>

#define N_NODES 100000
#define N_EDGES 1600000
#define F_IN    128
#define HC      128     // H * C
#define NGRAPH  64
#define NEG_SLOPE 0.2f

static constexpr int TOT_E = N_EDGES + N_NODES;         // with self loops

// CSR binned build
#define CHUNK  2048
#define NBLK   831            // ceil(TOT_E / CHUNK)
#define NBUCK  196            // ceil(N_NODES / 512), bucket = dst >> 9

#define GEMM_B 1563           // ceil(N_NODES / 64)
#define CNT_B  391            // ceil(N_NODES / 256)

typedef __bf16 bf16x8 __attribute__((ext_vector_type(8)));
typedef float  f32x4  __attribute__((ext_vector_type(4)));

__device__ __forceinline__ unsigned short f2bf_rne(float f) {
    unsigned u = __float_as_uint(f);
    u += 0x7fffu + ((u >> 16) & 1u);
    return (unsigned short)(u >> 16);
}
__device__ __forceinline__ float bf2f(unsigned b) {        // low 16 bits used
    return __uint_as_float(b << 16);
}

// ---------------- device bodies (shared between fused and standalone kernels) ----------------

// binned partition: edges -> block-local bucket-grouped packed pairs. word = (src<<9)|(dst&511)
__device__ __forceinline__ void binpart_body(int blk, int t,
                                             const int* __restrict__ ei,
                                             unsigned* __restrict__ pairs,
                                             int* __restrict__ seg_start,
                                             int* __restrict__ seg_cnt,
                                             int* cnt, int* wtot) {
    int lane = t & 63, w = t >> 6;
    long base = (long)blk * CHUNK;

    cnt[t] = 0;
    __syncthreads();

    for (int j = t; j < CHUNK; j += 256) {
        long i = base + j;
        int d = -1;
        if (i < N_EDGES)    d = ei[N_EDGES + i];
        else if (i < TOT_E) d = (int)(i - N_EDGES);
        if (d >= 0) atomicAdd(&cnt[d >> 9], 1);
    }
    __syncthreads();

    int c = cnt[t];
    int x = c;
#pragma unroll
    for (int off = 1; off < 64; off <<= 1) {
        int v = __shfl_up(x, off);
        if (lane >= off) x += v;
    }
    if (lane == 63) wtot[w] = x;
    __syncthreads();
    int add = 0;
#pragma unroll
    for (int k = 0; k < 3; ++k) if (k < w) add += wtot[k];
    x += add;
    int st = x - c;
    if (t < NBUCK) {
        seg_start[(size_t)blk * NBUCK + t] = st;
        seg_cnt[(size_t)blk * NBUCK + t]   = c;
    }
    __syncthreads();
    cnt[t] = st;
    __syncthreads();

    for (int j = t; j < CHUNK; j += 256) {
        long i = base + j;
        int s = -1, d = -1;
        if (i < N_EDGES)    { s = ei[i]; d = ei[N_EDGES + i]; }
        else if (i < TOT_E) { s = (int)(i - N_EDGES); d = s; }
        if (d >= 0) {
            int pos = atomicAdd(&cnt[d >> 9], 1);
            pairs[base + pos] = ((unsigned)s << 9) | ((unsigned)d & 511u);
        }
    }
}

// GEMM tile + fused alpha epilogue. Wave (wr,wc) owns rows 32wr..+31, cols 64wc..+63 (= head wc).
template<bool BF16IN>
__device__ __forceinline__ void gemm_body(int gbid, int t,
                                          const void* __restrict__ Xv,
                                          const unsigned short* __restrict__ Wt,
                                          unsigned short* __restrict__ Hout,
                                          const float* __restrict__ a_src,
                                          const float* __restrict__ a_dst,
                                          float* __restrict__ asrc,
                                          float* __restrict__ adst,
                                          unsigned short* A_lds) {
    int lane = t & 63, wave = t >> 6;
    int wc = wave & 1, wr = wave >> 1;
    int base = gbid * 64;

    bf16x8 Bf[4][4];
    {
        int colb = wc * 64 + (lane & 15);
        int kbb  = lane >> 4;
#pragma unroll
        for (int ct = 0; ct < 4; ++ct)
#pragma unroll
            for (int ks = 0; ks < 4; ++ks) {
                int kb = kbb + 4 * ks;
                Bf[ct][ks] = *(const bf16x8*)&Wt[(size_t)kb * (HC * 8) + (colb + ct * 16) * 8];
            }
    }

#pragma unroll
    for (int it = 0; it < 8; ++it) {
        int i = t + it * 256;
        int row = i >> 5, c4 = i & 31, k0 = c4 * 4;
        uint2 pk; pk.x = 0; pk.y = 0;
        if (base + row < N_NODES) {
            if (BF16IN) {
                pk = ((const uint2*)Xv)[(size_t)(base + row) * 32 + c4];
            } else {
                float4 v = ((const float4*)Xv)[(size_t)(base + row) * 32 + c4];
                pk.x = (unsigned)f2bf_rne(v.x) | ((unsigned)f2bf_rne(v.y) << 16);
                pk.y = (unsigned)f2bf_rne(v.z) | ((unsigned)f2bf_rne(v.w) << 16);
            }
        }
        int byte = row * 256 + (((k0 >> 3) ^ (row & 7)) << 4) + (k0 & 4) * 2;
        *(uint2*)((char*)A_lds + byte) = pk;
    }
    __syncthreads();

    f32x4 acc[2][4] = {};
#pragma unroll
    for (int ks = 0; ks < 4; ++ks) {
        bf16x8 Af[2];
#pragma unroll
        for (int r = 0; r < 2; ++r) {
            int row = wr * 32 + r * 16 + (lane & 15);
            int kb  = ks * 4 + (lane >> 4);
            int byte = row * 256 + ((kb ^ (row & 7)) << 4);
            Af[r] = *(const bf16x8*)((const char*)A_lds + byte);
        }
#pragma unroll
        for (int ct = 0; ct < 4; ++ct) {
            acc[0][ct] = __builtin_amdgcn_mfma_f32_16x16x32_bf16(Af[0], Bf[ct][ks], acc[0][ct], 0, 0, 0);
            acc[1][ct] = __builtin_amdgcn_mfma_f32_16x16x32_bf16(Af[1], Bf[ct][ks], acc[1][ct], 0, 0, 0);
        }
    }

    // H store (bf16)
#pragma unroll
    for (int r = 0; r < 2; ++r) {
        int row0 = base + wr * 32 + r * 16 + (lane >> 4) * 4;
#pragma unroll
        for (int reg = 0; reg < 4; ++reg) {
            int row = row0 + reg;
            if (row < N_NODES) {
#pragma unroll
                for (int ct = 0; ct < 4; ++ct) {
                    int col = wc * 64 + ct * 16 + (lane & 15);
                    Hout[(size_t)row * HC + col] = f2bf_rne(acc[r][ct][reg]);
                }
            }
        }
    }

    // fused alpha
    float as_c[4], ad_c[4];
#pragma unroll
    for (int ct = 0; ct < 4; ++ct) {
        int ch = wc * 64 + ct * 16 + (lane & 15);
        as_c[ct] = a_src[ch];
        ad_c[ct] = a_dst[ch];
    }
#pragma unroll
    for (int r = 0; r < 2; ++r) {
#pragma unroll
        for (int reg = 0; reg < 4; ++reg) {
            float ps = acc[r][0][reg] * as_c[0] + acc[r][1][reg] * as_c[1]
                     + acc[r][2][reg] * as_c[2] + acc[r][3][reg] * as_c[3];
            float pd = acc[r][0][reg] * ad_c[0] + acc[r][1][reg] * ad_c[1]
                     + acc[r][2][reg] * ad_c[2] + acc[r][3][reg] * ad_c[3];
#pragma unroll
            for (int off = 1; off < 16; off <<= 1) {
                ps += __shfl_xor(ps, off);
                pd += __shfl_xor(pd, off);
            }
            if ((lane & 15) == 0) {
                int row = base + wr * 32 + r * 16 + (lane >> 4) * 4 + reg;
                if (row < N_NODES) {
                    asrc[(size_t)row * 2 + wc] = ps;
                    adst[(size_t)row * 2 + wc] = pd;
                }
            }
        }
    }
}

// ---------------- fused main: gemm1 (x GEMM_B) ⊗ binpart (x NBLK) ⊗ counts (x CNT_B) -------
// first 2*NBLK blocks alternate gemm/binpart so both populations co-reside per CU.

__global__ __launch_bounds__(256) void fused_main(const float* __restrict__ x,
                                                  const unsigned short* __restrict__ wt1,
                                                  unsigned short* __restrict__ hA,
                                                  const float* __restrict__ a1s,
                                                  const float* __restrict__ a1d,
                                                  float* __restrict__ asrc,
                                                  float* __restrict__ adst,
                                                  const int* __restrict__ ei,
                                                  unsigned* __restrict__ pairs,
                                                  int* __restrict__ seg_start,
                                                  int* __restrict__ seg_cnt,
                                                  const int* __restrict__ batch,
                                                  int* __restrict__ counts) {
    __shared__ unsigned short A_lds[64 * F_IN];   // 16 KB (gemm branch)
    __shared__ int cnt[256];                      // binpart branch
    __shared__ int wtot[4];
    __shared__ int loc[NGRAPH];                   // counts branch
    int bid = blockIdx.x, t = threadIdx.x;

    if (bid < 2 * NBLK) {
        if (bid & 1) binpart_body(bid >> 1, t, ei, pairs, seg_start, seg_cnt, cnt, wtot);
        else         gemm_body<false>(bid >> 1, t, x, wt1, hA, a1s, a1d, asrc, adst, A_lds);
    } else if (bid < NBLK + GEMM_B) {
        gemm_body<false>(bid - NBLK, t, x, wt1, hA, a1s, a1d, asrc, adst, A_lds);
    } else {
        int cb = bid - (NBLK + GEMM_B);
        if (t < NGRAPH) loc[t] = 0;
        __syncthreads();
        int i = cb * 256 + t;
        if (i < N_NODES) atomicAdd(&loc[batch[i]], 1);
        __syncthreads();
        if (t < NGRAPH && loc[t]) atomicAdd(&counts[t], loc[t]);
    }
}

// ---------------- standalone gemm (layer 2) ----------------

__global__ __launch_bounds__(256) void gemm2_kernel(const unsigned short* __restrict__ Xv,
                                                    const unsigned short* __restrict__ Wt,
                                                    unsigned short* __restrict__ Hout,
                                                    const float* __restrict__ a_src,
                                                    const float* __restrict__ a_dst,
                                                    float* __restrict__ asrc,
                                                    float* __restrict__ adst) {
    __shared__ unsigned short A_lds[64 * F_IN];
    gemm_body<true>(blockIdx.x, threadIdx.x, Xv, Wt, Hout, a_src, a_dst, asrc, adst, A_lds);
}

// ---------------- per-bucket totals + base offsets ----------------

__global__ __launch_bounds__(256) void btot_kernel(const int* __restrict__ seg_cnt, int* __restrict__ btot) {
    int b = blockIdx.x, t = threadIdx.x;
    int s = 0;
    for (int j = t; j < NBLK; j += 256) s += seg_cnt[(size_t)j * NBUCK + b];
    for (int off = 32; off; off >>= 1) s += __shfl_down(s, off);
    __shared__ int ws[4];
    int lane = t & 63, w = t >> 6;
    if (lane == 0) ws[w] = s;
    __syncthreads();
    if (t == 0) btot[b] = ws[0] + ws[1] + ws[2] + ws[3];
}

__global__ __launch_bounds__(256) void bbase_kernel(const int* __restrict__ btot, int* __restrict__ bbase) {
    int t = threadIdx.x;
    int lane = t & 63, w = t >> 6;
    int v = (t < NBUCK) ? btot[t] : 0;
    int x = v;
#pragma unroll
    for (int off = 1; off < 64; off <<= 1) {
        int u = __shfl_up(x, off);
        if (lane >= off) x += u;
    }
    __shared__ int wt[4];
    if (lane == 63) wt[w] = x;
    __syncthreads();
    int add = 0;
#pragma unroll
    for (int k = 0; k < 3; ++k) if (k < w) add += wt[k];
    x += add;
    if (t < NBUCK) bbase[t] = x - v;   // exclusive
}

// ---------------- per-bucket build: count -> offs -> exact scatter ----------------

__global__ __launch_bounds__(1024) void bucket_build(const unsigned* __restrict__ pairs,
                                                     const int* __restrict__ seg_start,
                                                     const int* __restrict__ seg_cnt,
                                                     const int* __restrict__ bbase,
                                                     int* __restrict__ offs,
                                                     int* __restrict__ csr_src) {
    int b = blockIdx.x, t = threadIdx.x;
    int nodeBase = b << 9;
    __shared__ int cur[512];
    __shared__ int pref[NBLK];
    __shared__ int sstart[NBLK];
    __shared__ int wt2[16];

    if (t < 512) cur[t] = 0;
    for (int j = t; j < NBLK; j += 1024) {
        pref[j]   = seg_cnt[(size_t)j * NBUCK + b];
        sstart[j] = seg_start[(size_t)j * NBUCK + b];
    }
    __syncthreads();
    for (int off = 1; off < NBLK; off <<= 1) {
        int v = 0;
        if (t < NBLK && t >= off) v = pref[t - off];
        __syncthreads();
        if (t < NBLK) pref[t] += v;
        __syncthreads();
    }
    int M = pref[NBLK - 1];

    for (int j = t; j < M; j += 1024) {
        int lo = 0, hi = NBLK - 1;
        while (lo < hi) { int mid = (lo + hi) >> 1; if (pref[mid] > j) hi = mid; else lo = mid + 1; }
        int within = j - (lo ? pref[lo - 1] : 0);
        unsigned wd = pairs[(size_t)lo * CHUNK + sstart[lo] + within];
        atomicAdd(&cur[wd & 511u], 1);
    }
    __syncthreads();

    int lane = t & 63, w = t >> 6;
    int myc = (t < 512) ? cur[t] : 0;
    int x = myc;
#pragma unroll
    for (int off = 1; off < 64; off <<= 1) {
        int u = __shfl_up(x, off);
        if (lane >= off) x += u;
    }
    if (lane == 63) wt2[w] = x;
    __syncthreads();
    int add = 0;
#pragma unroll
    for (int k = 0; k < 15; ++k) if (k < w) add += wt2[k];
    x += add;
    int gstart = bbase[b] + x - myc;
    if (t < 512) {
        if (nodeBase + t <= N_NODES) offs[nodeBase + t] = gstart;
        cur[t] = gstart;
    }
    __syncthreads();

    for (int j = t; j < M; j += 1024) {
        int lo = 0, hi = NBLK - 1;
        while (lo < hi) { int mid = (lo + hi) >> 1; if (pref[mid] > j) hi = mid; else lo = mid + 1; }
        int within = j - (lo ? pref[lo - 1] : 0);
        unsigned wd = pairs[(size_t)lo * CHUNK + sstart[lo] + within];
        int pos = atomicAdd(&cur[wd & 511u], 1);
        csr_src[pos] = (int)(wd >> 9);
    }
}

// ---------------- W -> bf16, fragment-ready layout Wt[k>>3][col][k&7] (both weights) --------

__global__ __launch_bounds__(256) void wtconv_both(const float* __restrict__ W1, const float* __restrict__ W2,
                                                   unsigned short* __restrict__ Wt1, unsigned short* __restrict__ Wt2) {
    int i = blockIdx.x * 256 + threadIdx.x;
    const float* W = (i < F_IN * HC) ? W1 : W2;
    unsigned short* Wt = (i < F_IN * HC) ? Wt1 : Wt2;
    int j = (i < F_IN * HC) ? i : i - F_IN * HC;
    if (j < F_IN * HC) {
        int k = j >> 7, col = j & 127;
        Wt[(size_t)(k >> 3) * (HC * 8) + col * 8 + (k & 7)] = f2bf_rne(W[j]);
    }
}

// ---------------- aggregation: 8-lane edge groups (unchanged from round 10) ----------------

__global__ __launch_bounds__(256) void agg_kernel(const int* __restrict__ offs, const int* __restrict__ csr_src,
                                                  const float* __restrict__ asrc, const float* __restrict__ adst,
                                                  const unsigned short* __restrict__ Hin,
                                                  const float* __restrict__ bias,
                                                  unsigned short* __restrict__ Hout, int do_relu) {
    int wid  = (blockIdx.x * 256 + threadIdx.x) >> 6;
    int lane = threadIdx.x & 63;
    if (wid >= N_NODES) return;
    int beg = offs[wid], end = offs[wid + 1];
    int grp   = lane >> 3;
    int head  = grp & 1;
    int eslot = grp >> 1;          // 0..3
    int q8    = lane & 7;
    float2 adv = *(const float2*)&adst[(size_t)wid * 2];
    float madst = head ? adv.y : adv.x;
    const float2* av = (const float2*)asrc;
    const unsigned short* hbase = Hin + head * 64 + q8 * 8;

    float den = 0.f;
    float a0c = 0.f, a1c = 0.f, a2c = 0.f, a3c = 0.f;
    float a4c = 0.f, a5c = 0.f, a6c = 0.f, a7c = 0.f;

    for (int e = beg + eslot; e < end; e += 8) {
        int en = e + 4;
        bool v1 = en < end;
        int s0 = csr_src[e];
        int s1 = v1 ? csr_src[en] : s0;
        float2 aa0 = av[s0];
        float2 aa1 = av[s1];
        uint4 g0 = *(const uint4*)&hbase[(size_t)s0 * HC];
        uint4 g1 = *(const uint4*)&hbase[(size_t)s1 * HC];
        float l0 = (head ? aa0.y : aa0.x) + madst; l0 = l0 > 0.f ? l0 : NEG_SLOPE * l0;
        float l1 = (head ? aa1.y : aa1.x) + madst; l1 = l1 > 0.f ? l1 : NEG_SLOPE * l1;
        float w0 = __expf(l0);
        float w1 = v1 ? __expf(l1) : 0.f;
        den += w0 + w1;
        a0c = fmaf(w1, bf2f(g1.x & 0xffffu), fmaf(w0, bf2f(g0.x & 0xffffu), a0c));
        a1c = fmaf(w1, bf2f(g1.x >> 16),     fmaf(w0, bf2f(g0.x >> 16),     a1c));
        a2c = fmaf(w1, bf2f(g1.y & 0xffffu), fmaf(w0, bf2f(g0.y & 0xffffu), a2c));
        a3c = fmaf(w1, bf2f(g1.y >> 16),     fmaf(w0, bf2f(g0.y >> 16),     a3c));
        a4c = fmaf(w1, bf2f(g1.z & 0xffffu), fmaf(w0, bf2f(g0.z & 0xffffu), a4c));
        a5c = fmaf(w1, bf2f(g1.z >> 16),     fmaf(w0, bf2f(g0.z >> 16),     a5c));
        a6c = fmaf(w1, bf2f(g1.w & 0xffffu), fmaf(w0, bf2f(g0.w & 0xffffu), a6c));
        a7c = fmaf(w1, bf2f(g1.w >> 16),     fmaf(w0, bf2f(g0.w >> 16),     a7c));
    }

#pragma unroll
    for (int off = 16; off <= 32; off <<= 1) {
        den += __shfl_xor(den, off);
        a0c += __shfl_xor(a0c, off);
        a1c += __shfl_xor(a1c, off);
        a2c += __shfl_xor(a2c, off);
        a3c += __shfl_xor(a3c, off);
        a4c += __shfl_xor(a4c, off);
        a5c += __shfl_xor(a5c, off);
        a6c += __shfl_xor(a6c, off);
        a7c += __shfl_xor(a7c, off);
    }

    if (lane < 16) {
        float inv = 1.0f / den;
        float4 b0 = *(const float4*)&bias[lane * 8];
        float4 b1 = *(const float4*)&bias[lane * 8 + 4];
        float o0 = fmaf(a0c, inv, b0.x);
        float o1 = fmaf(a1c, inv, b0.y);
        float o2 = fmaf(a2c, inv, b0.z);
        float o3 = fmaf(a3c, inv, b0.w);
        float o4 = fmaf(a4c, inv, b1.x);
        float o5 = fmaf(a5c, inv, b1.y);
        float o6 = fmaf(a6c, inv, b1.z);
        float o7 = fmaf(a7c, inv, b1.w);
        if (do_relu) {
            o0 = fmaxf(o0, 0.f); o1 = fmaxf(o1, 0.f); o2 = fmaxf(o2, 0.f); o3 = fmaxf(o3, 0.f);
            o4 = fmaxf(o4, 0.f); o5 = fmaxf(o5, 0.f); o6 = fmaxf(o6, 0.f); o7 = fmaxf(o7, 0.f);
        }
        uint4 st;
        st.x = (unsigned)f2bf_rne(o0) | ((unsigned)f2bf_rne(o1) << 16);
        st.y = (unsigned)f2bf_rne(o2) | ((unsigned)f2bf_rne(o3) << 16);
        st.z = (unsigned)f2bf_rne(o4) | ((unsigned)f2bf_rne(o5) << 16);
        st.w = (unsigned)f2bf_rne(o6) | ((unsigned)f2bf_rne(o7) << 16);
        *(uint4*)&Hout[(size_t)wid * HC + lane * 8] = st;
    }
}

// ---------------- mean pool (bf16 input; 8K atomics only) ----------------

__global__ __launch_bounds__(256) void pool_kernel(const unsigned short* __restrict__ H2,
                                                   const int* __restrict__ counts,
                                                   float* __restrict__ out) {
    int g = blockIdx.x;
    int chunk = blockIdx.y;
    __shared__ int soff, scnt;
    if (threadIdx.x == 0) {
        int s = 0;
        for (int i = 0; i < g; ++i) s += counts[i];
        soff = s; scnt = counts[g];
    }
    __syncthreads();
    int start = soff, cnt = scnt;
    int r = threadIdx.x >> 7;
    int c = threadIdx.x & 127;
    float acc = 0.f;
    for (int v = chunk * 2 + r; v < cnt; v += 16)
        acc += bf2f((unsigned)H2[(size_t)(start + v) * HC + c]);
    float inv = 1.0f / fmaxf((float)cnt, 1.0f);
    atomicAdd(&out[g * HC + c], acc * inv);
}

// ---------------- launch ----------------

extern "C" void kernel_launch(void* const* d_in, const int* in_sizes, int n_in,
                              void* d_out, int out_size, void* d_ws, size_t ws_size,
                              hipStream_t stream) {
    const float* x     = (const float*)d_in[0];
    const int*   ei    = (const int*)d_in[1];
    const int*   batch = (const int*)d_in[2];
    const float* W1    = (const float*)d_in[3];
    const float* a1s   = (const float*)d_in[4];
    const float* a1d   = (const float*)d_in[5];
    const float* b1    = (const float*)d_in[6];
    const float* W2    = (const float*)d_in[7];
    const float* a2s   = (const float*)d_in[8];
    const float* a2d   = (const float*)d_in[9];
    const float* b2    = (const float*)d_in[10];
    float* out = (float*)d_out;

    char* ws = (char*)d_ws;
    const size_t NH = (size_t)N_NODES * HC;                 // elements per h buffer
    unsigned short* hA = (unsigned short*)ws;               // 25.6 MB
    unsigned short* hB = hA + NH;                           // 25.6 MB
    unsigned* pairs = (unsigned*)(hB + NH);                 // NBLK*CHUNK*4 = 6.8 MB
    float* asrc = (float*)(pairs + (size_t)NBLK * CHUNK);
    float* adst = asrc + (size_t)N_NODES * 2;
    unsigned short* wt1 = (unsigned short*)(adst + (size_t)N_NODES * 2);
    unsigned short* wt2 = wt1 + F_IN * HC;
    int*   offs = (int*)(wt2 + F_IN * HC);
    int*   csr  = offs + (N_NODES + 1);
    int*   seg_start = csr + TOT_E;
    int*   seg_cnt   = seg_start + (size_t)NBLK * NBUCK;
    int*   btot = seg_cnt + (size_t)NBLK * NBUCK;
    int*   bbase = btot + NBUCK;
    int*   counts = bbase + NBUCK;

    hipMemsetAsync(counts, 0, NGRAPH * sizeof(int), stream);
    hipMemsetAsync(out, 0, (size_t)out_size * sizeof(float), stream);

    // weights -> bf16 fragment layout (both layers, one launch)
    wtconv_both<<<(2 * F_IN * HC + 255) / 256, 256, 0, stream>>>(W1, W2, wt1, wt2);

    // fused: gemm1(+alpha) ⊗ binpart ⊗ counts
    fused_main<<<GEMM_B + NBLK + CNT_B, 256, 0, stream>>>(x, wt1, hA, a1s, a1d, asrc, adst,
                                                          ei, pairs, seg_start, seg_cnt,
                                                          batch, counts);

    // CSR finalize
    btot_kernel<<<NBUCK, 256, 0, stream>>>(seg_cnt, btot);
    bbase_kernel<<<1, 256, 0, stream>>>(btot, bbase);
    bucket_build<<<NBUCK, 1024, 0, stream>>>(pairs, seg_start, seg_cnt, bbase, offs, csr);

    int waveBlocks = (N_NODES + 3) / 4;

    // layer 1 aggregation
    agg_kernel<<<waveBlocks, 256, 0, stream>>>(offs, csr, asrc, adst, hA, b1, hB, 1);

    // layer 2
    gemm2_kernel<<<GEMM_B, 256, 0, stream>>>(hB, wt2, hA, a2s, a2d, asrc, adst);
    agg_kernel<<<waveBlocks, 256, 0, stream>>>(offs, csr, asrc, adst, hA, b2, hB, 0);

    // pool
    pool_kernel<<<dim3(NGRAPH, 8), 256, 0, stream>>>(hB, counts, out);
}

// Round 12
// 254.823 us; speedup vs baseline: 5.0397x; 1.0676x over previous
//
#include <hip/hip_runtime.h>

#define N_NODES 100000
#define N_EDGES 1600000
#define F_IN    128
#define HC      128     // H * C
#define NGRAPH  64
#define NEG_SLOPE 0.2f

static constexpr int TOT_E = N_EDGES + N_NODES;         // with self loops

// CSR binned build
#define CHUNK  2048
#define NBLK   831            // ceil(TOT_E / CHUNK)
#define NBUCK  196            // ceil(N_NODES / 512), bucket = dst >> 9

#define GEMM_B 1563           // ceil(N_NODES / 64)
#define CNT_B  391            // ceil(N_NODES / 256)

typedef __bf16 bf16x8 __attribute__((ext_vector_type(8)));
typedef float  f32x4  __attribute__((ext_vector_type(4)));
typedef float  f32x2  __attribute__((ext_vector_type(2)));

__device__ __forceinline__ unsigned short f2bf_rne(float f) {
    unsigned u = __float_as_uint(f);
    u += 0x7fffu + ((u >> 16) & 1u);
    return (unsigned short)(u >> 16);
}
__device__ __forceinline__ float bf2f(unsigned b) {        // low 16 bits used
    return __uint_as_float(b << 16);
}
__device__ __forceinline__ unsigned char f2fp8(float f) {  // OCP e4m3, HW RNE
    return (unsigned char)(__builtin_amdgcn_cvt_pk_fp8_f32(f, f, 0, 0) & 0xff);
}

// ---------------- device bodies ----------------

// binned partition: edges -> block-local bucket-grouped packed pairs. word = (src<<9)|(dst&511)
__device__ __forceinline__ void binpart_body(int blk, int t,
                                             const int* __restrict__ ei,
                                             unsigned* __restrict__ pairs,
                                             int* __restrict__ seg_start,
                                             int* __restrict__ seg_cnt,
                                             int* cnt, int* wtot) {
    int lane = t & 63, w = t >> 6;
    long base = (long)blk * CHUNK;

    cnt[t] = 0;
    __syncthreads();

    for (int j = t; j < CHUNK; j += 256) {
        long i = base + j;
        int d = -1;
        if (i < N_EDGES)    d = ei[N_EDGES + i];
        else if (i < TOT_E) d = (int)(i - N_EDGES);
        if (d >= 0) atomicAdd(&cnt[d >> 9], 1);
    }
    __syncthreads();

    int c = cnt[t];
    int x = c;
#pragma unroll
    for (int off = 1; off < 64; off <<= 1) {
        int v = __shfl_up(x, off);
        if (lane >= off) x += v;
    }
    if (lane == 63) wtot[w] = x;
    __syncthreads();
    int add = 0;
#pragma unroll
    for (int k = 0; k < 3; ++k) if (k < w) add += wtot[k];
    x += add;
    int st = x - c;
    if (t < NBUCK) {
        seg_start[(size_t)blk * NBUCK + t] = st;
        seg_cnt[(size_t)blk * NBUCK + t]   = c;
    }
    __syncthreads();
    cnt[t] = st;
    __syncthreads();

    for (int j = t; j < CHUNK; j += 256) {
        long i = base + j;
        int s = -1, d = -1;
        if (i < N_EDGES)    { s = ei[i]; d = ei[N_EDGES + i]; }
        else if (i < TOT_E) { s = (int)(i - N_EDGES); d = s; }
        if (d >= 0) {
            int pos = atomicAdd(&cnt[d >> 9], 1);
            pairs[base + pos] = ((unsigned)s << 9) | ((unsigned)d & 511u);
        }
    }
}

// GEMM tile + fused alpha epilogue. H stored fp8 e4m3 (gather table); alpha from fp32 acc.
template<bool BF16IN>
__device__ __forceinline__ void gemm_body(int gbid, int t,
                                          const void* __restrict__ Xv,
                                          const unsigned short* __restrict__ Wt,
                                          unsigned char* __restrict__ Hout,
                                          const float* __restrict__ a_src,
                                          const float* __restrict__ a_dst,
                                          float* __restrict__ asrc,
                                          float* __restrict__ adst,
                                          unsigned short* A_lds) {
    int lane = t & 63, wave = t >> 6;
    int wc = wave & 1, wr = wave >> 1;
    int base = gbid * 64;

    bf16x8 Bf[4][4];
    {
        int colb = wc * 64 + (lane & 15);
        int kbb  = lane >> 4;
#pragma unroll
        for (int ct = 0; ct < 4; ++ct)
#pragma unroll
            for (int ks = 0; ks < 4; ++ks) {
                int kb = kbb + 4 * ks;
                Bf[ct][ks] = *(const bf16x8*)&Wt[(size_t)kb * (HC * 8) + (colb + ct * 16) * 8];
            }
    }

#pragma unroll
    for (int it = 0; it < 8; ++it) {
        int i = t + it * 256;
        int row = i >> 5, c4 = i & 31, k0 = c4 * 4;
        uint2 pk; pk.x = 0; pk.y = 0;
        if (base + row < N_NODES) {
            if (BF16IN) {
                pk = ((const uint2*)Xv)[(size_t)(base + row) * 32 + c4];
            } else {
                float4 v = ((const float4*)Xv)[(size_t)(base + row) * 32 + c4];
                pk.x = (unsigned)f2bf_rne(v.x) | ((unsigned)f2bf_rne(v.y) << 16);
                pk.y = (unsigned)f2bf_rne(v.z) | ((unsigned)f2bf_rne(v.w) << 16);
            }
        }
        int byte = row * 256 + (((k0 >> 3) ^ (row & 7)) << 4) + (k0 & 4) * 2;
        *(uint2*)((char*)A_lds + byte) = pk;
    }
    __syncthreads();

    f32x4 acc[2][4] = {};
#pragma unroll
    for (int ks = 0; ks < 4; ++ks) {
        bf16x8 Af[2];
#pragma unroll
        for (int r = 0; r < 2; ++r) {
            int row = wr * 32 + r * 16 + (lane & 15);
            int kb  = ks * 4 + (lane >> 4);
            int byte = row * 256 + ((kb ^ (row & 7)) << 4);
            Af[r] = *(const bf16x8*)((const char*)A_lds + byte);
        }
#pragma unroll
        for (int ct = 0; ct < 4; ++ct) {
            acc[0][ct] = __builtin_amdgcn_mfma_f32_16x16x32_bf16(Af[0], Bf[ct][ks], acc[0][ct], 0, 0, 0);
            acc[1][ct] = __builtin_amdgcn_mfma_f32_16x16x32_bf16(Af[1], Bf[ct][ks], acc[1][ct], 0, 0, 0);
        }
    }

    // H store (fp8 e4m3)
#pragma unroll
    for (int r = 0; r < 2; ++r) {
        int row0 = base + wr * 32 + r * 16 + (lane >> 4) * 4;
#pragma unroll
        for (int reg = 0; reg < 4; ++reg) {
            int row = row0 + reg;
            if (row < N_NODES) {
#pragma unroll
                for (int ct = 0; ct < 4; ++ct) {
                    int col = wc * 64 + ct * 16 + (lane & 15);
                    Hout[(size_t)row * HC + col] = f2fp8(acc[r][ct][reg]);
                }
            }
        }
    }

    // fused alpha (exact fp32 acc)
    float as_c[4], ad_c[4];
#pragma unroll
    for (int ct = 0; ct < 4; ++ct) {
        int ch = wc * 64 + ct * 16 + (lane & 15);
        as_c[ct] = a_src[ch];
        ad_c[ct] = a_dst[ch];
    }
#pragma unroll
    for (int r = 0; r < 2; ++r) {
#pragma unroll
        for (int reg = 0; reg < 4; ++reg) {
            float ps = acc[r][0][reg] * as_c[0] + acc[r][1][reg] * as_c[1]
                     + acc[r][2][reg] * as_c[2] + acc[r][3][reg] * as_c[3];
            float pd = acc[r][0][reg] * ad_c[0] + acc[r][1][reg] * ad_c[1]
                     + acc[r][2][reg] * ad_c[2] + acc[r][3][reg] * ad_c[3];
#pragma unroll
            for (int off = 1; off < 16; off <<= 1) {
                ps += __shfl_xor(ps, off);
                pd += __shfl_xor(pd, off);
            }
            if ((lane & 15) == 0) {
                int row = base + wr * 32 + r * 16 + (lane >> 4) * 4 + reg;
                if (row < N_NODES) {
                    asrc[(size_t)row * 2 + wc] = ps;
                    adst[(size_t)row * 2 + wc] = pd;
                }
            }
        }
    }
}

// ---------------- fused main: gemm1 ⊗ binpart ⊗ counts ----------------

__global__ __launch_bounds__(256) void fused_main(const float* __restrict__ x,
                                                  const unsigned short* __restrict__ wt1,
                                                  unsigned char* __restrict__ hA,
                                                  const float* __restrict__ a1s,
                                                  const float* __restrict__ a1d,
                                                  float* __restrict__ asrc,
                                                  float* __restrict__ adst,
                                                  const int* __restrict__ ei,
                                                  unsigned* __restrict__ pairs,
                                                  int* __restrict__ seg_start,
                                                  int* __restrict__ seg_cnt,
                                                  const int* __restrict__ batch,
                                                  int* __restrict__ counts) {
    __shared__ unsigned short A_lds[64 * F_IN];   // 16 KB (gemm branch)
    __shared__ int cnt[256];                      // binpart branch
    __shared__ int wtot[4];
    __shared__ int loc[NGRAPH];                   // counts branch
    int bid = blockIdx.x, t = threadIdx.x;

    if (bid < 2 * NBLK) {
        if (bid & 1) binpart_body(bid >> 1, t, ei, pairs, seg_start, seg_cnt, cnt, wtot);
        else         gemm_body<false>(bid >> 1, t, x, wt1, hA, a1s, a1d, asrc, adst, A_lds);
    } else if (bid < NBLK + GEMM_B) {
        gemm_body<false>(bid - NBLK, t, x, wt1, hA, a1s, a1d, asrc, adst, A_lds);
    } else {
        int cb = bid - (NBLK + GEMM_B);
        if (t < NGRAPH) loc[t] = 0;
        __syncthreads();
        int i = cb * 256 + t;
        if (i < N_NODES) atomicAdd(&loc[batch[i]], 1);
        __syncthreads();
        if (t < NGRAPH && loc[t]) atomicAdd(&counts[t], loc[t]);
    }
}

// ---------------- standalone gemm (layer 2: bf16 in, fp8 out) ----------------

__global__ __launch_bounds__(256) void gemm2_kernel(const unsigned short* __restrict__ Xv,
                                                    const unsigned short* __restrict__ Wt,
                                                    unsigned char* __restrict__ Hout,
                                                    const float* __restrict__ a_src,
                                                    const float* __restrict__ a_dst,
                                                    float* __restrict__ asrc,
                                                    float* __restrict__ adst) {
    __shared__ unsigned short A_lds[64 * F_IN];
    gemm_body<true>(blockIdx.x, threadIdx.x, Xv, Wt, Hout, a_src, a_dst, asrc, adst, A_lds);
}

// ---------------- per-bucket totals + base offsets ----------------

__global__ __launch_bounds__(256) void btot_kernel(const int* __restrict__ seg_cnt, int* __restrict__ btot) {
    int b = blockIdx.x, t = threadIdx.x;
    int s = 0;
    for (int j = t; j < NBLK; j += 256) s += seg_cnt[(size_t)j * NBUCK + b];
    for (int off = 32; off; off >>= 1) s += __shfl_down(s, off);
    __shared__ int ws[4];
    int lane = t & 63, w = t >> 6;
    if (lane == 0) ws[w] = s;
    __syncthreads();
    if (t == 0) btot[b] = ws[0] + ws[1] + ws[2] + ws[3];
}

__global__ __launch_bounds__(256) void bbase_kernel(const int* __restrict__ btot, int* __restrict__ bbase) {
    int t = threadIdx.x;
    int lane = t & 63, w = t >> 6;
    int v = (t < NBUCK) ? btot[t] : 0;
    int x = v;
#pragma unroll
    for (int off = 1; off < 64; off <<= 1) {
        int u = __shfl_up(x, off);
        if (lane >= off) x += u;
    }
    __shared__ int wt[4];
    if (lane == 63) wt[w] = x;
    __syncthreads();
    int add = 0;
#pragma unroll
    for (int k = 0; k < 3; ++k) if (k < w) add += wt[k];
    x += add;
    if (t < NBUCK) bbase[t] = x - v;   // exclusive
}

// ---------------- per-bucket build: count -> offs -> exact scatter ----------------

__global__ __launch_bounds__(1024) void bucket_build(const unsigned* __restrict__ pairs,
                                                     const int* __restrict__ seg_start,
                                                     const int* __restrict__ seg_cnt,
                                                     const int* __restrict__ bbase,
                                                     int* __restrict__ offs,
                                                     int* __restrict__ csr_src) {
    int b = blockIdx.x, t = threadIdx.x;
    int nodeBase = b << 9;
    __shared__ int cur[512];
    __shared__ int pref[NBLK];
    __shared__ int sstart[NBLK];
    __shared__ int wt2[16];

    if (t < 512) cur[t] = 0;
    for (int j = t; j < NBLK; j += 1024) {
        pref[j]   = seg_cnt[(size_t)j * NBUCK + b];
        sstart[j] = seg_start[(size_t)j * NBUCK + b];
    }
    __syncthreads();
    for (int off = 1; off < NBLK; off <<= 1) {
        int v = 0;
        if (t < NBLK && t >= off) v = pref[t - off];
        __syncthreads();
        if (t < NBLK) pref[t] += v;
        __syncthreads();
    }
    int M = pref[NBLK - 1];

    for (int j = t; j < M; j += 1024) {
        int lo = 0, hi = NBLK - 1;
        while (lo < hi) { int mid = (lo + hi) >> 1; if (pref[mid] > j) hi = mid; else lo = mid + 1; }
        int within = j - (lo ? pref[lo - 1] : 0);
        unsigned wd = pairs[(size_t)lo * CHUNK + sstart[lo] + within];
        atomicAdd(&cur[wd & 511u], 1);
    }
    __syncthreads();

    int lane = t & 63, w = t >> 6;
    int myc = (t < 512) ? cur[t] : 0;
    int x = myc;
#pragma unroll
    for (int off = 1; off < 64; off <<= 1) {
        int u = __shfl_up(x, off);
        if (lane >= off) x += u;
    }
    if (lane == 63) wt2[w] = x;
    __syncthreads();
    int add = 0;
#pragma unroll
    for (int k = 0; k < 15; ++k) if (k < w) add += wt2[k];
    x += add;
    int gstart = bbase[b] + x - myc;
    if (t < 512) {
        if (nodeBase + t <= N_NODES) offs[nodeBase + t] = gstart;
        cur[t] = gstart;
    }
    __syncthreads();

    for (int j = t; j < M; j += 1024) {
        int lo = 0, hi = NBLK - 1;
        while (lo < hi) { int mid = (lo + hi) >> 1; if (pref[mid] > j) hi = mid; else lo = mid + 1; }
        int within = j - (lo ? pref[lo - 1] : 0);
        unsigned wd = pairs[(size_t)lo * CHUNK + sstart[lo] + within];
        int pos = atomicAdd(&cur[wd & 511u], 1);
        csr_src[pos] = (int)(wd >> 9);
    }
}

// ---------------- W -> bf16, fragment-ready layout (both weights) ----------------

__global__ __launch_bounds__(256) void wtconv_both(const float* __restrict__ W1, const float* __restrict__ W2,
                                                   unsigned short* __restrict__ Wt1, unsigned short* __restrict__ Wt2) {
    int i = blockIdx.x * 256 + threadIdx.x;
    const float* W = (i < F_IN * HC) ? W1 : W2;
    unsigned short* Wt = (i < F_IN * HC) ? Wt1 : Wt2;
    int j = (i < F_IN * HC) ? i : i - F_IN * HC;
    if (j < F_IN * HC) {
        int k = j >> 7, col = j & 127;
        Wt[(size_t)(k >> 3) * (HC * 8) + col * 8 + (k & 7)] = f2bf_rne(W[j]);
    }
}

// ---------------- aggregation: 8-lane edge groups, fp8 h gather ----------------
// grp = lane>>3; head = grp&1; eslot = grp>>1; q8 = lane&7 holds channels head*64+q8*8
// (8 fp8 = 8 B). Output hB stays bf16 (lanes 0..15, channels lane*8).

__global__ __launch_bounds__(256) void agg_kernel(const int* __restrict__ offs, const int* __restrict__ csr_src,
                                                  const float* __restrict__ asrc, const float* __restrict__ adst,
                                                  const unsigned char* __restrict__ Hin,
                                                  const float* __restrict__ bias,
                                                  unsigned short* __restrict__ Hout, int do_relu) {
    int wid  = (blockIdx.x * 256 + threadIdx.x) >> 6;
    int lane = threadIdx.x & 63;
    if (wid >= N_NODES) return;
    int beg = offs[wid], end = offs[wid + 1];
    int grp   = lane >> 3;
    int head  = grp & 1;
    int eslot = grp >> 1;          // 0..3
    int q8    = lane & 7;
    float2 adv = *(const float2*)&adst[(size_t)wid * 2];
    float madst = head ? adv.y : adv.x;
    const float2* av = (const float2*)asrc;
    const unsigned char* hbase = Hin + head * 64 + q8 * 8;

    float den = 0.f;
    float a0c = 0.f, a1c = 0.f, a2c = 0.f, a3c = 0.f;
    float a4c = 0.f, a5c = 0.f, a6c = 0.f, a7c = 0.f;

    for (int e = beg + eslot; e < end; e += 8) {
        int en = e + 4;
        bool v1 = en < end;
        int s0 = csr_src[e];
        int s1 = v1 ? csr_src[en] : s0;
        float2 aa0 = av[s0];
        float2 aa1 = av[s1];
        uint2 g0 = *(const uint2*)&hbase[(size_t)s0 * HC];
        uint2 g1 = *(const uint2*)&hbase[(size_t)s1 * HC];
        float l0 = (head ? aa0.y : aa0.x) + madst; l0 = l0 > 0.f ? l0 : NEG_SLOPE * l0;
        float l1 = (head ? aa1.y : aa1.x) + madst; l1 = l1 > 0.f ? l1 : NEG_SLOPE * l1;
        float w0 = __expf(l0);
        float w1 = v1 ? __expf(l1) : 0.f;
        den += w0 + w1;
        f32x2 p00 = __builtin_amdgcn_cvt_pk_f32_fp8(g0.x, 0);
        f32x2 p01 = __builtin_amdgcn_cvt_pk_f32_fp8(g0.x, 1);
        f32x2 p02 = __builtin_amdgcn_cvt_pk_f32_fp8(g0.y, 0);
        f32x2 p03 = __builtin_amdgcn_cvt_pk_f32_fp8(g0.y, 1);
        f32x2 p10 = __builtin_amdgcn_cvt_pk_f32_fp8(g1.x, 0);
        f32x2 p11 = __builtin_amdgcn_cvt_pk_f32_fp8(g1.x, 1);
        f32x2 p12 = __builtin_amdgcn_cvt_pk_f32_fp8(g1.y, 0);
        f32x2 p13 = __builtin_amdgcn_cvt_pk_f32_fp8(g1.y, 1);
        a0c = fmaf(w1, p10.x, fmaf(w0, p00.x, a0c));
        a1c = fmaf(w1, p10.y, fmaf(w0, p00.y, a1c));
        a2c = fmaf(w1, p11.x, fmaf(w0, p01.x, a2c));
        a3c = fmaf(w1, p11.y, fmaf(w0, p01.y, a3c));
        a4c = fmaf(w1, p12.x, fmaf(w0, p02.x, a4c));
        a5c = fmaf(w1, p12.y, fmaf(w0, p02.y, a5c));
        a6c = fmaf(w1, p13.x, fmaf(w0, p03.x, a6c));
        a7c = fmaf(w1, p13.y, fmaf(w0, p03.y, a7c));
    }

#pragma unroll
    for (int off = 16; off <= 32; off <<= 1) {
        den += __shfl_xor(den, off);
        a0c += __shfl_xor(a0c, off);
        a1c += __shfl_xor(a1c, off);
        a2c += __shfl_xor(a2c, off);
        a3c += __shfl_xor(a3c, off);
        a4c += __shfl_xor(a4c, off);
        a5c += __shfl_xor(a5c, off);
        a6c += __shfl_xor(a6c, off);
        a7c += __shfl_xor(a7c, off);
    }

    if (lane < 16) {
        float inv = 1.0f / den;
        float4 b0 = *(const float4*)&bias[lane * 8];
        float4 b1 = *(const float4*)&bias[lane * 8 + 4];
        float o0 = fmaf(a0c, inv, b0.x);
        float o1 = fmaf(a1c, inv, b0.y);
        float o2 = fmaf(a2c, inv, b0.z);
        float o3 = fmaf(a3c, inv, b0.w);
        float o4 = fmaf(a4c, inv, b1.x);
        float o5 = fmaf(a5c, inv, b1.y);
        float o6 = fmaf(a6c, inv, b1.z);
        float o7 = fmaf(a7c, inv, b1.w);
        if (do_relu) {
            o0 = fmaxf(o0, 0.f); o1 = fmaxf(o1, 0.f); o2 = fmaxf(o2, 0.f); o3 = fmaxf(o3, 0.f);
            o4 = fmaxf(o4, 0.f); o5 = fmaxf(o5, 0.f); o6 = fmaxf(o6, 0.f); o7 = fmaxf(o7, 0.f);
        }
        uint4 st;
        st.x = (unsigned)f2bf_rne(o0) | ((unsigned)f2bf_rne(o1) << 16);
        st.y = (unsigned)f2bf_rne(o2) | ((unsigned)f2bf_rne(o3) << 16);
        st.z = (unsigned)f2bf_rne(o4) | ((unsigned)f2bf_rne(o5) << 16);
        st.w = (unsigned)f2bf_rne(o6) | ((unsigned)f2bf_rne(o7) << 16);
        *(uint4*)&Hout[(size_t)wid * HC + lane * 8] = st;
    }
}

// ---------------- mean pool (bf16 input; 8K atomics only) ----------------

__global__ __launch_bounds__(256) void pool_kernel(const unsigned short* __restrict__ H2,
                                                   const int* __restrict__ counts,
                                                   float* __restrict__ out) {
    int g = blockIdx.x;
    int chunk = blockIdx.y;
    __shared__ int soff, scnt;
    if (threadIdx.x == 0) {
        int s = 0;
        for (int i = 0; i < g; ++i) s += counts[i];
        soff = s; scnt = counts[g];
    }
    __syncthreads();
    int start = soff, cnt = scnt;
    int r = threadIdx.x >> 7;
    int c = threadIdx.x & 127;
    float acc = 0.f;
    for (int v = chunk * 2 + r; v < cnt; v += 16)
        acc += bf2f((unsigned)H2[(size_t)(start + v) * HC + c]);
    float inv = 1.0f / fmaxf((float)cnt, 1.0f);
    atomicAdd(&out[g * HC + c], acc * inv);
}

// ---------------- launch ----------------

extern "C" void kernel_launch(void* const* d_in, const int* in_sizes, int n_in,
                              void* d_out, int out_size, void* d_ws, size_t ws_size,
                              hipStream_t stream) {
    const float* x     = (const float*)d_in[0];
    const int*   ei    = (const int*)d_in[1];
    const int*   batch = (const int*)d_in[2];
    const float* W1    = (const float*)d_in[3];
    const float* a1s   = (const float*)d_in[4];
    const float* a1d   = (const float*)d_in[5];
    const float* b1    = (const float*)d_in[6];
    const float* W2    = (const float*)d_in[7];
    const float* a2s   = (const float*)d_in[8];
    const float* a2d   = (const float*)d_in[9];
    const float* b2    = (const float*)d_in[10];
    float* out = (float*)d_out;

    char* ws = (char*)d_ws;
    const size_t NH = (size_t)N_NODES * HC;
    unsigned char* hA = (unsigned char*)ws;                 // fp8 gather table, 12.8 MB
    unsigned short* hB = (unsigned short*)(ws + NH);        // bf16, 25.6 MB
    unsigned* pairs = (unsigned*)(hB + NH);                 // 6.8 MB
    float* asrc = (float*)(pairs + (size_t)NBLK * CHUNK);
    float* adst = asrc + (size_t)N_NODES * 2;
    unsigned short* wt1 = (unsigned short*)(adst + (size_t)N_NODES * 2);
    unsigned short* wt2 = wt1 + F_IN * HC;
    int*   offs = (int*)(wt2 + F_IN * HC);
    int*   csr  = offs + (N_NODES + 1);
    int*   seg_start = csr + TOT_E;
    int*   seg_cnt   = seg_start + (size_t)NBLK * NBUCK;
    int*   btot = seg_cnt + (size_t)NBLK * NBUCK;
    int*   bbase = btot + NBUCK;
    int*   counts = bbase + NBUCK;

    hipMemsetAsync(counts, 0, NGRAPH * sizeof(int), stream);
    hipMemsetAsync(out, 0, (size_t)out_size * sizeof(float), stream);

    // weights -> bf16 fragment layout (both layers, one launch)
    wtconv_both<<<(2 * F_IN * HC + 255) / 256, 256, 0, stream>>>(W1, W2, wt1, wt2);

    // fused: gemm1(+alpha) ⊗ binpart ⊗ counts
    fused_main<<<GEMM_B + NBLK + CNT_B, 256, 0, stream>>>(x, wt1, hA, a1s, a1d, asrc, adst,
                                                          ei, pairs, seg_start, seg_cnt,
                                                          batch, counts);

    // CSR finalize
    btot_kernel<<<NBUCK, 256, 0, stream>>>(seg_cnt, btot);
    bbase_kernel<<<1, 256, 0, stream>>>(btot, bbase);
    bucket_build<<<NBUCK, 1024, 0, stream>>>(pairs, seg_start, seg_cnt, bbase, offs, csr);

    int waveBlocks = (N_NODES + 3) / 4;

    // layer 1 aggregation
    agg_kernel<<<waveBlocks, 256, 0, stream>>>(offs, csr, asrc, adst, hA, b1, hB, 1);

    // layer 2
    gemm2_kernel<<<GEMM_B, 256, 0, stream>>>(hB, wt2, hA, a2s, a2d, asrc, adst);
    agg_kernel<<<waveBlocks, 256, 0, stream>>>(offs, csr, asrc, adst, hA, b2, hB, 0);

    // pool
    pool_kernel<<<dim3(NGRAPH, 8), 256, 0, stream>>>(hB, counts, out);
}

// Round 13
// 247.980 us; speedup vs baseline: 5.1787x; 1.0276x over previous
//
#include <hip/hip_runtime.h>

#define N_NODES 100000
#define N_EDGES 1600000
#define F_IN    128
#define HC      128     // H * C
#define NGRAPH  64
#define NEG_SLOPE 0.2f

static constexpr int TOT_E = N_EDGES + N_NODES;         // with self loops

// CSR binned build
#define CHUNK  2048
#define NBLK   831            // ceil(TOT_E / CHUNK)
#define NBUCK  196            // ceil(N_NODES / 512), bucket = dst >> 9

#define GEMM_B 1563           // ceil(N_NODES / 64)
#define CNT_B  391            // ceil(N_NODES / 256)

typedef __bf16 bf16x8 __attribute__((ext_vector_type(8)));
typedef float  f32x4  __attribute__((ext_vector_type(4)));
typedef float  f32x2  __attribute__((ext_vector_type(2)));

__device__ __forceinline__ unsigned short f2bf_rne(float f) {
    unsigned u = __float_as_uint(f);
    u += 0x7fffu + ((u >> 16) & 1u);
    return (unsigned short)(u >> 16);
}
__device__ __forceinline__ float bf2f(unsigned b) {        // low 16 bits used
    return __uint_as_float(b << 16);
}
__device__ __forceinline__ unsigned char f2fp8(float f) {  // OCP e4m3, HW RNE
    return (unsigned char)(__builtin_amdgcn_cvt_pk_fp8_f32(f, f, 0, 0) & 0xff);
}

// ---------------- device bodies ----------------

// binned partition: edges -> block-local bucket-grouped packed pairs. word = (src<<9)|(dst&511)
__device__ __forceinline__ void binpart_body(int blk, int t,
                                             const int* __restrict__ ei,
                                             unsigned* __restrict__ pairs,
                                             int* __restrict__ seg_start,
                                             int* __restrict__ seg_cnt,
                                             int* cnt, int* wtot) {
    int lane = t & 63, w = t >> 6;
    long base = (long)blk * CHUNK;

    cnt[t] = 0;
    __syncthreads();

    for (int j = t; j < CHUNK; j += 256) {
        long i = base + j;
        int d = -1;
        if (i < N_EDGES)    d = ei[N_EDGES + i];
        else if (i < TOT_E) d = (int)(i - N_EDGES);
        if (d >= 0) atomicAdd(&cnt[d >> 9], 1);
    }
    __syncthreads();

    int c = cnt[t];
    int x = c;
#pragma unroll
    for (int off = 1; off < 64; off <<= 1) {
        int v = __shfl_up(x, off);
        if (lane >= off) x += v;
    }
    if (lane == 63) wtot[w] = x;
    __syncthreads();
    int add = 0;
#pragma unroll
    for (int k = 0; k < 3; ++k) if (k < w) add += wtot[k];
    x += add;
    int st = x - c;
    if (t < NBUCK) {
        seg_start[(size_t)blk * NBUCK + t] = st;
        seg_cnt[(size_t)blk * NBUCK + t]   = c;
    }
    __syncthreads();
    cnt[t] = st;
    __syncthreads();

    for (int j = t; j < CHUNK; j += 256) {
        long i = base + j;
        int s = -1, d = -1;
        if (i < N_EDGES)    { s = ei[i]; d = ei[N_EDGES + i]; }
        else if (i < TOT_E) { s = (int)(i - N_EDGES); d = s; }
        if (d >= 0) {
            int pos = atomicAdd(&cnt[d >> 9], 1);
            pairs[base + pos] = ((unsigned)s << 9) | ((unsigned)d & 511u);
        }
    }
}

// GEMM tile + fused alpha epilogue. H stored fp8 e4m3 (gather table); alpha from fp32 acc.
template<bool BF16IN>
__device__ __forceinline__ void gemm_body(int gbid, int t,
                                          const void* __restrict__ Xv,
                                          const unsigned short* __restrict__ Wt,
                                          unsigned char* __restrict__ Hout,
                                          const float* __restrict__ a_src,
                                          const float* __restrict__ a_dst,
                                          float* __restrict__ asrc,
                                          float* __restrict__ adst,
                                          unsigned short* A_lds) {
    int lane = t & 63, wave = t >> 6;
    int wc = wave & 1, wr = wave >> 1;
    int base = gbid * 64;

    bf16x8 Bf[4][4];
    {
        int colb = wc * 64 + (lane & 15);
        int kbb  = lane >> 4;
#pragma unroll
        for (int ct = 0; ct < 4; ++ct)
#pragma unroll
            for (int ks = 0; ks < 4; ++ks) {
                int kb = kbb + 4 * ks;
                Bf[ct][ks] = *(const bf16x8*)&Wt[(size_t)kb * (HC * 8) + (colb + ct * 16) * 8];
            }
    }

#pragma unroll
    for (int it = 0; it < 8; ++it) {
        int i = t + it * 256;
        int row = i >> 5, c4 = i & 31, k0 = c4 * 4;
        uint2 pk; pk.x = 0; pk.y = 0;
        if (base + row < N_NODES) {
            if (BF16IN) {
                pk = ((const uint2*)Xv)[(size_t)(base + row) * 32 + c4];
            } else {
                float4 v = ((const float4*)Xv)[(size_t)(base + row) * 32 + c4];
                pk.x = (unsigned)f2bf_rne(v.x) | ((unsigned)f2bf_rne(v.y) << 16);
                pk.y = (unsigned)f2bf_rne(v.z) | ((unsigned)f2bf_rne(v.w) << 16);
            }
        }
        int byte = row * 256 + (((k0 >> 3) ^ (row & 7)) << 4) + (k0 & 4) * 2;
        *(uint2*)((char*)A_lds + byte) = pk;
    }
    __syncthreads();

    f32x4 acc[2][4] = {};
#pragma unroll
    for (int ks = 0; ks < 4; ++ks) {
        bf16x8 Af[2];
#pragma unroll
        for (int r = 0; r < 2; ++r) {
            int row = wr * 32 + r * 16 + (lane & 15);
            int kb  = ks * 4 + (lane >> 4);
            int byte = row * 256 + ((kb ^ (row & 7)) << 4);
            Af[r] = *(const bf16x8*)((const char*)A_lds + byte);
        }
#pragma unroll
        for (int ct = 0; ct < 4; ++ct) {
            acc[0][ct] = __builtin_amdgcn_mfma_f32_16x16x32_bf16(Af[0], Bf[ct][ks], acc[0][ct], 0, 0, 0);
            acc[1][ct] = __builtin_amdgcn_mfma_f32_16x16x32_bf16(Af[1], Bf[ct][ks], acc[1][ct], 0, 0, 0);
        }
    }

    // H store (fp8 e4m3)
#pragma unroll
    for (int r = 0; r < 2; ++r) {
        int row0 = base + wr * 32 + r * 16 + (lane >> 4) * 4;
#pragma unroll
        for (int reg = 0; reg < 4; ++reg) {
            int row = row0 + reg;
            if (row < N_NODES) {
#pragma unroll
                for (int ct = 0; ct < 4; ++ct) {
                    int col = wc * 64 + ct * 16 + (lane & 15);
                    Hout[(size_t)row * HC + col] = f2fp8(acc[r][ct][reg]);
                }
            }
        }
    }

    // fused alpha (exact fp32 acc)
    float as_c[4], ad_c[4];
#pragma unroll
    for (int ct = 0; ct < 4; ++ct) {
        int ch = wc * 64 + ct * 16 + (lane & 15);
        as_c[ct] = a_src[ch];
        ad_c[ct] = a_dst[ch];
    }
#pragma unroll
    for (int r = 0; r < 2; ++r) {
#pragma unroll
        for (int reg = 0; reg < 4; ++reg) {
            float ps = acc[r][0][reg] * as_c[0] + acc[r][1][reg] * as_c[1]
                     + acc[r][2][reg] * as_c[2] + acc[r][3][reg] * as_c[3];
            float pd = acc[r][0][reg] * ad_c[0] + acc[r][1][reg] * ad_c[1]
                     + acc[r][2][reg] * ad_c[2] + acc[r][3][reg] * ad_c[3];
#pragma unroll
            for (int off = 1; off < 16; off <<= 1) {
                ps += __shfl_xor(ps, off);
                pd += __shfl_xor(pd, off);
            }
            if ((lane & 15) == 0) {
                int row = base + wr * 32 + r * 16 + (lane >> 4) * 4 + reg;
                if (row < N_NODES) {
                    asrc[(size_t)row * 2 + wc] = ps;
                    adst[(size_t)row * 2 + wc] = pd;
                }
            }
        }
    }
}

// ---------------- fused main: gemm1 ⊗ binpart ⊗ counts ----------------

__global__ __launch_bounds__(256) void fused_main(const float* __restrict__ x,
                                                  const unsigned short* __restrict__ wt1,
                                                  unsigned char* __restrict__ hA,
                                                  const float* __restrict__ a1s,
                                                  const float* __restrict__ a1d,
                                                  float* __restrict__ asrc,
                                                  float* __restrict__ adst,
                                                  const int* __restrict__ ei,
                                                  unsigned* __restrict__ pairs,
                                                  int* __restrict__ seg_start,
                                                  int* __restrict__ seg_cnt,
                                                  const int* __restrict__ batch,
                                                  int* __restrict__ counts) {
    __shared__ unsigned short A_lds[64 * F_IN];   // 16 KB (gemm branch)
    __shared__ int cnt[256];                      // binpart branch
    __shared__ int wtot[4];
    __shared__ int loc[NGRAPH];                   // counts branch
    int bid = blockIdx.x, t = threadIdx.x;

    if (bid < 2 * NBLK) {
        if (bid & 1) binpart_body(bid >> 1, t, ei, pairs, seg_start, seg_cnt, cnt, wtot);
        else         gemm_body<false>(bid >> 1, t, x, wt1, hA, a1s, a1d, asrc, adst, A_lds);
    } else if (bid < NBLK + GEMM_B) {
        gemm_body<false>(bid - NBLK, t, x, wt1, hA, a1s, a1d, asrc, adst, A_lds);
    } else {
        int cb = bid - (NBLK + GEMM_B);
        if (t < NGRAPH) loc[t] = 0;
        __syncthreads();
        int i = cb * 256 + t;
        if (i < N_NODES) atomicAdd(&loc[batch[i]], 1);
        __syncthreads();
        if (t < NGRAPH && loc[t]) atomicAdd(&counts[t], loc[t]);
    }
}

// ---------------- standalone gemm (layer 2: bf16 in, fp8 out) ----------------

__global__ __launch_bounds__(256) void gemm2_kernel(const unsigned short* __restrict__ Xv,
                                                    const unsigned short* __restrict__ Wt,
                                                    unsigned char* __restrict__ Hout,
                                                    const float* __restrict__ a_src,
                                                    const float* __restrict__ a_dst,
                                                    float* __restrict__ asrc,
                                                    float* __restrict__ adst) {
    __shared__ unsigned short A_lds[64 * F_IN];
    gemm_body<true>(blockIdx.x, threadIdx.x, Xv, Wt, Hout, a_src, a_dst, asrc, adst, A_lds);
}

// ---------------- per-bucket totals + base offsets ----------------

__global__ __launch_bounds__(256) void btot_kernel(const int* __restrict__ seg_cnt, int* __restrict__ btot) {
    int b = blockIdx.x, t = threadIdx.x;
    int s = 0;
    for (int j = t; j < NBLK; j += 256) s += seg_cnt[(size_t)j * NBUCK + b];
    for (int off = 32; off; off >>= 1) s += __shfl_down(s, off);
    __shared__ int ws[4];
    int lane = t & 63, w = t >> 6;
    if (lane == 0) ws[w] = s;
    __syncthreads();
    if (t == 0) btot[b] = ws[0] + ws[1] + ws[2] + ws[3];
}

__global__ __launch_bounds__(256) void bbase_kernel(const int* __restrict__ btot, int* __restrict__ bbase) {
    int t = threadIdx.x;
    int lane = t & 63, w = t >> 6;
    int v = (t < NBUCK) ? btot[t] : 0;
    int x = v;
#pragma unroll
    for (int off = 1; off < 64; off <<= 1) {
        int u = __shfl_up(x, off);
        if (lane >= off) x += u;
    }
    __shared__ int wt[4];
    if (lane == 63) wt[w] = x;
    __syncthreads();
    int add = 0;
#pragma unroll
    for (int k = 0; k < 3; ++k) if (k < w) add += wt[k];
    x += add;
    if (t < NBUCK) bbase[t] = x - v;   // exclusive
}

// ---------------- per-bucket build: count -> offs -> exact scatter ----------------

__global__ __launch_bounds__(1024) void bucket_build(const unsigned* __restrict__ pairs,
                                                     const int* __restrict__ seg_start,
                                                     const int* __restrict__ seg_cnt,
                                                     const int* __restrict__ bbase,
                                                     int* __restrict__ offs,
                                                     int* __restrict__ csr_src) {
    int b = blockIdx.x, t = threadIdx.x;
    int nodeBase = b << 9;
    __shared__ int cur[512];
    __shared__ int pref[NBLK];
    __shared__ int sstart[NBLK];
    __shared__ int wt2[16];

    if (t < 512) cur[t] = 0;
    for (int j = t; j < NBLK; j += 1024) {
        pref[j]   = seg_cnt[(size_t)j * NBUCK + b];
        sstart[j] = seg_start[(size_t)j * NBUCK + b];
    }
    __syncthreads();
    for (int off = 1; off < NBLK; off <<= 1) {
        int v = 0;
        if (t < NBLK && t >= off) v = pref[t - off];
        __syncthreads();
        if (t < NBLK) pref[t] += v;
        __syncthreads();
    }
    int M = pref[NBLK - 1];

    for (int j = t; j < M; j += 1024) {
        int lo = 0, hi = NBLK - 1;
        while (lo < hi) { int mid = (lo + hi) >> 1; if (pref[mid] > j) hi = mid; else lo = mid + 1; }
        int within = j - (lo ? pref[lo - 1] : 0);
        unsigned wd = pairs[(size_t)lo * CHUNK + sstart[lo] + within];
        atomicAdd(&cur[wd & 511u], 1);
    }
    __syncthreads();

    int lane = t & 63, w = t >> 6;
    int myc = (t < 512) ? cur[t] : 0;
    int x = myc;
#pragma unroll
    for (int off = 1; off < 64; off <<= 1) {
        int u = __shfl_up(x, off);
        if (lane >= off) x += u;
    }
    if (lane == 63) wt2[w] = x;
    __syncthreads();
    int add = 0;
#pragma unroll
    for (int k = 0; k < 15; ++k) if (k < w) add += wt2[k];
    x += add;
    int gstart = bbase[b] + x - myc;
    if (t < 512) {
        if (nodeBase + t <= N_NODES) offs[nodeBase + t] = gstart;
        cur[t] = gstart;
    }
    __syncthreads();

    for (int j = t; j < M; j += 1024) {
        int lo = 0, hi = NBLK - 1;
        while (lo < hi) { int mid = (lo + hi) >> 1; if (pref[mid] > j) hi = mid; else lo = mid + 1; }
        int within = j - (lo ? pref[lo - 1] : 0);
        unsigned wd = pairs[(size_t)lo * CHUNK + sstart[lo] + within];
        int pos = atomicAdd(&cur[wd & 511u], 1);
        csr_src[pos] = (int)(wd >> 9);
    }
}

// ---------------- W -> bf16, fragment-ready layout (both weights) ----------------

__global__ __launch_bounds__(256) void wtconv_both(const float* __restrict__ W1, const float* __restrict__ W2,
                                                   unsigned short* __restrict__ Wt1, unsigned short* __restrict__ Wt2) {
    int i = blockIdx.x * 256 + threadIdx.x;
    const float* W = (i < F_IN * HC) ? W1 : W2;
    unsigned short* Wt = (i < F_IN * HC) ? Wt1 : Wt2;
    int j = (i < F_IN * HC) ? i : i - F_IN * HC;
    if (j < F_IN * HC) {
        int k = j >> 7, col = j & 127;
        Wt[(size_t)(k >> 3) * (HC * 8) + col * 8 + (k & 7)] = f2bf_rne(W[j]);
    }
}

// ---------------- aggregation: 8-lane edge groups, 16 fp8 ch/lane (full 128 B row/group) ---
// grp = lane>>3 (edge slot 0..7); q = lane&7 holds channels q*16..q*16+15; head = q>>2.
// 2x unroll -> 16 edges in flight/wave, halved per-edge fixed VALU. Reduction: xor8/16/32
// (preserves q). Lanes 0..7 write 32 B each (channels q*16..+15).

__global__ __launch_bounds__(256) void agg_kernel(const int* __restrict__ offs, const int* __restrict__ csr_src,
                                                  const float* __restrict__ asrc, const float* __restrict__ adst,
                                                  const unsigned char* __restrict__ Hin,
                                                  const float* __restrict__ bias,
                                                  unsigned short* __restrict__ Hout, int do_relu) {
    int wid  = (blockIdx.x * 256 + threadIdx.x) >> 6;
    int lane = threadIdx.x & 63;
    if (wid >= N_NODES) return;
    int beg = offs[wid], end = offs[wid + 1];
    int grp = lane >> 3;           // edge slot 0..7
    int q   = lane & 7;            // channels q*16 .. q*16+15
    int head = q >> 2;
    float madst = adst[(size_t)wid * 2 + head];        // scalar load (own head)
    const unsigned char* hbase = Hin + q * 16;

    float den = 0.f;
    float ac[16];
#pragma unroll
    for (int i = 0; i < 16; ++i) ac[i] = 0.f;

    for (int e = beg + grp; e < end; e += 16) {
        int en = e + 8;
        bool v1 = en < end;
        int s0 = csr_src[e];
        int s1 = v1 ? csr_src[en] : s0;
        float aa0 = asrc[(size_t)s0 * 2 + head];       // scalar gathers (own head)
        float aa1 = asrc[(size_t)s1 * 2 + head];
        uint4 g0 = *(const uint4*)&hbase[(size_t)s0 * HC];
        uint4 g1 = *(const uint4*)&hbase[(size_t)s1 * HC];
        float l0 = aa0 + madst; l0 = l0 > 0.f ? l0 : NEG_SLOPE * l0;
        float l1 = aa1 + madst; l1 = l1 > 0.f ? l1 : NEG_SLOPE * l1;
        float w0 = __expf(l0);
        float w1 = v1 ? __expf(l1) : 0.f;
        den += w0 + w1;
        unsigned d0[4] = { g0.x, g0.y, g0.z, g0.w };
        unsigned d1[4] = { g1.x, g1.y, g1.z, g1.w };
#pragma unroll
        for (int k = 0; k < 4; ++k) {
            f32x2 p0a = __builtin_amdgcn_cvt_pk_f32_fp8(d0[k], 0);
            f32x2 p0b = __builtin_amdgcn_cvt_pk_f32_fp8(d0[k], 1);
            f32x2 p1a = __builtin_amdgcn_cvt_pk_f32_fp8(d1[k], 0);
            f32x2 p1b = __builtin_amdgcn_cvt_pk_f32_fp8(d1[k], 1);
            ac[k * 4 + 0] = fmaf(w1, p1a.x, fmaf(w0, p0a.x, ac[k * 4 + 0]));
            ac[k * 4 + 1] = fmaf(w1, p1a.y, fmaf(w0, p0a.y, ac[k * 4 + 1]));
            ac[k * 4 + 2] = fmaf(w1, p1b.x, fmaf(w0, p0b.x, ac[k * 4 + 2]));
            ac[k * 4 + 3] = fmaf(w1, p1b.y, fmaf(w0, p0b.y, ac[k * 4 + 3]));
        }
    }

#pragma unroll
    for (int off = 8; off <= 32; off <<= 1) {
        den += __shfl_xor(den, off);
#pragma unroll
        for (int i = 0; i < 16; ++i) ac[i] += __shfl_xor(ac[i], off);
    }

    if (lane < 8) {
        float inv = 1.0f / den;
        float o[16];
#pragma unroll
        for (int k = 0; k < 4; ++k) {
            float4 bb = *(const float4*)&bias[q * 16 + k * 4];
            o[k * 4 + 0] = fmaf(ac[k * 4 + 0], inv, bb.x);
            o[k * 4 + 1] = fmaf(ac[k * 4 + 1], inv, bb.y);
            o[k * 4 + 2] = fmaf(ac[k * 4 + 2], inv, bb.z);
            o[k * 4 + 3] = fmaf(ac[k * 4 + 3], inv, bb.w);
        }
        if (do_relu) {
#pragma unroll
            for (int i = 0; i < 16; ++i) o[i] = fmaxf(o[i], 0.f);
        }
        uint4 st0, st1;
        st0.x = (unsigned)f2bf_rne(o[0])  | ((unsigned)f2bf_rne(o[1])  << 16);
        st0.y = (unsigned)f2bf_rne(o[2])  | ((unsigned)f2bf_rne(o[3])  << 16);
        st0.z = (unsigned)f2bf_rne(o[4])  | ((unsigned)f2bf_rne(o[5])  << 16);
        st0.w = (unsigned)f2bf_rne(o[6])  | ((unsigned)f2bf_rne(o[7])  << 16);
        st1.x = (unsigned)f2bf_rne(o[8])  | ((unsigned)f2bf_rne(o[9])  << 16);
        st1.y = (unsigned)f2bf_rne(o[10]) | ((unsigned)f2bf_rne(o[11]) << 16);
        st1.z = (unsigned)f2bf_rne(o[12]) | ((unsigned)f2bf_rne(o[13]) << 16);
        st1.w = (unsigned)f2bf_rne(o[14]) | ((unsigned)f2bf_rne(o[15]) << 16);
        *(uint4*)&Hout[(size_t)wid * HC + q * 16]     = st0;
        *(uint4*)&Hout[(size_t)wid * HC + q * 16 + 8] = st1;
    }
}

// ---------------- mean pool (bf16 input; 8K atomics only) ----------------

__global__ __launch_bounds__(256) void pool_kernel(const unsigned short* __restrict__ H2,
                                                   const int* __restrict__ counts,
                                                   float* __restrict__ out) {
    int g = blockIdx.x;
    int chunk = blockIdx.y;
    __shared__ int soff, scnt;
    if (threadIdx.x == 0) {
        int s = 0;
        for (int i = 0; i < g; ++i) s += counts[i];
        soff = s; scnt = counts[g];
    }
    __syncthreads();
    int start = soff, cnt = scnt;
    int r = threadIdx.x >> 7;
    int c = threadIdx.x & 127;
    float acc = 0.f;
    for (int v = chunk * 2 + r; v < cnt; v += 16)
        acc += bf2f((unsigned)H2[(size_t)(start + v) * HC + c]);
    float inv = 1.0f / fmaxf((float)cnt, 1.0f);
    atomicAdd(&out[g * HC + c], acc * inv);
}

// ---------------- launch ----------------

extern "C" void kernel_launch(void* const* d_in, const int* in_sizes, int n_in,
                              void* d_out, int out_size, void* d_ws, size_t ws_size,
                              hipStream_t stream) {
    const float* x     = (const float*)d_in[0];
    const int*   ei    = (const int*)d_in[1];
    const int*   batch = (const int*)d_in[2];
    const float* W1    = (const float*)d_in[3];
    const float* a1s   = (const float*)d_in[4];
    const float* a1d   = (const float*)d_in[5];
    const float* b1    = (const float*)d_in[6];
    const float* W2    = (const float*)d_in[7];
    const float* a2s   = (const float*)d_in[8];
    const float* a2d   = (const float*)d_in[9];
    const float* b2    = (const float*)d_in[10];
    float* out = (float*)d_out;

    char* ws = (char*)d_ws;
    const size_t NH = (size_t)N_NODES * HC;
    unsigned char* hA = (unsigned char*)ws;                 // fp8 gather table, 12.8 MB
    unsigned short* hB = (unsigned short*)(ws + NH);        // bf16, 25.6 MB
    unsigned* pairs = (unsigned*)(hB + NH);                 // 6.8 MB
    float* asrc = (float*)(pairs + (size_t)NBLK * CHUNK);
    float* adst = asrc + (size_t)N_NODES * 2;
    unsigned short* wt1 = (unsigned short*)(adst + (size_t)N_NODES * 2);
    unsigned short* wt2 = wt1 + F_IN * HC;
    int*   offs = (int*)(wt2 + F_IN * HC);
    int*   csr  = offs + (N_NODES + 1);
    int*   seg_start = csr + TOT_E;
    int*   seg_cnt   = seg_start + (size_t)NBLK * NBUCK;
    int*   btot = seg_cnt + (size_t)NBLK * NBUCK;
    int*   bbase = btot + NBUCK;
    int*   counts = bbase + NBUCK;

    hipMemsetAsync(counts, 0, NGRAPH * sizeof(int), stream);
    hipMemsetAsync(out, 0, (size_t)out_size * sizeof(float), stream);

    // weights -> bf16 fragment layout (both layers, one launch)
    wtconv_both<<<(2 * F_IN * HC + 255) / 256, 256, 0, stream>>>(W1, W2, wt1, wt2);

    // fused: gemm1(+alpha) ⊗ binpart ⊗ counts
    fused_main<<<GEMM_B + NBLK + CNT_B, 256, 0, stream>>>(x, wt1, hA, a1s, a1d, asrc, adst,
                                                          ei, pairs, seg_start, seg_cnt,
                                                          batch, counts);

    // CSR finalize
    btot_kernel<<<NBUCK, 256, 0, stream>>>(seg_cnt, btot);
    bbase_kernel<<<1, 256, 0, stream>>>(btot, bbase);
    bucket_build<<<NBUCK, 1024, 0, stream>>>(pairs, seg_start, seg_cnt, bbase, offs, csr);

    int waveBlocks = (N_NODES + 3) / 4;

    // layer 1 aggregation
    agg_kernel<<<waveBlocks, 256, 0, stream>>>(offs, csr, asrc, adst, hA, b1, hB, 1);

    // layer 2
    gemm2_kernel<<<GEMM_B, 256, 0, stream>>>(hB, wt2, hA, a2s, a2d, asrc, adst);
    agg_kernel<<<waveBlocks, 256, 0, stream>>>(offs, csr, asrc, adst, hA, b2, hB, 0);

    // pool
    pool_kernel<<<dim3(NGRAPH, 8), 256, 0, stream>>>(hB, counts, out);
}